// Round 3
// baseline (7793.300 us; speedup 1.0000x reference)
//
#include <hip/hip_runtime.h>
#include <math.h>

#define NN 4096
#define CC 256
#define HH 64
#define BT 16
#define KCC 100
#define NHH 8
#define HDD 32
#define C4 1024

typedef unsigned short bf16_t;

__device__ __forceinline__ float bf2f(bf16_t h) {
  return __uint_as_float(((unsigned)h) << 16);
}
__device__ __forceinline__ bf16_t f2bf(float f) {
  unsigned u = __float_as_uint(f);
  return (bf16_t)((u + 0x7FFFu + ((u >> 16) & 1u)) >> 16);
}

__device__ __forceinline__ float gelu_f(float x) {
  return 0.5f * x * (1.0f + erff(x * 0.7071067811865475f));
}

__device__ __forceinline__ float block_sum256(float v) {
  __shared__ float sh[4];
#pragma unroll
  for (int off = 32; off; off >>= 1) v += __shfl_xor(v, off, 64);
  __syncthreads();
  if ((threadIdx.x & 63) == 0) sh[threadIdx.x >> 6] = v;
  __syncthreads();
  return sh[0] + sh[1] + sh[2] + sh[3];
}

// select xt[bt] base without materializing xt: tt<3 -> mem[(b*3+tt)], tt==3 -> x[b]
__device__ __forceinline__ const float* xt_base(const float* x, const float* mem, int bt) {
  int b = bt >> 2, tt = bt & 3;
  return (tt < 3) ? (mem + (size_t)(b * 3 + tt) * NN * CC)
                  : (x + (size_t)b * NN * CC);
}

// wt[((ky*7+kx)*CC+ci)*CC+co] = conv1_w[((co*CC+ci)*7+ky)*7+kx]
__global__ __launch_bounds__(256) void transpose_w1(const float* __restrict__ w,
                                                    float* __restrict__ wt) {
  int i = blockIdx.x * 256 + threadIdx.x;
  if (i >= 49 * CC * CC) return;
  int co = i & 255;
  int ci = (i >> 8) & 255;
  int kk = i >> 16;
  int ky = kk / 7, kx = kk % 7;
  wt[i] = w[((size_t)(co * CC + ci) * 7 + ky) * 7 + kx];
}

// 7x7 conv as implicit GEMM. Block: one image row (bt,h) x 64 co. bf16 out = gelu(conv+bias)
__global__ __launch_bounds__(256) void conv1_kernel(const float* __restrict__ x,
                                                    const float* __restrict__ mem,
                                                    const float* __restrict__ wt,
                                                    const float* __restrict__ bias,
                                                    bf16_t* __restrict__ h1) {
  int bx = blockIdx.x;
  int co0 = (bx & 3) * 64;
  int row = bx >> 2;
  int bt = row >> 6;
  int h = row & 63;
  __shared__ float As[8][72];      // [ci][j], j = input col + 3 (0..69)
  __shared__ float Ws[7][8][64];   // [kx][ci][co]
  int tid = threadIdx.x;
  int txn = tid & 15;   // co group (4 co)
  int tym = tid >> 4;   // w group (4 w)
  float acc[4][4] = {};
  const float* xbase = xt_base(x, mem, bt);
  for (int ky = 0; ky < 7; ++ky) {
    int r = h + ky - 3;
    if (r < 0 || r >= HH) continue;
    for (int ci0 = 0; ci0 < CC; ci0 += 8) {
      for (int idx = tid; idx < 560; idx += 256) {
        int ci = idx & 7;
        int j = idx >> 3;
        int col = j - 3;
        float v = 0.f;
        if (col >= 0 && col < 64) v = xbase[((size_t)r * 64 + col) * CC + ci0 + ci];
        As[ci][j] = v;
      }
      for (int idx = tid; idx < 3584; idx += 256) {
        int co = idx & 63;
        int ci = (idx >> 6) & 7;
        int kx = idx >> 9;
        Ws[kx][ci][co] = wt[((size_t)(ky * 7 + kx) * CC + ci0 + ci) * CC + co0 + co];
      }
      __syncthreads();
      for (int ci = 0; ci < 8; ++ci) {
        float a[10];
        float4 t0 = *(const float4*)&As[ci][tym * 4];
        float4 t1 = *(const float4*)&As[ci][tym * 4 + 4];
        float2 t2 = *(const float2*)&As[ci][tym * 4 + 8];
        a[0] = t0.x; a[1] = t0.y; a[2] = t0.z; a[3] = t0.w;
        a[4] = t1.x; a[5] = t1.y; a[6] = t1.z; a[7] = t1.w;
        a[8] = t2.x; a[9] = t2.y;
#pragma unroll
        for (int kx = 0; kx < 7; ++kx) {
          float4 w4 = *(const float4*)&Ws[kx][ci][txn * 4];
#pragma unroll
          for (int wi = 0; wi < 4; ++wi) {
            float av = a[wi + kx];
            acc[wi][0] += av * w4.x;
            acc[wi][1] += av * w4.y;
            acc[wi][2] += av * w4.z;
            acc[wi][3] += av * w4.w;
          }
        }
      }
      __syncthreads();
    }
  }
#pragma unroll
  for (int wi = 0; wi < 4; ++wi) {
    int w = tym * 4 + wi;
    bf16_t* dst = h1 + ((size_t)bt * NN + h * 64 + w) * CC + co0 + txn * 4;
#pragma unroll
    for (int coi = 0; coi < 4; ++coi) {
      float v = acc[wi][coi] + bias[co0 + txn * 4 + coi];
      dst[coi] = f2bf(gelu_f(v));
    }
  }
}

// out[m,n] = act(sum_k A[m,k]*W[n,k] + bias[n]); W row-major (N,K) fp32.
// ABF: A is bf16. OBF: out is bf16. TOUT: out[n*ldo+m] instead of out[m*ldo+n].
template <int GELU, int BIAS, int TOUT, int ABF, int OBF>
__global__ __launch_bounds__(256) void gemm_nt(const void* __restrict__ Ap,
                                               const float* __restrict__ Wm,
                                               const float* __restrict__ bias,
                                               void* __restrict__ outp,
                                               int M, int N, int K, int ldo) {
  __shared__ float As[16][68];
  __shared__ float Ws[16][68];
  int tid = threadIdx.x;
  int n0 = blockIdx.x * 64, m0 = blockIdx.y * 64;
  int txn = tid & 15, tym = tid >> 4;
  int mi = tid >> 2, kq = (tid & 3) * 4;
  float acc[4][4] = {};
  for (int k0 = 0; k0 < K; k0 += 16) {
    float4 av = {0, 0, 0, 0}, wv = {0, 0, 0, 0};
    if (m0 + mi < M) {
      if (ABF) {
        ushort4 u = *(const ushort4*)((const bf16_t*)Ap + (size_t)(m0 + mi) * K + k0 + kq);
        av.x = bf2f(u.x); av.y = bf2f(u.y); av.z = bf2f(u.z); av.w = bf2f(u.w);
      } else {
        av = *(const float4*)((const float*)Ap + (size_t)(m0 + mi) * K + k0 + kq);
      }
    }
    if (n0 + mi < N) wv = *(const float4*)&Wm[(size_t)(n0 + mi) * K + k0 + kq];
    As[kq + 0][mi] = av.x; As[kq + 1][mi] = av.y; As[kq + 2][mi] = av.z; As[kq + 3][mi] = av.w;
    Ws[kq + 0][mi] = wv.x; Ws[kq + 1][mi] = wv.y; Ws[kq + 2][mi] = wv.z; Ws[kq + 3][mi] = wv.w;
    __syncthreads();
#pragma unroll
    for (int ki = 0; ki < 16; ++ki) {
      float4 a4 = *(const float4*)&As[ki][tym * 4];
      float4 w4 = *(const float4*)&Ws[ki][txn * 4];
      float am[4] = {a4.x, a4.y, a4.z, a4.w};
      float wn[4] = {w4.x, w4.y, w4.z, w4.w};
#pragma unroll
      for (int i = 0; i < 4; ++i)
#pragma unroll
        for (int j = 0; j < 4; ++j) acc[i][j] += am[i] * wn[j];
    }
    __syncthreads();
  }
#pragma unroll
  for (int i = 0; i < 4; ++i) {
    int m = m0 + tym * 4 + i;
    if (m >= M) continue;
#pragma unroll
    for (int j = 0; j < 4; ++j) {
      int n = n0 + txn * 4 + j;
      if (n >= N) continue;
      float v = acc[i][j];
      if (BIAS) v += bias[n];
      if (GELU) v = gelu_f(v);
      size_t idx = TOUT ? ((size_t)n * ldo + m) : ((size_t)m * ldo + n);
      if (OBF)
        ((bf16_t*)outp)[idx] = f2bf(v);
      else
        ((float*)outp)[idx] = v;
    }
  }
}

// 1600 rows of 4096 contiguous floats, softmax in place
__global__ __launch_bounds__(256) void softmax_rows(float* __restrict__ p) {
  __shared__ float sh[8];
  int tid = threadIdx.x;
  float* base = p + (size_t)blockIdx.x * NN;
  float vals[16];
  float mx = -1e30f;
#pragma unroll
  for (int i = 0; i < 16; ++i) {
    vals[i] = base[tid + i * 256];
    mx = fmaxf(mx, vals[i]);
  }
#pragma unroll
  for (int off = 32; off; off >>= 1) mx = fmaxf(mx, __shfl_xor(mx, off, 64));
  if ((tid & 63) == 0) sh[tid >> 6] = mx;
  __syncthreads();
  mx = fmaxf(fmaxf(sh[0], sh[1]), fmaxf(sh[2], sh[3]));
  float s = 0.f;
#pragma unroll
  for (int i = 0; i < 16; ++i) {
    vals[i] = expf(vals[i] - mx);
    s += vals[i];
  }
#pragma unroll
  for (int off = 32; off; off >>= 1) s += __shfl_xor(s, off, 64);
  if ((tid & 63) == 0) sh[4 + (tid >> 6)] = s;
  __syncthreads();
  s = sh[4] + sh[5] + sh[6] + sh[7];
  float inv = 1.f / s;
#pragma unroll
  for (int i = 0; i < 16; ++i) base[tid + i * 256] = vals[i] * inv;
}

// center[bt][kc][c] = sum_n soft[(kc*16+bt)*4096+n] * xt[bt][n][c]  (xt read from x/mem)
__global__ __launch_bounds__(256) void center_einsum(const float* __restrict__ soft,
                                                     const float* __restrict__ x,
                                                     const float* __restrict__ mem,
                                                     float* __restrict__ center) {
  int bt = blockIdx.x & 15;
  int kg = blockIdx.x >> 4;  // 0..9
  int c = threadIdx.x;
  const float* xbase = xt_base(x, mem, bt);
  __shared__ float sl[10][512];
  float acc[10] = {};
  for (int n0 = 0; n0 < NN; n0 += 512) {
    for (int idx = threadIdx.x; idx < 10 * 512; idx += 256) {
      int n = idx & 511;
      int j = idx >> 9;
      sl[j][n] = soft[((size_t)(kg * 10 + j) * BT + bt) * NN + n0 + n];
    }
    __syncthreads();
    for (int n = 0; n < 512; ++n) {
      float xv = xbase[((size_t)(n0 + n)) * CC + c];
#pragma unroll
      for (int j = 0; j < 10; ++j) acc[j] += sl[j][n] * xv;
    }
    __syncthreads();
  }
#pragma unroll
  for (int j = 0; j < 10; ++j)
    center[((size_t)bt * KCC + kg * 10 + j) * CC + c] = acc[j];
}

// cosine-sim gating + LN -> cin[b][kc][c]
__global__ __launch_bounds__(256) void sim_cin(const float* __restrict__ center,
                                               const float* __restrict__ alpha_p,
                                               const float* __restrict__ beta_p,
                                               const float* __restrict__ lnw,
                                               const float* __restrict__ lnb,
                                               float* __restrict__ cin) {
  int b = blockIdx.x / KCC, kc = blockIdx.x % KCC;
  int c = threadIdx.x;
  float p0 = center[(((size_t)(b * 4 + 0)) * KCC + kc) * CC + c];
  float p1 = center[(((size_t)(b * 4 + 1)) * KCC + kc) * CC + c];
  float p2 = center[(((size_t)(b * 4 + 2)) * KCC + kc) * CC + c];
  float lst = center[(((size_t)(b * 4 + 3)) * KCC + kc) * CC + c];
  float ll = block_sum256(lst * lst);
  float q0 = block_sum256(p0 * p0);
  float q1 = block_sum256(p1 * p1);
  float q2 = block_sum256(p2 * p2);
  float d0 = block_sum256(lst * p0);
  float d1 = block_sum256(lst * p1);
  float d2 = block_sum256(lst * p2);
  float alpha = alpha_p[0], beta = beta_p[0];
  float nl = sqrtf(ll);
  float c0 = 1.f / (1.f + expf(-(beta + alpha * (d0 / fmaxf(nl * sqrtf(q0), 1e-8f)))));
  float c1 = 1.f / (1.f + expf(-(beta + alpha * (d1 / fmaxf(nl * sqrtf(q1), 1e-8f)))));
  float c2 = 1.f / (1.f + expf(-(beta + alpha * (d2 / fmaxf(nl * sqrtf(q2), 1e-8f)))));
  float v = lst + c0 * p0 + c1 * p1 + c2 * p2;
  float m = block_sum256(v) * (1.f / CC);
  float dv = v - m;
  float var = block_sum256(dv * dv) * (1.f / CC);
  cin[((size_t)b * KCC + kc) * CC + c] = dv * rsqrtf(var + 1e-5f) * lnw[c] + lnb[c];
}

// fused attention: one block per (b,n). scores(8x100) -> softmax -> o(256)
__global__ __launch_bounds__(256) void attn_kernel(const float* __restrict__ q,
                                                   const float* __restrict__ kb,
                                                   const float* __restrict__ vb,
                                                   float* __restrict__ ob) {
  int b = blockIdx.x >> 12, n = blockIdx.x & 4095;
  int tid = threadIdx.x;
  __shared__ float qs[CC];
  __shared__ float sc[NHH][KCC + 4];
  qs[tid] = q[((size_t)b * NN + n) * CC + tid] * 0.17677669529663687f;  // hd^-0.5
  __syncthreads();
  if (tid < KCC) {
    const float* krow = kb + ((size_t)b * KCC + tid) * CC;
#pragma unroll
    for (int h = 0; h < NHH; ++h) {
      float s = 0.f;
#pragma unroll
      for (int d = 0; d < HDD; ++d) s += qs[h * HDD + d] * krow[h * HDD + d];
      sc[h][tid] = s;
    }
  }
  __syncthreads();
  int h = tid >> 5, d = tid & 31;
  float mx = -1e30f;
  for (int kc = d; kc < KCC; kc += 32) mx = fmaxf(mx, sc[h][kc]);
#pragma unroll
  for (int off = 16; off; off >>= 1) mx = fmaxf(mx, __shfl_xor(mx, off, 32));
  float sm = 0.f;
  for (int kc = d; kc < KCC; kc += 32) {
    float e = expf(sc[h][kc] - mx);
    sc[h][kc] = e;
    sm += e;
  }
#pragma unroll
  for (int off = 16; off; off >>= 1) sm += __shfl_xor(sm, off, 32);
  __syncthreads();
  float inv = 1.f / sm;
  float o = 0.f;
  const float* vbase = vb + (size_t)b * KCC * CC + tid;
  for (int kc = 0; kc < KCC; ++kc) o += sc[h][kc] * vbase[(size_t)kc * CC];
  ob[((size_t)b * NN + n) * CC + tid] = o * inv;
}

// dst[row][c] = res[row][c] + LN(y[row][:])[c]
__global__ __launch_bounds__(256) void add_ln(const float* __restrict__ res,
                                              const float* __restrict__ y,
                                              const float* __restrict__ lnw,
                                              const float* __restrict__ lnb,
                                              float* __restrict__ dst) {
  size_t row = blockIdx.x;
  int c = threadIdx.x;
  float v = y[row * CC + c];
  float m = block_sum256(v) * (1.f / CC);
  float dv = v - m;
  float var = block_sum256(dv * dv) * (1.f / CC);
  dst[row * CC + c] = res[row * CC + c] + dv * rsqrtf(var + 1e-5f) * lnw[c] + lnb[c];
}

// depthwise 3x3 + bias + gelu, one batch b per launch; y1 bf16 (full), y2c bf16 (chunk)
__global__ __launch_bounds__(256) void dwconv_kernel(const bf16_t* __restrict__ y1,
                                                     const float* __restrict__ dww,
                                                     const float* __restrict__ dwb,
                                                     bf16_t* __restrict__ y2c, int b) {
  int n = blockIdx.x;  // px within this b
  int h = n >> 6, w = n & 63;
  int c40 = threadIdx.x * 4;
  float wreg[4][9];
#pragma unroll
  for (int j = 0; j < 4; ++j)
#pragma unroll
    for (int t2 = 0; t2 < 9; ++t2) wreg[j][t2] = dww[(size_t)(c40 + j) * 9 + t2];
  float acc[4] = {0, 0, 0, 0};
#pragma unroll
  for (int dy = 0; dy < 3; ++dy) {
    int r = h + dy - 1;
    if (r < 0 || r >= HH) continue;
#pragma unroll
    for (int dx = 0; dx < 3; ++dx) {
      int cl = w + dx - 1;
      if (cl < 0 || cl >= 64) continue;
      ushort4 u = *(const ushort4*)(y1 + ((size_t)b * NN + r * 64 + cl) * C4 + c40);
      int t2 = dy * 3 + dx;
      acc[0] += bf2f(u.x) * wreg[0][t2];
      acc[1] += bf2f(u.y) * wreg[1][t2];
      acc[2] += bf2f(u.z) * wreg[2][t2];
      acc[3] += bf2f(u.w) * wreg[3][t2];
    }
  }
  ushort4 o;
  o.x = f2bf(gelu_f(acc[0] + dwb[c40 + 0]));
  o.y = f2bf(gelu_f(acc[1] + dwb[c40 + 1]));
  o.z = f2bf(gelu_f(acc[2] + dwb[c40 + 2]));
  o.w = f2bf(gelu_f(acc[3] + dwb[c40 + 3]));
  *(ushort4*)(y2c + (size_t)n * C4 + c40) = o;
}

extern "C" void kernel_launch(void* const* d_in, const int* in_sizes, int n_in,
                              void* d_out, int out_size, void* d_ws, size_t ws_size,
                              hipStream_t stream) {
  const float* x = (const float*)d_in[0];
  const float* mem = (const float*)d_in[1];
  const float* conv1_w = (const float*)d_in[2];
  const float* conv1_b = (const float*)d_in[3];
  const float* conv2_w = (const float*)d_in[4];
  const float* conv2_b = (const float*)d_in[5];
  const float* conv3_w = (const float*)d_in[6];
  const float* sim_a = (const float*)d_in[7];
  const float* sim_b = (const float*)d_in[8];
  const float* ln_w = (const float*)d_in[9];
  const float* ln_b = (const float*)d_in[10];
  const float* q_w = (const float*)d_in[11];
  const float* q_b = (const float*)d_in[12];
  const float* k_w = (const float*)d_in[13];
  const float* k_b = (const float*)d_in[14];
  const float* v_w = (const float*)d_in[15];
  const float* v_b = (const float*)d_in[16];
  const float* proj_w = (const float*)d_in[17];
  const float* proj_b = (const float*)d_in[18];
  const float* fc1_w = (const float*)d_in[19];
  const float* fc1_b = (const float*)d_in[20];
  const float* dw_w = (const float*)d_in[21];
  const float* dw_b = (const float*)d_in[22];
  const float* fc2_w = (const float*)d_in[23];
  const float* fc2_b = (const float*)d_in[24];

  // Byte-addressed workspace layout. Total 109,035,520 B = 104 MB.
  char* base = (char*)d_ws;
  bf16_t* bh1 = (bf16_t*)(base);                     // 33,554,432 B [conv1 out bf16]
  float* czt = (float*)(base + 33554432);            // 26,214,400 B
  float* wt1 = (float*)(base + 59768832);            // 12,845,056 B [dead after conv1]
  float* h2c = (float*)(base + 72613888);            // 16,777,216 B [dead after conv3]
  float* outb = (float*)(base + 89391104);           // 16,777,216 B
  float* center = (float*)(base + 106168320);        //  1,638,400 B
  float* cin = (float*)(base + 107806720);           //    409,600 B
  float* kb = (float*)(base + 108216320);            //    409,600 B
  float* vb = (float*)(base + 108625920);            //    409,600 B
  // Aliases (lifetimes verified against launch order):
  float* qb = (float*)(base);        // 16.8 MB; bh1 dead after conv2 chunks
  bf16_t* by1 = (bf16_t*)(base);     // 33.5 MB; qb dead after attn
  float* obuf = czt;                 // 16.8 MB; czt dead after center_einsum
  float* pbuf = h2c;                 // 16.8 MB; h2c dead after conv3 chunks
  bf16_t* y2c = (bf16_t*)wt1;        //  8.4 MB; wt1 dead after conv1
  float* yout = czt;                 // 16.8 MB; obuf dead after proj
  float* dout = (float*)d_out;

  transpose_w1<<<12544, 256, 0, stream>>>(conv1_w, wt1);
  conv1_kernel<<<4096, 256, 0, stream>>>(x, mem, wt1, conv1_b, bh1);
  // conv2 (gelu, bf16 A) -> conv3 (transposed store), chunked through h2c (4 x 16384 px)
  for (int i = 0; i < 4; ++i) {
    gemm_nt<1, 1, 0, 1, 0><<<dim3(4, 256), 256, 0, stream>>>(
        bh1 + (size_t)i * 16384 * CC, conv2_w, conv2_b, h2c, 16384, 256, 256, 256);
    gemm_nt<0, 0, 1, 0, 0><<<dim3(2, 256), 256, 0, stream>>>(
        h2c, conv3_w, nullptr, czt + (size_t)i * 16384, 16384, 100, 256, 65536);
  }
  softmax_rows<<<1600, 256, 0, stream>>>(czt);
  center_einsum<<<160, 256, 0, stream>>>(czt, x, mem, center);
  sim_cin<<<400, 256, 0, stream>>>(center, sim_a, sim_b, ln_w, ln_b, cin);
  gemm_nt<0, 1, 0, 0, 0><<<dim3(4, 256), 256, 0, stream>>>(x, q_w, q_b, qb,
                                                           16384, 256, 256, 256);
  gemm_nt<0, 1, 0, 0, 0><<<dim3(4, 7), 256, 0, stream>>>(cin, k_w, k_b, kb,
                                                         400, 256, 256, 256);
  gemm_nt<0, 1, 0, 0, 0><<<dim3(4, 7), 256, 0, stream>>>(cin, v_w, v_b, vb,
                                                         400, 256, 256, 256);
  attn_kernel<<<16384, 256, 0, stream>>>(qb, kb, vb, obuf);
  gemm_nt<0, 1, 0, 0, 0><<<dim3(4, 256), 256, 0, stream>>>(obuf, proj_w, proj_b, pbuf,
                                                           16384, 256, 256, 256);
  add_ln<<<16384, 256, 0, stream>>>(x, pbuf, ln_w, ln_b, outb);
  gemm_nt<0, 1, 0, 0, 1><<<dim3(16, 256), 256, 0, stream>>>(outb, fc1_w, fc1_b, by1,
                                                            16384, 1024, 256, 1024);
  // dwconv (bf16) -> fc2 (bf16 A), chunked per batch b through y2c (8.4 MB)
  for (int b = 0; b < 4; ++b) {
    dwconv_kernel<<<4096, 256, 0, stream>>>(by1, dw_w, dw_b, y2c, b);
    gemm_nt<0, 1, 0, 1, 0><<<dim3(4, 64), 256, 0, stream>>>(
        y2c, fc2_w, fc2_b, yout + (size_t)b * NN * CC, 4096, 256, 1024, 256);
  }
  add_ln<<<16384, 256, 0, stream>>>(outb, yout, ln_w, ln_b, dout);
}

// Round 4
// 2087.049 us; speedup vs baseline: 3.7341x; 3.7341x over previous
//
#include <hip/hip_runtime.h>
#include <math.h>

#define NN 4096
#define CC 256
#define HH 64
#define BT 16
#define KCC 100
#define NHH 8
#define HDD 32
#define C4 1024

typedef unsigned short bf16_t;
typedef short s16x8 __attribute__((ext_vector_type(8)));
typedef float f32x4 __attribute__((ext_vector_type(4)));

__device__ __forceinline__ float bf2f(bf16_t h) {
  return __uint_as_float(((unsigned)h) << 16);
}
__device__ __forceinline__ bf16_t f2bf(float f) {
  unsigned u = __float_as_uint(f);
  return (bf16_t)((u + 0x7FFFu + ((u >> 16) & 1u)) >> 16);
}

__device__ __forceinline__ float gelu_f(float x) {
  return 0.5f * x * (1.0f + erff(x * 0.7071067811865475f));
}

__device__ __forceinline__ float block_sum256(float v) {
  __shared__ float sh[4];
#pragma unroll
  for (int off = 32; off; off >>= 1) v += __shfl_xor(v, off, 64);
  __syncthreads();
  if ((threadIdx.x & 63) == 0) sh[threadIdx.x >> 6] = v;
  __syncthreads();
  return sh[0] + sh[1] + sh[2] + sh[3];
}

// select xt[bt] base without materializing xt: tt<3 -> mem[(b*3+tt)], tt==3 -> x[b]
__device__ __forceinline__ const float* xt_base(const float* x, const float* mem, int bt) {
  int b = bt >> 2, tt = bt & 3;
  return (tt < 3) ? (mem + (size_t)(b * 3 + tt) * NN * CC)
                  : (x + (size_t)b * NN * CC);
}

// xtb[bt][n][c] bf16 from x/mem fp32
__global__ __launch_bounds__(256) void build_xtb(const float* __restrict__ x,
                                                 const float* __restrict__ mem,
                                                 bf16_t* __restrict__ xtb) {
  int i = blockIdx.x * 256 + threadIdx.x;  // float4 index over BT*NN*CC/4
  int c4 = i & 63;
  int n = (i >> 6) & 4095;
  int bt = i >> 18;
  const float* src = xt_base(x, mem, bt) + (size_t)n * CC + c4 * 4;
  float4 v = *(const float4*)src;
  ushort4 o;
  o.x = f2bf(v.x); o.y = f2bf(v.y); o.z = f2bf(v.z); o.w = f2bf(v.w);
  *(ushort4*)(xtb + (size_t)i * 4) = o;
}

// wtb layout: [ky][cig(8)][cq(4)][kx(7)][oct(4)][co(64)][cj(8)] bf16
// element (ky,kx,ci,co): ci = cig*32+oct*8+cj, co_global = cq*64+co
__global__ __launch_bounds__(256) void transpose_w1b(const float* __restrict__ w,
                                                     bf16_t* __restrict__ wtb) {
  int i = blockIdx.x * 256 + threadIdx.x;
  if (i >= 7 * 8 * 4 * 7 * 4 * 64 * 8) return;
  int cj = i & 7;
  int t = i >> 3;
  int co = t & 63; t >>= 6;
  int oc = t & 3; t >>= 2;
  int kx = t % 7; t /= 7;
  int cq = t & 3; t >>= 2;
  int cg = t & 7;
  int ky = t >> 3;
  int ci = cg * 32 + oc * 8 + cj;
  int cog = cq * 64 + co;
  wtb[i] = f2bf(w[((size_t)(cog * CC + ci) * 7 + ky) * 7 + kx]);
}

// conv1 as bf16 MFMA implicit GEMM. Block: (bt, 4 output rows, 64 co).
// Wave wv = output row h0+wv; 4 m-tiles (64 px) x 4 n-tiles (64 co), 16x16x32 MFMA.
__global__ __launch_bounds__(256, 3) void conv1_mfma(const bf16_t* __restrict__ xtb,
                                                     const bf16_t* __restrict__ wtb,
                                                     const float* __restrict__ bias,
                                                     bf16_t* __restrict__ h1) {
  int bt = blockIdx.x >> 6;
  int h0 = ((blockIdx.x >> 2) & 15) * 4;
  int cq = blockIdx.x & 3;
  int co0 = cq * 64;
  int tid = threadIdx.x;
  int wv = tid >> 6;       // output row offset 0..3
  int lane = tid & 63;
  int lm = lane & 15;      // m (A) / n (B) lane index
  int g = lane >> 4;       // k-octet group
  __shared__ short As[4][4][70][8];  // [row][oct][col(-3..66)][cj]  17920 B
  __shared__ short Ws[7][4][64][8];  // [kx][oct][co][cj]            28672 B
  f32x4 acc[4][4] = {};
  const size_t xbase = (size_t)bt * (NN * CC);
  for (int ky = 0; ky < 7; ++ky) {
    int r0 = h0 + ky - 3;
    for (int cig = 0; cig < 8; ++cig) {
      int ci0 = cig * 32;
      // stage A: 4 rows x 70 cols x 4 octs = 1120 chunks of 16 B (zero-padded halo)
      for (int idx = tid; idx < 1120; idx += 256) {
        int rr = idx / 280;
        int rem = idx - rr * 280;
        int col = rem >> 2;
        int oc = rem & 3;
        int r = r0 + rr, icol = col - 3;
        s16x8 v = {0, 0, 0, 0, 0, 0, 0, 0};
        if (r >= 0 && r < HH && icol >= 0 && icol < 64)
          v = *(const s16x8*)(xtb + xbase + ((size_t)(r * 64 + icol)) * CC + ci0 + oc * 8);
        *(s16x8*)&As[rr][oc][col][0] = v;
      }
      // stage W: 1792 contiguous 16 B chunks (layout matches LDS order exactly)
      const bf16_t* wsrc = wtb + ((size_t)((ky * 8 + cig) * 4 + cq)) * (1792 * 8);
      for (int idx = tid; idx < 1792; idx += 256) {
        int kx = idx >> 8;
        int oc = (idx >> 6) & 3;
        int co = idx & 63;
        *(s16x8*)&Ws[kx][oc][co][0] = *(const s16x8*)(wsrc + (size_t)idx * 8);
      }
      __syncthreads();
#pragma unroll
      for (int kx = 0; kx < 7; ++kx) {
        s16x8 af[4], bf[4];
#pragma unroll
        for (int mt = 0; mt < 4; ++mt)
          af[mt] = *(const s16x8*)&As[wv][g][mt * 16 + lm + kx][0];
#pragma unroll
        for (int nt = 0; nt < 4; ++nt)
          bf[nt] = *(const s16x8*)&Ws[kx][g][nt * 16 + lm][0];
#pragma unroll
        for (int mt = 0; mt < 4; ++mt)
#pragma unroll
          for (int nt = 0; nt < 4; ++nt)
            acc[mt][nt] = __builtin_amdgcn_mfma_f32_16x16x32_bf16(af[mt], bf[nt],
                                                                  acc[mt][nt], 0, 0, 0);
      }
      __syncthreads();
    }
  }
  // epilogue: C/D layout col=lane&15 (co), row=(lane>>4)*4+reg (pixel)
  int row = h0 + wv;
#pragma unroll
  for (int nt = 0; nt < 4; ++nt) {
    int co = co0 + nt * 16 + lm;
    float bs = bias[co];
#pragma unroll
    for (int mt = 0; mt < 4; ++mt) {
#pragma unroll
      for (int rg = 0; rg < 4; ++rg) {
        int col = mt * 16 + g * 4 + rg;
        float vv = acc[mt][nt][rg] + bs;
        h1[xbase + (size_t)(row * 64 + col) * CC + co] = f2bf(gelu_f(vv));
      }
    }
  }
}

// out[m,n] = act(sum_k A[m,k]*W[n,k] + bias[n]); W row-major (N,K) fp32.
// ABF: A is bf16. OBF: out is bf16. TOUT: out[n*ldo+m] instead of out[m*ldo+n].
template <int GELU, int BIAS, int TOUT, int ABF, int OBF>
__global__ __launch_bounds__(256) void gemm_nt(const void* __restrict__ Ap,
                                               const float* __restrict__ Wm,
                                               const float* __restrict__ bias,
                                               void* __restrict__ outp,
                                               int M, int N, int K, int ldo) {
  __shared__ float As[16][68];
  __shared__ float Ws[16][68];
  int tid = threadIdx.x;
  int n0 = blockIdx.x * 64, m0 = blockIdx.y * 64;
  int txn = tid & 15, tym = tid >> 4;
  int mi = tid >> 2, kq = (tid & 3) * 4;
  float acc[4][4] = {};
  for (int k0 = 0; k0 < K; k0 += 16) {
    float4 av = {0, 0, 0, 0}, wv = {0, 0, 0, 0};
    if (m0 + mi < M) {
      if (ABF) {
        ushort4 u = *(const ushort4*)((const bf16_t*)Ap + (size_t)(m0 + mi) * K + k0 + kq);
        av.x = bf2f(u.x); av.y = bf2f(u.y); av.z = bf2f(u.z); av.w = bf2f(u.w);
      } else {
        av = *(const float4*)((const float*)Ap + (size_t)(m0 + mi) * K + k0 + kq);
      }
    }
    if (n0 + mi < N) wv = *(const float4*)&Wm[(size_t)(n0 + mi) * K + k0 + kq];
    As[kq + 0][mi] = av.x; As[kq + 1][mi] = av.y; As[kq + 2][mi] = av.z; As[kq + 3][mi] = av.w;
    Ws[kq + 0][mi] = wv.x; Ws[kq + 1][mi] = wv.y; Ws[kq + 2][mi] = wv.z; Ws[kq + 3][mi] = wv.w;
    __syncthreads();
#pragma unroll
    for (int ki = 0; ki < 16; ++ki) {
      float4 a4 = *(const float4*)&As[ki][tym * 4];
      float4 w4 = *(const float4*)&Ws[ki][txn * 4];
      float am[4] = {a4.x, a4.y, a4.z, a4.w};
      float wn[4] = {w4.x, w4.y, w4.z, w4.w};
#pragma unroll
      for (int i = 0; i < 4; ++i)
#pragma unroll
        for (int j = 0; j < 4; ++j) acc[i][j] += am[i] * wn[j];
    }
    __syncthreads();
  }
#pragma unroll
  for (int i = 0; i < 4; ++i) {
    int m = m0 + tym * 4 + i;
    if (m >= M) continue;
#pragma unroll
    for (int j = 0; j < 4; ++j) {
      int n = n0 + txn * 4 + j;
      if (n >= N) continue;
      float v = acc[i][j];
      if (BIAS) v += bias[n];
      if (GELU) v = gelu_f(v);
      size_t idx = TOUT ? ((size_t)n * ldo + m) : ((size_t)m * ldo + n);
      if (OBF)
        ((bf16_t*)outp)[idx] = f2bf(v);
      else
        ((float*)outp)[idx] = v;
    }
  }
}

// 1600 rows of 4096 contiguous floats, softmax in place
__global__ __launch_bounds__(256) void softmax_rows(float* __restrict__ p) {
  __shared__ float sh[8];
  int tid = threadIdx.x;
  float* base = p + (size_t)blockIdx.x * NN;
  float vals[16];
  float mx = -1e30f;
#pragma unroll
  for (int i = 0; i < 16; ++i) {
    vals[i] = base[tid + i * 256];
    mx = fmaxf(mx, vals[i]);
  }
#pragma unroll
  for (int off = 32; off; off >>= 1) mx = fmaxf(mx, __shfl_xor(mx, off, 64));
  if ((tid & 63) == 0) sh[tid >> 6] = mx;
  __syncthreads();
  mx = fmaxf(fmaxf(sh[0], sh[1]), fmaxf(sh[2], sh[3]));
  float s = 0.f;
#pragma unroll
  for (int i = 0; i < 16; ++i) {
    vals[i] = expf(vals[i] - mx);
    s += vals[i];
  }
#pragma unroll
  for (int off = 32; off; off >>= 1) s += __shfl_xor(s, off, 64);
  if ((tid & 63) == 0) sh[4 + (tid >> 6)] = s;
  __syncthreads();
  s = sh[4] + sh[5] + sh[6] + sh[7];
  float inv = 1.f / s;
#pragma unroll
  for (int i = 0; i < 16; ++i) base[tid + i * 256] = vals[i] * inv;
}

// center[bt][kc][c] = sum_n soft[(kc*16+bt)*4096+n] * xt[bt][n][c]  (xt read from x/mem)
__global__ __launch_bounds__(256) void center_einsum(const float* __restrict__ soft,
                                                     const float* __restrict__ x,
                                                     const float* __restrict__ mem,
                                                     float* __restrict__ center) {
  int bt = blockIdx.x & 15;
  int kg = blockIdx.x >> 4;  // 0..9
  int c = threadIdx.x;
  const float* xbase = xt_base(x, mem, bt);
  __shared__ float sl[10][512];
  float acc[10] = {};
  for (int n0 = 0; n0 < NN; n0 += 512) {
    for (int idx = threadIdx.x; idx < 10 * 512; idx += 256) {
      int n = idx & 511;
      int j = idx >> 9;
      sl[j][n] = soft[((size_t)(kg * 10 + j) * BT + bt) * NN + n0 + n];
    }
    __syncthreads();
    for (int n = 0; n < 512; ++n) {
      float xv = xbase[((size_t)(n0 + n)) * CC + c];
#pragma unroll
      for (int j = 0; j < 10; ++j) acc[j] += sl[j][n] * xv;
    }
    __syncthreads();
  }
#pragma unroll
  for (int j = 0; j < 10; ++j)
    center[((size_t)bt * KCC + kg * 10 + j) * CC + c] = acc[j];
}

// cosine-sim gating + LN -> cin[b][kc][c]
__global__ __launch_bounds__(256) void sim_cin(const float* __restrict__ center,
                                               const float* __restrict__ alpha_p,
                                               const float* __restrict__ beta_p,
                                               const float* __restrict__ lnw,
                                               const float* __restrict__ lnb,
                                               float* __restrict__ cin) {
  int b = blockIdx.x / KCC, kc = blockIdx.x % KCC;
  int c = threadIdx.x;
  float p0 = center[(((size_t)(b * 4 + 0)) * KCC + kc) * CC + c];
  float p1 = center[(((size_t)(b * 4 + 1)) * KCC + kc) * CC + c];
  float p2 = center[(((size_t)(b * 4 + 2)) * KCC + kc) * CC + c];
  float lst = center[(((size_t)(b * 4 + 3)) * KCC + kc) * CC + c];
  float ll = block_sum256(lst * lst);
  float q0 = block_sum256(p0 * p0);
  float q1 = block_sum256(p1 * p1);
  float q2 = block_sum256(p2 * p2);
  float d0 = block_sum256(lst * p0);
  float d1 = block_sum256(lst * p1);
  float d2 = block_sum256(lst * p2);
  float alpha = alpha_p[0], beta = beta_p[0];
  float nl = sqrtf(ll);
  float c0 = 1.f / (1.f + expf(-(beta + alpha * (d0 / fmaxf(nl * sqrtf(q0), 1e-8f)))));
  float c1 = 1.f / (1.f + expf(-(beta + alpha * (d1 / fmaxf(nl * sqrtf(q1), 1e-8f)))));
  float c2 = 1.f / (1.f + expf(-(beta + alpha * (d2 / fmaxf(nl * sqrtf(q2), 1e-8f)))));
  float v = lst + c0 * p0 + c1 * p1 + c2 * p2;
  float m = block_sum256(v) * (1.f / CC);
  float dv = v - m;
  float var = block_sum256(dv * dv) * (1.f / CC);
  cin[((size_t)b * KCC + kc) * CC + c] = dv * rsqrtf(var + 1e-5f) * lnw[c] + lnb[c];
}

// fused attention: one block per (b,n). scores(8x100) -> softmax -> o(256)
__global__ __launch_bounds__(256) void attn_kernel(const float* __restrict__ q,
                                                   const float* __restrict__ kb,
                                                   const float* __restrict__ vb,
                                                   float* __restrict__ ob) {
  int b = blockIdx.x >> 12, n = blockIdx.x & 4095;
  int tid = threadIdx.x;
  __shared__ float qs[CC];
  __shared__ float sc[NHH][KCC + 4];
  qs[tid] = q[((size_t)b * NN + n) * CC + tid] * 0.17677669529663687f;  // hd^-0.5
  __syncthreads();
  if (tid < KCC) {
    const float* krow = kb + ((size_t)b * KCC + tid) * CC;
#pragma unroll
    for (int h = 0; h < NHH; ++h) {
      float s = 0.f;
#pragma unroll
      for (int d = 0; d < HDD; ++d) s += qs[h * HDD + d] * krow[h * HDD + d];
      sc[h][tid] = s;
    }
  }
  __syncthreads();
  int h = tid >> 5, d = tid & 31;
  float mx = -1e30f;
  for (int kc = d; kc < KCC; kc += 32) mx = fmaxf(mx, sc[h][kc]);
#pragma unroll
  for (int off = 16; off; off >>= 1) mx = fmaxf(mx, __shfl_xor(mx, off, 32));
  float sm = 0.f;
  for (int kc = d; kc < KCC; kc += 32) {
    float e = expf(sc[h][kc] - mx);
    sc[h][kc] = e;
    sm += e;
  }
#pragma unroll
  for (int off = 16; off; off >>= 1) sm += __shfl_xor(sm, off, 32);
  __syncthreads();
  float inv = 1.f / sm;
  float o = 0.f;
  const float* vbase = vb + (size_t)b * KCC * CC + tid;
  for (int kc = 0; kc < KCC; ++kc) o += sc[h][kc] * vbase[(size_t)kc * CC];
  ob[((size_t)b * NN + n) * CC + tid] = o * inv;
}

// dst[row][c] = res[row][c] + LN(y[row][:])[c]
__global__ __launch_bounds__(256) void add_ln(const float* __restrict__ res,
                                              const float* __restrict__ y,
                                              const float* __restrict__ lnw,
                                              const float* __restrict__ lnb,
                                              float* __restrict__ dst) {
  size_t row = blockIdx.x;
  int c = threadIdx.x;
  float v = y[row * CC + c];
  float m = block_sum256(v) * (1.f / CC);
  float dv = v - m;
  float var = block_sum256(dv * dv) * (1.f / CC);
  dst[row * CC + c] = res[row * CC + c] + dv * rsqrtf(var + 1e-5f) * lnw[c] + lnb[c];
}

// depthwise 3x3 + bias + gelu, one batch b per launch; y1 bf16 (full), y2c bf16 (chunk)
__global__ __launch_bounds__(256) void dwconv_kernel(const bf16_t* __restrict__ y1,
                                                     const float* __restrict__ dww,
                                                     const float* __restrict__ dwb,
                                                     bf16_t* __restrict__ y2c, int b) {
  int n = blockIdx.x;  // px within this b
  int h = n >> 6, w = n & 63;
  int c40 = threadIdx.x * 4;
  float wreg[4][9];
#pragma unroll
  for (int j = 0; j < 4; ++j)
#pragma unroll
    for (int t2 = 0; t2 < 9; ++t2) wreg[j][t2] = dww[(size_t)(c40 + j) * 9 + t2];
  float acc[4] = {0, 0, 0, 0};
#pragma unroll
  for (int dy = 0; dy < 3; ++dy) {
    int r = h + dy - 1;
    if (r < 0 || r >= HH) continue;
#pragma unroll
    for (int dx = 0; dx < 3; ++dx) {
      int cl = w + dx - 1;
      if (cl < 0 || cl >= 64) continue;
      ushort4 u = *(const ushort4*)(y1 + ((size_t)b * NN + r * 64 + cl) * C4 + c40);
      int t2 = dy * 3 + dx;
      acc[0] += bf2f(u.x) * wreg[0][t2];
      acc[1] += bf2f(u.y) * wreg[1][t2];
      acc[2] += bf2f(u.z) * wreg[2][t2];
      acc[3] += bf2f(u.w) * wreg[3][t2];
    }
  }
  ushort4 o;
  o.x = f2bf(gelu_f(acc[0] + dwb[c40 + 0]));
  o.y = f2bf(gelu_f(acc[1] + dwb[c40 + 1]));
  o.z = f2bf(gelu_f(acc[2] + dwb[c40 + 2]));
  o.w = f2bf(gelu_f(acc[3] + dwb[c40 + 3]));
  *(ushort4*)(y2c + (size_t)n * C4 + c40) = o;
}

extern "C" void kernel_launch(void* const* d_in, const int* in_sizes, int n_in,
                              void* d_out, int out_size, void* d_ws, size_t ws_size,
                              hipStream_t stream) {
  const float* x = (const float*)d_in[0];
  const float* mem = (const float*)d_in[1];
  const float* conv1_w = (const float*)d_in[2];
  const float* conv1_b = (const float*)d_in[3];
  const float* conv2_w = (const float*)d_in[4];
  const float* conv2_b = (const float*)d_in[5];
  const float* conv3_w = (const float*)d_in[6];
  const float* sim_a = (const float*)d_in[7];
  const float* sim_b = (const float*)d_in[8];
  const float* ln_w = (const float*)d_in[9];
  const float* ln_b = (const float*)d_in[10];
  const float* q_w = (const float*)d_in[11];
  const float* q_b = (const float*)d_in[12];
  const float* k_w = (const float*)d_in[13];
  const float* k_b = (const float*)d_in[14];
  const float* v_w = (const float*)d_in[15];
  const float* v_b = (const float*)d_in[16];
  const float* proj_w = (const float*)d_in[17];
  const float* proj_b = (const float*)d_in[18];
  const float* fc1_w = (const float*)d_in[19];
  const float* fc1_b = (const float*)d_in[20];
  const float* dw_w = (const float*)d_in[21];
  const float* dw_b = (const float*)d_in[22];
  const float* fc2_w = (const float*)d_in[23];
  const float* fc2_b = (const float*)d_in[24];

  // Byte-addressed workspace. Peak 96,190,464 B = 91.7 MB (< 104 MB known-good).
  char* base = (char*)d_ws;
  bf16_t* bh1 = (bf16_t*)(base);              // 33,554,432 B [conv1 out bf16]
  float* czt = (float*)(base + 33554432);     // 26,214,400 B [conv3 .. center]
  float* h2c = (float*)(base + 59768832);     // 16,777,216 B [conv2 chunk ping]
  float* outb = (float*)(base + 76546048);    // 16,777,216 B
  float* center = (float*)(base + 93323264);  //  1,638,400 B
  float* cin = (float*)(base + 94961664);     //    409,600 B
  float* kb = (float*)(base + 95371264);      //    409,600 B
  float* vb = (float*)(base + 95780864);      //    409,600 B
  // conv1 staging, aliased over not-yet-live czt/h2c/outb:
  bf16_t* xtb = (bf16_t*)(base + 33554432);   // 33,554,432 B [build_xtb .. conv1]
  bf16_t* wtb = (bf16_t*)(base + 67108864);   // 12,845,056 B [transpose .. conv1]
  // Later-phase aliases (lifetimes verified against launch order):
  float* qb = (float*)(base);        // 16.8 MB; bh1 dead after conv2 chunks
  bf16_t* by1 = (bf16_t*)(base);     // 33.5 MB; qb dead after attn
  float* obuf = czt;                 // 16.8 MB; czt dead after center_einsum
  float* pbuf = h2c;                 // 16.8 MB; h2c dead after conv3 chunks
  bf16_t* y2c = (bf16_t*)h2c;        //  8.4 MB; pbuf dead after add_ln
  float* yout = czt;                 // 16.8 MB; obuf dead after proj
  float* dout = (float*)d_out;

  build_xtb<<<16384, 256, 0, stream>>>(x, mem, xtb);
  transpose_w1b<<<25088, 256, 0, stream>>>(conv1_w, wtb);
  conv1_mfma<<<1024, 256, 0, stream>>>(xtb, wtb, conv1_b, bh1);
  // conv2 (gelu, bf16 A) -> conv3 (transposed store), chunked through h2c (4 x 16384 px)
  for (int i = 0; i < 4; ++i) {
    gemm_nt<1, 1, 0, 1, 0><<<dim3(4, 256), 256, 0, stream>>>(
        bh1 + (size_t)i * 16384 * CC, conv2_w, conv2_b, h2c, 16384, 256, 256, 256);
    gemm_nt<0, 0, 1, 0, 0><<<dim3(2, 256), 256, 0, stream>>>(
        h2c, conv3_w, nullptr, czt + (size_t)i * 16384, 16384, 100, 256, 65536);
  }
  softmax_rows<<<1600, 256, 0, stream>>>(czt);
  center_einsum<<<160, 256, 0, stream>>>(czt, x, mem, center);
  sim_cin<<<400, 256, 0, stream>>>(center, sim_a, sim_b, ln_w, ln_b, cin);
  gemm_nt<0, 1, 0, 0, 0><<<dim3(4, 256), 256, 0, stream>>>(x, q_w, q_b, qb,
                                                           16384, 256, 256, 256);
  gemm_nt<0, 1, 0, 0, 0><<<dim3(4, 7), 256, 0, stream>>>(cin, k_w, k_b, kb,
                                                         400, 256, 256, 256);
  gemm_nt<0, 1, 0, 0, 0><<<dim3(4, 7), 256, 0, stream>>>(cin, v_w, v_b, vb,
                                                         400, 256, 256, 256);
  attn_kernel<<<16384, 256, 0, stream>>>(qb, kb, vb, obuf);
  gemm_nt<0, 1, 0, 0, 0><<<dim3(4, 256), 256, 0, stream>>>(obuf, proj_w, proj_b, pbuf,
                                                           16384, 256, 256, 256);
  add_ln<<<16384, 256, 0, stream>>>(x, pbuf, ln_w, ln_b, outb);
  gemm_nt<0, 1, 0, 0, 1><<<dim3(16, 256), 256, 0, stream>>>(outb, fc1_w, fc1_b, by1,
                                                            16384, 1024, 256, 1024);
  // dwconv (bf16) -> fc2 (bf16 A), chunked per batch b through y2c (8.4 MB)
  for (int b = 0; b < 4; ++b) {
    dwconv_kernel<<<4096, 256, 0, stream>>>(by1, dw_w, dw_b, y2c, b);
    gemm_nt<0, 1, 0, 1, 0><<<dim3(4, 64), 256, 0, stream>>>(
        y2c, fc2_w, fc2_b, yout + (size_t)b * NN * CC, 4096, 256, 1024, 256);
  }
  add_ln<<<16384, 256, 0, stream>>>(outb, yout, ln_w, ln_b, dout);
}

// Round 5
// 1697.359 us; speedup vs baseline: 4.5914x; 1.2296x over previous
//
#include <hip/hip_runtime.h>
#include <math.h>

#define NN 4096
#define CC 256
#define HH 64
#define BT 16
#define KCC 100
#define NHH 8
#define HDD 32
#define C4 1024

typedef unsigned short bf16_t;
typedef short s16x8 __attribute__((ext_vector_type(8)));
typedef float f32x4 __attribute__((ext_vector_type(4)));

__device__ __forceinline__ float bf2f(bf16_t h) {
  return __uint_as_float(((unsigned)h) << 16);
}
__device__ __forceinline__ bf16_t f2bf(float f) {
  unsigned u = __float_as_uint(f);
  return (bf16_t)((u + 0x7FFFu + ((u >> 16) & 1u)) >> 16);
}

__device__ __forceinline__ float gelu_f(float x) {
  return 0.5f * x * (1.0f + erff(x * 0.7071067811865475f));
}

__device__ __forceinline__ float block_sum256(float v) {
  __shared__ float sh[4];
#pragma unroll
  for (int off = 32; off; off >>= 1) v += __shfl_xor(v, off, 64);
  __syncthreads();
  if ((threadIdx.x & 63) == 0) sh[threadIdx.x >> 6] = v;
  __syncthreads();
  return sh[0] + sh[1] + sh[2] + sh[3];
}

__device__ __forceinline__ const float* xt_base(const float* x, const float* mem, int bt) {
  int b = bt >> 2, tt = bt & 3;
  return (tt < 3) ? (mem + (size_t)(b * 3 + tt) * NN * CC)
                  : (x + (size_t)b * NN * CC);
}

// fp32 -> bf16 elementwise
__global__ __launch_bounds__(256) void cvt_bf16(const float* __restrict__ src,
                                                bf16_t* __restrict__ dst, int n) {
  int i = blockIdx.x * 256 + threadIdx.x;
  if (i < n) dst[i] = f2bf(src[i]);
}

// xtb[bt][n][c] bf16 from x/mem fp32
__global__ __launch_bounds__(256) void build_xtb(const float* __restrict__ x,
                                                 const float* __restrict__ mem,
                                                 bf16_t* __restrict__ xtb) {
  int i = blockIdx.x * 256 + threadIdx.x;
  int c4 = i & 63;
  int n = (i >> 6) & 4095;
  int bt = i >> 18;
  const float* src = xt_base(x, mem, bt) + (size_t)n * CC + c4 * 4;
  float4 v = *(const float4*)src;
  ushort4 o;
  o.x = f2bf(v.x); o.y = f2bf(v.y); o.z = f2bf(v.z); o.w = f2bf(v.w);
  *(ushort4*)(xtb + (size_t)i * 4) = o;
}

// wtb layout: [ky][cig(8)][cq(4)][kx(7)][oct(4)][co(64)][cj(8)] bf16
__global__ __launch_bounds__(256) void transpose_w1b(const float* __restrict__ w,
                                                     bf16_t* __restrict__ wtb) {
  int i = blockIdx.x * 256 + threadIdx.x;
  if (i >= 7 * 8 * 4 * 7 * 4 * 64 * 8) return;
  int cj = i & 7;
  int t = i >> 3;
  int co = t & 63; t >>= 6;
  int oc = t & 3; t >>= 2;
  int kx = t % 7; t /= 7;
  int cq = t & 3; t >>= 2;
  int cg = t & 7;
  int ky = t >> 3;
  int ci = cg * 32 + oc * 8 + cj;
  int cog = cq * 64 + co;
  wtb[i] = f2bf(w[((size_t)(cog * CC + ci) * 7 + ky) * 7 + kx]);
}

// conv1 as bf16 MFMA implicit GEMM (unchanged from R4: 640 us, passes)
__global__ __launch_bounds__(256, 3) void conv1_mfma(const bf16_t* __restrict__ xtb,
                                                     const bf16_t* __restrict__ wtb,
                                                     const float* __restrict__ bias,
                                                     bf16_t* __restrict__ h1) {
  int bt = blockIdx.x >> 6;
  int h0 = ((blockIdx.x >> 2) & 15) * 4;
  int cq = blockIdx.x & 3;
  int co0 = cq * 64;
  int tid = threadIdx.x;
  int wv = tid >> 6;
  int lane = tid & 63;
  int lm = lane & 15;
  int g = lane >> 4;
  __shared__ short As[4][4][70][8];
  __shared__ short Ws[7][4][64][8];
  f32x4 acc[4][4] = {};
  const size_t xbase = (size_t)bt * (NN * CC);
  for (int ky = 0; ky < 7; ++ky) {
    int r0 = h0 + ky - 3;
    for (int cig = 0; cig < 8; ++cig) {
      int ci0 = cig * 32;
      for (int idx = tid; idx < 1120; idx += 256) {
        int rr = idx / 280;
        int rem = idx - rr * 280;
        int col = rem >> 2;
        int oc = rem & 3;
        int r = r0 + rr, icol = col - 3;
        s16x8 v = {0, 0, 0, 0, 0, 0, 0, 0};
        if (r >= 0 && r < HH && icol >= 0 && icol < 64)
          v = *(const s16x8*)(xtb + xbase + ((size_t)(r * 64 + icol)) * CC + ci0 + oc * 8);
        *(s16x8*)&As[rr][oc][col][0] = v;
      }
      const bf16_t* wsrc = wtb + ((size_t)((ky * 8 + cig) * 4 + cq)) * (1792 * 8);
      for (int idx = tid; idx < 1792; idx += 256) {
        int kx = idx >> 8;
        int oc = (idx >> 6) & 3;
        int co = idx & 63;
        *(s16x8*)&Ws[kx][oc][co][0] = *(const s16x8*)(wsrc + (size_t)idx * 8);
      }
      __syncthreads();
#pragma unroll
      for (int kx = 0; kx < 7; ++kx) {
        s16x8 af[4], bf[4];
#pragma unroll
        for (int mt = 0; mt < 4; ++mt)
          af[mt] = *(const s16x8*)&As[wv][g][mt * 16 + lm + kx][0];
#pragma unroll
        for (int nt = 0; nt < 4; ++nt)
          bf[nt] = *(const s16x8*)&Ws[kx][g][nt * 16 + lm][0];
#pragma unroll
        for (int mt = 0; mt < 4; ++mt)
#pragma unroll
          for (int nt = 0; nt < 4; ++nt)
            acc[mt][nt] = __builtin_amdgcn_mfma_f32_16x16x32_bf16(af[mt], bf[nt],
                                                                  acc[mt][nt], 0, 0, 0);
      }
      __syncthreads();
    }
  }
  int row = h0 + wv;
#pragma unroll
  for (int nt = 0; nt < 4; ++nt) {
    int co = co0 + nt * 16 + lm;
    float bs = bias[co];
#pragma unroll
    for (int mt = 0; mt < 4; ++mt) {
#pragma unroll
      for (int rg = 0; rg < 4; ++rg) {
        int col = mt * 16 + g * 4 + rg;
        float vv = acc[mt][nt][rg] + bs;
        h1[xbase + (size_t)(row * 64 + col) * CC + co] = f2bf(gelu_f(vv));
      }
    }
  }
}

// bf16 MFMA GEMM: out[m,n] = act(sum_k A[m,k]*W[n,k] + bias[n]).
// A (M x K) bf16, W (N x K) bf16. M must be a multiple of 128. N guarded.
// TOUT: out[n*ldo+m]. OBF: bf16 out. Tile 128x128, 4 waves x (64x64), BK=32.
template <int GELU, int BIAS, int TOUT, int OBF>
__global__ __launch_bounds__(256) void gemm_mfma(const bf16_t* __restrict__ A,
                                                 const bf16_t* __restrict__ W,
                                                 const float* __restrict__ bias,
                                                 void* __restrict__ outp,
                                                 int M, int N, int K, int ldo) {
  __shared__ short As[128][40];  // padded: addr16 stride 5 -> 2-way max on frag reads
  __shared__ short Bs[128][40];
  int tid = threadIdx.x;
  int n0 = blockIdx.x * 128, m0 = blockIdx.y * 128;
  int lane = tid & 63, wv = tid >> 6;
  int wm = wv & 1, wn = wv >> 1;
  int lm = lane & 15, g = lane >> 4;
  f32x4 acc[4][4] = {};
  int r1 = tid >> 2, kq = tid & 3;
  int r2 = r1 + 64;
  for (int k0 = 0; k0 < K; k0 += 32) {
    *(s16x8*)&As[r1][kq * 8] = *(const s16x8*)(A + (size_t)(m0 + r1) * K + k0 + kq * 8);
    *(s16x8*)&As[r2][kq * 8] = *(const s16x8*)(A + (size_t)(m0 + r2) * K + k0 + kq * 8);
    s16x8 z = {0, 0, 0, 0, 0, 0, 0, 0};
    s16x8 b1 = z, b2 = z;
    if (n0 + r1 < N) b1 = *(const s16x8*)(W + (size_t)(n0 + r1) * K + k0 + kq * 8);
    if (n0 + r2 < N) b2 = *(const s16x8*)(W + (size_t)(n0 + r2) * K + k0 + kq * 8);
    *(s16x8*)&Bs[r1][kq * 8] = b1;
    *(s16x8*)&Bs[r2][kq * 8] = b2;
    __syncthreads();
    s16x8 af[4], bf[4];
#pragma unroll
    for (int mt = 0; mt < 4; ++mt)
      af[mt] = *(const s16x8*)&As[wm * 64 + mt * 16 + lm][g * 8];
#pragma unroll
    for (int nt = 0; nt < 4; ++nt)
      bf[nt] = *(const s16x8*)&Bs[wn * 64 + nt * 16 + lm][g * 8];
#pragma unroll
    for (int mt = 0; mt < 4; ++mt)
#pragma unroll
      for (int nt = 0; nt < 4; ++nt)
        acc[mt][nt] = __builtin_amdgcn_mfma_f32_16x16x32_bf16(af[mt], bf[nt],
                                                              acc[mt][nt], 0, 0, 0);
    __syncthreads();
  }
#pragma unroll
  for (int nt = 0; nt < 4; ++nt) {
    int n = n0 + wn * 64 + nt * 16 + lm;
    if (n >= N) continue;
    float bs = BIAS ? bias[n] : 0.f;
#pragma unroll
    for (int mt = 0; mt < 4; ++mt) {
#pragma unroll
      for (int rg = 0; rg < 4; ++rg) {
        int m = m0 + wm * 64 + mt * 16 + g * 4 + rg;
        float v = acc[mt][nt][rg] + bs;
        if (GELU) v = gelu_f(v);
        size_t idx = TOUT ? ((size_t)n * ldo + m) : ((size_t)m * ldo + n);
        if (OBF)
          ((bf16_t*)outp)[idx] = f2bf(v);
        else
          ((float*)outp)[idx] = v;
      }
    }
  }
}

// fp32 gemm for tiny k/v projections (M=400)
template <int GELU, int BIAS>
__global__ __launch_bounds__(256) void gemm_nt(const float* __restrict__ Ap,
                                               const float* __restrict__ Wm,
                                               const float* __restrict__ bias,
                                               float* __restrict__ outp,
                                               int M, int N, int K, int ldo) {
  __shared__ float As[16][68];
  __shared__ float Ws[16][68];
  int tid = threadIdx.x;
  int n0 = blockIdx.x * 64, m0 = blockIdx.y * 64;
  int txn = tid & 15, tym = tid >> 4;
  int mi = tid >> 2, kq = (tid & 3) * 4;
  float acc[4][4] = {};
  for (int k0 = 0; k0 < K; k0 += 16) {
    float4 av = {0, 0, 0, 0}, wvv = {0, 0, 0, 0};
    if (m0 + mi < M) av = *(const float4*)&Ap[(size_t)(m0 + mi) * K + k0 + kq];
    if (n0 + mi < N) wvv = *(const float4*)&Wm[(size_t)(n0 + mi) * K + k0 + kq];
    As[kq + 0][mi] = av.x; As[kq + 1][mi] = av.y; As[kq + 2][mi] = av.z; As[kq + 3][mi] = av.w;
    Ws[kq + 0][mi] = wvv.x; Ws[kq + 1][mi] = wvv.y; Ws[kq + 2][mi] = wvv.z; Ws[kq + 3][mi] = wvv.w;
    __syncthreads();
#pragma unroll
    for (int ki = 0; ki < 16; ++ki) {
      float4 a4 = *(const float4*)&As[ki][tym * 4];
      float4 w4 = *(const float4*)&Ws[ki][txn * 4];
      float am[4] = {a4.x, a4.y, a4.z, a4.w};
      float wn[4] = {w4.x, w4.y, w4.z, w4.w};
#pragma unroll
      for (int i = 0; i < 4; ++i)
#pragma unroll
        for (int j = 0; j < 4; ++j) acc[i][j] += am[i] * wn[j];
    }
    __syncthreads();
  }
#pragma unroll
  for (int i = 0; i < 4; ++i) {
    int m = m0 + tym * 4 + i;
    if (m >= M) continue;
#pragma unroll
    for (int j = 0; j < 4; ++j) {
      int n = n0 + txn * 4 + j;
      if (n >= N) continue;
      float v = acc[i][j];
      if (BIAS) v += bias[n];
      if (GELU) v = gelu_f(v);
      outp[(size_t)m * ldo + n] = v;
    }
  }
}

// 1600 rows of 4096 contiguous bf16, softmax in place
__global__ __launch_bounds__(256) void softmax_rows(bf16_t* __restrict__ p) {
  __shared__ float sh[8];
  int tid = threadIdx.x;
  bf16_t* base = p + (size_t)blockIdx.x * NN;
  float vals[16];
  float mx = -1e30f;
#pragma unroll
  for (int i = 0; i < 16; ++i) {
    vals[i] = bf2f(base[tid + i * 256]);
    mx = fmaxf(mx, vals[i]);
  }
#pragma unroll
  for (int off = 32; off; off >>= 1) mx = fmaxf(mx, __shfl_xor(mx, off, 64));
  if ((tid & 63) == 0) sh[tid >> 6] = mx;
  __syncthreads();
  mx = fmaxf(fmaxf(sh[0], sh[1]), fmaxf(sh[2], sh[3]));
  float s = 0.f;
#pragma unroll
  for (int i = 0; i < 16; ++i) {
    vals[i] = expf(vals[i] - mx);
    s += vals[i];
  }
#pragma unroll
  for (int off = 32; off; off >>= 1) s += __shfl_xor(s, off, 64);
  if ((tid & 63) == 0) sh[4 + (tid >> 6)] = s;
  __syncthreads();
  s = sh[4] + sh[5] + sh[6] + sh[7];
  float inv = 1.f / s;
#pragma unroll
  for (int i = 0; i < 16; ++i) base[tid + i * 256] = f2bf(vals[i] * inv);
}

// center[bt][kc][c] = sum_n soft[(kc*16+bt)*4096+n] * xt[bt][n][c]
__global__ __launch_bounds__(256) void center_einsum(const bf16_t* __restrict__ soft,
                                                     const float* __restrict__ x,
                                                     const float* __restrict__ mem,
                                                     float* __restrict__ center) {
  int bt = blockIdx.x & 15;
  int kg = blockIdx.x >> 4;
  int c = threadIdx.x;
  const float* xbase = xt_base(x, mem, bt);
  __shared__ float sl[10][512];
  float acc[10] = {};
  for (int n0 = 0; n0 < NN; n0 += 512) {
    for (int idx = threadIdx.x; idx < 10 * 512; idx += 256) {
      int n = idx & 511;
      int j = idx >> 9;
      sl[j][n] = bf2f(soft[((size_t)(kg * 10 + j) * BT + bt) * NN + n0 + n]);
    }
    __syncthreads();
    for (int n = 0; n < 512; ++n) {
      float xv = xbase[((size_t)(n0 + n)) * CC + c];
#pragma unroll
      for (int j = 0; j < 10; ++j) acc[j] += sl[j][n] * xv;
    }
    __syncthreads();
  }
#pragma unroll
  for (int j = 0; j < 10; ++j)
    center[((size_t)bt * KCC + kg * 10 + j) * CC + c] = acc[j];
}

// cosine-sim gating + LN -> cin[b][kc][c]
__global__ __launch_bounds__(256) void sim_cin(const float* __restrict__ center,
                                               const float* __restrict__ alpha_p,
                                               const float* __restrict__ beta_p,
                                               const float* __restrict__ lnw,
                                               const float* __restrict__ lnb,
                                               float* __restrict__ cin) {
  int b = blockIdx.x / KCC, kc = blockIdx.x % KCC;
  int c = threadIdx.x;
  float p0 = center[(((size_t)(b * 4 + 0)) * KCC + kc) * CC + c];
  float p1 = center[(((size_t)(b * 4 + 1)) * KCC + kc) * CC + c];
  float p2 = center[(((size_t)(b * 4 + 2)) * KCC + kc) * CC + c];
  float lst = center[(((size_t)(b * 4 + 3)) * KCC + kc) * CC + c];
  float ll = block_sum256(lst * lst);
  float q0 = block_sum256(p0 * p0);
  float q1 = block_sum256(p1 * p1);
  float q2 = block_sum256(p2 * p2);
  float d0 = block_sum256(lst * p0);
  float d1 = block_sum256(lst * p1);
  float d2 = block_sum256(lst * p2);
  float alpha = alpha_p[0], beta = beta_p[0];
  float nl = sqrtf(ll);
  float c0 = 1.f / (1.f + expf(-(beta + alpha * (d0 / fmaxf(nl * sqrtf(q0), 1e-8f)))));
  float c1 = 1.f / (1.f + expf(-(beta + alpha * (d1 / fmaxf(nl * sqrtf(q1), 1e-8f)))));
  float c2 = 1.f / (1.f + expf(-(beta + alpha * (d2 / fmaxf(nl * sqrtf(q2), 1e-8f)))));
  float v = lst + c0 * p0 + c1 * p1 + c2 * p2;
  float m = block_sum256(v) * (1.f / CC);
  float dv = v - m;
  float var = block_sum256(dv * dv) * (1.f / CC);
  cin[((size_t)b * KCC + kc) * CC + c] = dv * rsqrtf(var + 1e-5f) * lnw[c] + lnb[c];
}

// fused attention: one block per (b,n). bf16 output.
__global__ __launch_bounds__(256) void attn_kernel(const float* __restrict__ q,
                                                   const float* __restrict__ kb,
                                                   const float* __restrict__ vb,
                                                   bf16_t* __restrict__ ob) {
  int b = blockIdx.x >> 12, n = blockIdx.x & 4095;
  int tid = threadIdx.x;
  __shared__ float qs[CC];
  __shared__ float sc[NHH][KCC + 4];
  qs[tid] = q[((size_t)b * NN + n) * CC + tid] * 0.17677669529663687f;
  __syncthreads();
  if (tid < KCC) {
    const float* krow = kb + ((size_t)b * KCC + tid) * CC;
#pragma unroll
    for (int h = 0; h < NHH; ++h) {
      float s = 0.f;
#pragma unroll
      for (int d = 0; d < HDD; ++d) s += qs[h * HDD + d] * krow[h * HDD + d];
      sc[h][tid] = s;
    }
  }
  __syncthreads();
  int h = tid >> 5, d = tid & 31;
  float mx = -1e30f;
  for (int kc = d; kc < KCC; kc += 32) mx = fmaxf(mx, sc[h][kc]);
#pragma unroll
  for (int off = 16; off; off >>= 1) mx = fmaxf(mx, __shfl_xor(mx, off, 32));
  float sm = 0.f;
  for (int kc = d; kc < KCC; kc += 32) {
    float e = expf(sc[h][kc] - mx);
    sc[h][kc] = e;
    sm += e;
  }
#pragma unroll
  for (int off = 16; off; off >>= 1) sm += __shfl_xor(sm, off, 32);
  __syncthreads();
  float inv = 1.f / sm;
  float o = 0.f;
  const float* vbase = vb + (size_t)b * KCC * CC + tid;
  for (int kc = 0; kc < KCC; ++kc) o += sc[h][kc] * vbase[(size_t)kc * CC];
  ob[((size_t)b * NN + n) * CC + tid] = f2bf(o * inv);
}

// dst[row][c] = res[row][c] + LN(y[row][:])[c]; WB: also write bf16 copy
template <int WB>
__global__ __launch_bounds__(256) void add_ln(const float* __restrict__ res,
                                              const float* __restrict__ y,
                                              const float* __restrict__ lnw,
                                              const float* __restrict__ lnb,
                                              float* __restrict__ dst,
                                              bf16_t* __restrict__ dst_b) {
  size_t row = blockIdx.x;
  int c = threadIdx.x;
  float v = y[row * CC + c];
  float m = block_sum256(v) * (1.f / CC);
  float dv = v - m;
  float var = block_sum256(dv * dv) * (1.f / CC);
  float o = res[row * CC + c] + dv * rsqrtf(var + 1e-5f) * lnw[c] + lnb[c];
  dst[row * CC + c] = o;
  if (WB) dst_b[row * CC + c] = f2bf(o);
}

// depthwise 3x3 + bias + gelu, one batch b per launch
__global__ __launch_bounds__(256) void dwconv_kernel(const bf16_t* __restrict__ y1,
                                                     const float* __restrict__ dww,
                                                     const float* __restrict__ dwb,
                                                     bf16_t* __restrict__ y2c, int b) {
  int n = blockIdx.x;
  int h = n >> 6, w = n & 63;
  int c40 = threadIdx.x * 4;
  float wreg[4][9];
#pragma unroll
  for (int j = 0; j < 4; ++j)
#pragma unroll
    for (int t2 = 0; t2 < 9; ++t2) wreg[j][t2] = dww[(size_t)(c40 + j) * 9 + t2];
  float acc[4] = {0, 0, 0, 0};
#pragma unroll
  for (int dy = 0; dy < 3; ++dy) {
    int r = h + dy - 1;
    if (r < 0 || r >= HH) continue;
#pragma unroll
    for (int dx = 0; dx < 3; ++dx) {
      int cl = w + dx - 1;
      if (cl < 0 || cl >= 64) continue;
      ushort4 u = *(const ushort4*)(y1 + ((size_t)b * NN + r * 64 + cl) * C4 + c40);
      int t2 = dy * 3 + dx;
      acc[0] += bf2f(u.x) * wreg[0][t2];
      acc[1] += bf2f(u.y) * wreg[1][t2];
      acc[2] += bf2f(u.z) * wreg[2][t2];
      acc[3] += bf2f(u.w) * wreg[3][t2];
    }
  }
  ushort4 o;
  o.x = f2bf(gelu_f(acc[0] + dwb[c40 + 0]));
  o.y = f2bf(gelu_f(acc[1] + dwb[c40 + 1]));
  o.z = f2bf(gelu_f(acc[2] + dwb[c40 + 2]));
  o.w = f2bf(gelu_f(acc[3] + dwb[c40 + 3]));
  *(ushort4*)(y2c + (size_t)n * C4 + c40) = o;
}

extern "C" void kernel_launch(void* const* d_in, const int* in_sizes, int n_in,
                              void* d_out, int out_size, void* d_ws, size_t ws_size,
                              hipStream_t stream) {
  const float* x = (const float*)d_in[0];
  const float* mem = (const float*)d_in[1];
  const float* conv1_w = (const float*)d_in[2];
  const float* conv1_b = (const float*)d_in[3];
  const float* conv2_w = (const float*)d_in[4];
  const float* conv2_b = (const float*)d_in[5];
  const float* conv3_w = (const float*)d_in[6];
  const float* sim_a = (const float*)d_in[7];
  const float* sim_b = (const float*)d_in[8];
  const float* ln_w = (const float*)d_in[9];
  const float* ln_b = (const float*)d_in[10];
  const float* q_w = (const float*)d_in[11];
  const float* q_b = (const float*)d_in[12];
  const float* k_w = (const float*)d_in[13];
  const float* k_b = (const float*)d_in[14];
  const float* v_w = (const float*)d_in[15];
  const float* v_b = (const float*)d_in[16];
  const float* proj_w = (const float*)d_in[17];
  const float* proj_b = (const float*)d_in[18];
  const float* fc1_w = (const float*)d_in[19];
  const float* fc1_b = (const float*)d_in[20];
  const float* dw_w = (const float*)d_in[21];
  const float* dw_b = (const float*)d_in[22];
  const float* fc2_w = (const float*)d_in[23];
  const float* fc2_b = (const float*)d_in[24];

  // Workspace: 93,044,736 B = 88.7 MB (< 104 MB known-good). Regions w/ lifetimes:
  char* base = (char*)d_ws;
  // R0 [0,33.5M): xtb [build..q-gemm] -> by1 [fc1..dwconv]
  bf16_t* xtb = (bf16_t*)(base);
  bf16_t* by1 = (bf16_t*)(base);
  // R1 [33.5M,67.1M): bh1 [conv1..conv2] -> qb@+0 [q..attn] -> outb@+0 [addln1..end]
  //                   pbuf@+16.8M [proj..addln1] -> yout@+16.8M [fc2..addln2]
  bf16_t* bh1 = (bf16_t*)(base + 33554432);
  float* qb = (float*)(base + 33554432);
  float* outb = (float*)(base + 33554432);
  float* pbuf = (float*)(base + 50331648);
  float* yout = (float*)(base + 50331648);
  // R2 [67.1M,80.2M): czt bf16 [conv3..center] -> obz [attn..proj] -> outb_b [addln1..fc1]
  bf16_t* czt = (bf16_t*)(base + 67108864);
  bf16_t* obz = (bf16_t*)(base + 67108864);
  bf16_t* outb_b = (bf16_t*)(base + 67108864);
  // R3 [80.2M,88.6M): wtb(6.4M) [..conv1] -> h2c bf16 [conv2..conv3] -> y2c [dw..fc2]
  bf16_t* wtb = (bf16_t*)(base + 80216064);
  bf16_t* h2c = (bf16_t*)(base + 80216064);
  bf16_t* y2c = (bf16_t*)(base + 80216064);
  // R4 small
  bf16_t* wbz = (bf16_t*)(base + 88604672);       // 1.5 MB packed bf16 weights
  float* center = (float*)(base + 90177536);      // 1.6 MB
  float* cin = (float*)(base + 91815936);
  float* kb = (float*)(base + 92225536);
  float* vb = (float*)(base + 92635136);
  float* dout = (float*)d_out;

  // packed bf16 weight offsets (elements)
  bf16_t* conv2_wb = wbz;            // 65536
  bf16_t* conv3_wb = wbz + 65536;    // 25600
  bf16_t* q_wb = wbz + 91136;        // 65536
  bf16_t* proj_wb = wbz + 156672;    // 65536
  bf16_t* fc1_wb = wbz + 222208;     // 262144
  bf16_t* fc2_wb = wbz + 484352;     // 262144

  cvt_bf16<<<256, 256, 0, stream>>>(conv2_w, conv2_wb, 65536);
  cvt_bf16<<<100, 256, 0, stream>>>(conv3_w, conv3_wb, 25600);
  cvt_bf16<<<256, 256, 0, stream>>>(q_w, q_wb, 65536);
  cvt_bf16<<<256, 256, 0, stream>>>(proj_w, proj_wb, 65536);
  cvt_bf16<<<1024, 256, 0, stream>>>(fc1_w, fc1_wb, 262144);
  cvt_bf16<<<1024, 256, 0, stream>>>(fc2_w, fc2_wb, 262144);
  build_xtb<<<16384, 256, 0, stream>>>(x, mem, xtb);
  transpose_w1b<<<25088, 256, 0, stream>>>(conv1_w, wtb);
  conv1_mfma<<<1024, 256, 0, stream>>>(xtb, wtb, conv1_b, bh1);
  // conv2 (gelu, bf16 out) -> conv3 (transposed bf16 store), chunked (4 x 16384 px)
  for (int i = 0; i < 4; ++i) {
    gemm_mfma<1, 1, 0, 1><<<dim3(2, 128), 256, 0, stream>>>(
        bh1 + (size_t)i * 16384 * CC, conv2_wb, conv2_b, h2c, 16384, 256, 256, 256);
    gemm_mfma<0, 0, 1, 1><<<dim3(1, 128), 256, 0, stream>>>(
        h2c, conv3_wb, nullptr, czt + (size_t)i * 16384, 16384, 100, 256, 65536);
  }
  softmax_rows<<<1600, 256, 0, stream>>>(czt);
  center_einsum<<<160, 256, 0, stream>>>(czt, x, mem, center);
  sim_cin<<<400, 256, 0, stream>>>(center, sim_a, sim_b, ln_w, ln_b, cin);
  // q = x @ q_w^T + q_b, using xtb slabs (bt = 4b+3), M=4096 per b
  for (int b = 0; b < 4; ++b) {
    gemm_mfma<0, 1, 0, 0><<<dim3(2, 32), 256, 0, stream>>>(
        xtb + (size_t)(b * 4 + 3) * NN * CC, q_wb, q_b,
        qb + (size_t)b * NN * CC, 4096, 256, 256, 256);
  }
  gemm_nt<0, 1><<<dim3(4, 7), 256, 0, stream>>>(cin, k_w, k_b, kb, 400, 256, 256, 256);
  gemm_nt<0, 1><<<dim3(4, 7), 256, 0, stream>>>(cin, v_w, v_b, vb, 400, 256, 256, 256);
  attn_kernel<<<16384, 256, 0, stream>>>(qb, kb, vb, obz);
  gemm_mfma<0, 1, 0, 0><<<dim3(2, 128), 256, 0, stream>>>(obz, proj_wb, proj_b, pbuf,
                                                          16384, 256, 256, 256);
  add_ln<1><<<16384, 256, 0, stream>>>(x, pbuf, ln_w, ln_b, outb, outb_b);
  gemm_mfma<0, 1, 0, 1><<<dim3(8, 128), 256, 0, stream>>>(outb_b, fc1_wb, fc1_b, by1,
                                                          16384, 1024, 256, 1024);
  // dwconv (bf16) -> fc2, chunked per batch b
  for (int b = 0; b < 4; ++b) {
    dwconv_kernel<<<4096, 256, 0, stream>>>(by1, dw_w, dw_b, y2c, b);
    gemm_mfma<0, 1, 0, 0><<<dim3(2, 32), 256, 0, stream>>>(
        y2c, fc2_wb, fc2_b, yout + (size_t)b * NN * CC, 4096, 256, 1024, 256);
  }
  add_ln<0><<<16384, 256, 0, stream>>>(outb, yout, ln_w, ln_b, dout, nullptr);
}

// Round 6
// 1372.535 us; speedup vs baseline: 5.6780x; 1.2367x over previous
//
#include <hip/hip_runtime.h>
#include <math.h>

#define NN 4096
#define CC 256
#define HH 64
#define BT 16
#define KCC 100
#define NHH 8
#define HDD 32
#define C4 1024

typedef unsigned short bf16_t;
typedef short s16x8 __attribute__((ext_vector_type(8)));
typedef float f32x4 __attribute__((ext_vector_type(4)));

__device__ __forceinline__ float bf2f(bf16_t h) {
  return __uint_as_float(((unsigned)h) << 16);
}
__device__ __forceinline__ bf16_t f2bf(float f) {
  unsigned u = __float_as_uint(f);
  return (bf16_t)((u + 0x7FFFu + ((u >> 16) & 1u)) >> 16);
}

__device__ __forceinline__ float gelu_f(float x) {
  return 0.5f * x * (1.0f + erff(x * 0.7071067811865475f));
}

__device__ __forceinline__ float block_sum256(float v) {
  __shared__ float sh[4];
#pragma unroll
  for (int off = 32; off; off >>= 1) v += __shfl_xor(v, off, 64);
  __syncthreads();
  if ((threadIdx.x & 63) == 0) sh[threadIdx.x >> 6] = v;
  __syncthreads();
  return sh[0] + sh[1] + sh[2] + sh[3];
}

__device__ __forceinline__ const float* xt_base(const float* x, const float* mem, int bt) {
  int b = bt >> 2, tt = bt & 3;
  return (tt < 3) ? (mem + (size_t)(b * 3 + tt) * NN * CC)
                  : (x + (size_t)b * NN * CC);
}

__global__ __launch_bounds__(256) void cvt_bf16(const float* __restrict__ src,
                                                bf16_t* __restrict__ dst, int n) {
  int i = blockIdx.x * 256 + threadIdx.x;
  if (i < n) dst[i] = f2bf(src[i]);
}

// xtb[bt][n][c] bf16 from x/mem fp32
__global__ __launch_bounds__(256) void build_xtb(const float* __restrict__ x,
                                                 const float* __restrict__ mem,
                                                 bf16_t* __restrict__ xtb) {
  int i = blockIdx.x * 256 + threadIdx.x;
  int c4 = i & 63;
  int n = (i >> 6) & 4095;
  int bt = i >> 18;
  const float* src = xt_base(x, mem, bt) + (size_t)n * CC + c4 * 4;
  float4 v = *(const float4*)src;
  ushort4 o;
  o.x = f2bf(v.x); o.y = f2bf(v.y); o.z = f2bf(v.z); o.w = f2bf(v.w);
  *(ushort4*)(xtb + (size_t)i * 4) = o;
}

// wtb layout: [ky][cig(8)][cq(4)][kx(7)][oct(4)][co(64)][cj(8)] bf16
__global__ __launch_bounds__(256) void transpose_w1b(const float* __restrict__ w,
                                                     bf16_t* __restrict__ wtb) {
  int i = blockIdx.x * 256 + threadIdx.x;
  if (i >= 7 * 8 * 4 * 7 * 4 * 64 * 8) return;
  int cj = i & 7;
  int t = i >> 3;
  int co = t & 63; t >>= 6;
  int oc = t & 3; t >>= 2;
  int kx = t % 7; t /= 7;
  int cq = t & 3; t >>= 2;
  int cg = t & 7;
  int ky = t >> 3;
  int ci = cg * 32 + oc * 8 + cj;
  int cog = cq * 64 + co;
  wtb[i] = f2bf(w[((size_t)(cog * CC + ci) * 7 + ky) * 7 + kx]);
}

// conv1 as bf16 MFMA implicit GEMM (unchanged: ~580 us, verified)
__global__ __launch_bounds__(256, 3) void conv1_mfma(const bf16_t* __restrict__ xtb,
                                                     const bf16_t* __restrict__ wtb,
                                                     const float* __restrict__ bias,
                                                     bf16_t* __restrict__ h1) {
  int bt = blockIdx.x >> 6;
  int h0 = ((blockIdx.x >> 2) & 15) * 4;
  int cq = blockIdx.x & 3;
  int co0 = cq * 64;
  int tid = threadIdx.x;
  int wv = tid >> 6;
  int lane = tid & 63;
  int lm = lane & 15;
  int g = lane >> 4;
  __shared__ short As[4][4][70][8];
  __shared__ short Ws[7][4][64][8];
  f32x4 acc[4][4] = {};
  const size_t xbase = (size_t)bt * (NN * CC);
  for (int ky = 0; ky < 7; ++ky) {
    int r0 = h0 + ky - 3;
    for (int cig = 0; cig < 8; ++cig) {
      int ci0 = cig * 32;
      for (int idx = tid; idx < 1120; idx += 256) {
        int rr = idx / 280;
        int rem = idx - rr * 280;
        int col = rem >> 2;
        int oc = rem & 3;
        int r = r0 + rr, icol = col - 3;
        s16x8 v = {0, 0, 0, 0, 0, 0, 0, 0};
        if (r >= 0 && r < HH && icol >= 0 && icol < 64)
          v = *(const s16x8*)(xtb + xbase + ((size_t)(r * 64 + icol)) * CC + ci0 + oc * 8);
        *(s16x8*)&As[rr][oc][col][0] = v;
      }
      const bf16_t* wsrc = wtb + ((size_t)((ky * 8 + cig) * 4 + cq)) * (1792 * 8);
      for (int idx = tid; idx < 1792; idx += 256) {
        int kx = idx >> 8;
        int oc = (idx >> 6) & 3;
        int co = idx & 63;
        *(s16x8*)&Ws[kx][oc][co][0] = *(const s16x8*)(wsrc + (size_t)idx * 8);
      }
      __syncthreads();
#pragma unroll
      for (int kx = 0; kx < 7; ++kx) {
        s16x8 af[4], bf[4];
#pragma unroll
        for (int mt = 0; mt < 4; ++mt)
          af[mt] = *(const s16x8*)&As[wv][g][mt * 16 + lm + kx][0];
#pragma unroll
        for (int nt = 0; nt < 4; ++nt)
          bf[nt] = *(const s16x8*)&Ws[kx][g][nt * 16 + lm][0];
#pragma unroll
        for (int mt = 0; mt < 4; ++mt)
#pragma unroll
          for (int nt = 0; nt < 4; ++nt)
            acc[mt][nt] = __builtin_amdgcn_mfma_f32_16x16x32_bf16(af[mt], bf[nt],
                                                                  acc[mt][nt], 0, 0, 0);
      }
      __syncthreads();
    }
  }
  int row = h0 + wv;
#pragma unroll
  for (int nt = 0; nt < 4; ++nt) {
    int co = co0 + nt * 16 + lm;
    float bs = bias[co];
#pragma unroll
    for (int mt = 0; mt < 4; ++mt) {
#pragma unroll
      for (int rg = 0; rg < 4; ++rg) {
        int col = mt * 16 + g * 4 + rg;
        float vv = acc[mt][nt][rg] + bs;
        h1[xbase + (size_t)(row * 64 + col) * CC + co] = f2bf(gelu_f(vv));
      }
    }
  }
}

// bf16 MFMA GEMM with optional z-slab batching: A += z*aStr (elems), out idx += z*oStr.
template <int GELU, int BIAS, int TOUT, int OBF>
__global__ __launch_bounds__(256) void gemm_mfma(const bf16_t* __restrict__ A,
                                                 const bf16_t* __restrict__ W,
                                                 const float* __restrict__ bias,
                                                 void* __restrict__ outp,
                                                 int M, int N, int K, int ldo,
                                                 size_t aStr, size_t oStr) {
  __shared__ short As[128][40];
  __shared__ short Bs[128][40];
  A += (size_t)blockIdx.z * aStr;
  size_t obase = (size_t)blockIdx.z * oStr;
  int tid = threadIdx.x;
  int n0 = blockIdx.x * 128, m0 = blockIdx.y * 128;
  int lane = tid & 63, wv = tid >> 6;
  int wm = wv & 1, wn = wv >> 1;
  int lm = lane & 15, g = lane >> 4;
  f32x4 acc[4][4] = {};
  int r1 = tid >> 2, kq = tid & 3;
  int r2 = r1 + 64;
  for (int k0 = 0; k0 < K; k0 += 32) {
    *(s16x8*)&As[r1][kq * 8] = *(const s16x8*)(A + (size_t)(m0 + r1) * K + k0 + kq * 8);
    *(s16x8*)&As[r2][kq * 8] = *(const s16x8*)(A + (size_t)(m0 + r2) * K + k0 + kq * 8);
    s16x8 z = {0, 0, 0, 0, 0, 0, 0, 0};
    s16x8 b1 = z, b2 = z;
    if (n0 + r1 < N) b1 = *(const s16x8*)(W + (size_t)(n0 + r1) * K + k0 + kq * 8);
    if (n0 + r2 < N) b2 = *(const s16x8*)(W + (size_t)(n0 + r2) * K + k0 + kq * 8);
    *(s16x8*)&Bs[r1][kq * 8] = b1;
    *(s16x8*)&Bs[r2][kq * 8] = b2;
    __syncthreads();
    s16x8 af[4], bf[4];
#pragma unroll
    for (int mt = 0; mt < 4; ++mt)
      af[mt] = *(const s16x8*)&As[wm * 64 + mt * 16 + lm][g * 8];
#pragma unroll
    for (int nt = 0; nt < 4; ++nt)
      bf[nt] = *(const s16x8*)&Bs[wn * 64 + nt * 16 + lm][g * 8];
#pragma unroll
    for (int mt = 0; mt < 4; ++mt)
#pragma unroll
      for (int nt = 0; nt < 4; ++nt)
        acc[mt][nt] = __builtin_amdgcn_mfma_f32_16x16x32_bf16(af[mt], bf[nt],
                                                              acc[mt][nt], 0, 0, 0);
    __syncthreads();
  }
#pragma unroll
  for (int nt = 0; nt < 4; ++nt) {
    int n = n0 + wn * 64 + nt * 16 + lm;
    if (n >= N) continue;
    float bs = BIAS ? bias[n] : 0.f;
#pragma unroll
    for (int mt = 0; mt < 4; ++mt) {
#pragma unroll
      for (int rg = 0; rg < 4; ++rg) {
        int m = m0 + wm * 64 + mt * 16 + g * 4 + rg;
        float v = acc[mt][nt][rg] + bs;
        if (GELU) v = gelu_f(v);
        size_t idx = obase + (TOUT ? ((size_t)n * ldo + m) : ((size_t)m * ldo + n));
        if (OBF)
          ((bf16_t*)outp)[idx] = f2bf(v);
        else
          ((float*)outp)[idx] = v;
      }
    }
  }
}

// fp32 gemm for tiny k/v projections (M=400)
template <int GELU, int BIAS>
__global__ __launch_bounds__(256) void gemm_nt(const float* __restrict__ Ap,
                                               const float* __restrict__ Wm,
                                               const float* __restrict__ bias,
                                               float* __restrict__ outp,
                                               int M, int N, int K, int ldo) {
  __shared__ float As[16][68];
  __shared__ float Ws[16][68];
  int tid = threadIdx.x;
  int n0 = blockIdx.x * 64, m0 = blockIdx.y * 64;
  int txn = tid & 15, tym = tid >> 4;
  int mi = tid >> 2, kq = (tid & 3) * 4;
  float acc[4][4] = {};
  for (int k0 = 0; k0 < K; k0 += 16) {
    float4 av = {0, 0, 0, 0}, wvv = {0, 0, 0, 0};
    if (m0 + mi < M) av = *(const float4*)&Ap[(size_t)(m0 + mi) * K + k0 + kq];
    if (n0 + mi < N) wvv = *(const float4*)&Wm[(size_t)(n0 + mi) * K + k0 + kq];
    As[kq + 0][mi] = av.x; As[kq + 1][mi] = av.y; As[kq + 2][mi] = av.z; As[kq + 3][mi] = av.w;
    Ws[kq + 0][mi] = wvv.x; Ws[kq + 1][mi] = wvv.y; Ws[kq + 2][mi] = wvv.z; Ws[kq + 3][mi] = wvv.w;
    __syncthreads();
#pragma unroll
    for (int ki = 0; ki < 16; ++ki) {
      float4 a4 = *(const float4*)&As[ki][tym * 4];
      float4 w4 = *(const float4*)&Ws[ki][txn * 4];
      float am[4] = {a4.x, a4.y, a4.z, a4.w};
      float wn[4] = {w4.x, w4.y, w4.z, w4.w};
#pragma unroll
      for (int i = 0; i < 4; ++i)
#pragma unroll
        for (int j = 0; j < 4; ++j) acc[i][j] += am[i] * wn[j];
    }
    __syncthreads();
  }
#pragma unroll
  for (int i = 0; i < 4; ++i) {
    int m = m0 + tym * 4 + i;
    if (m >= M) continue;
#pragma unroll
    for (int j = 0; j < 4; ++j) {
      int n = n0 + txn * 4 + j;
      if (n >= N) continue;
      float v = acc[i][j];
      if (BIAS) v += bias[n];
      if (GELU) v = gelu_f(v);
      outp[(size_t)m * ldo + n] = v;
    }
  }
}

// 1600 rows of 4096 contiguous bf16, softmax in place
__global__ __launch_bounds__(256) void softmax_rows(bf16_t* __restrict__ p) {
  __shared__ float sh[8];
  int tid = threadIdx.x;
  bf16_t* base = p + (size_t)blockIdx.x * NN;
  float vals[16];
  float mx = -1e30f;
#pragma unroll
  for (int i = 0; i < 16; ++i) {
    vals[i] = bf2f(base[tid + i * 256]);
    mx = fmaxf(mx, vals[i]);
  }
#pragma unroll
  for (int off = 32; off; off >>= 1) mx = fmaxf(mx, __shfl_xor(mx, off, 64));
  if ((tid & 63) == 0) sh[tid >> 6] = mx;
  __syncthreads();
  mx = fmaxf(fmaxf(sh[0], sh[1]), fmaxf(sh[2], sh[3]));
  float s = 0.f;
#pragma unroll
  for (int i = 0; i < 16; ++i) {
    vals[i] = expf(vals[i] - mx);
    s += vals[i];
  }
#pragma unroll
  for (int off = 32; off; off >>= 1) s += __shfl_xor(s, off, 64);
  if ((tid & 63) == 0) sh[4 + (tid >> 6)] = s;
  __syncthreads();
  s = sh[4] + sh[5] + sh[6] + sh[7];
  float inv = 1.f / s;
#pragma unroll
  for (int i = 0; i < 16; ++i) base[tid + i * 256] = f2bf(vals[i] * inv);
}

// partial[nc][bt][kc][c] = sum over n-chunk nc of soft * xtb
__global__ __launch_bounds__(256) void center_einsum2(const bf16_t* __restrict__ soft,
                                                      const bf16_t* __restrict__ xtb,
                                                      float* __restrict__ partial) {
  int bt = blockIdx.x, kg = blockIdx.y, nc = blockIdx.z;
  int c = threadIdx.x;
  __shared__ float sl[10][512];
  float acc[10] = {};
  for (int n0 = nc * 1024; n0 < nc * 1024 + 1024; n0 += 512) {
    for (int idx = threadIdx.x; idx < 5120; idx += 256) {
      int n = idx & 511;
      int j = idx >> 9;
      sl[j][n] = bf2f(soft[((size_t)(kg * 10 + j) * BT + bt) * NN + n0 + n]);
    }
    __syncthreads();
    for (int n = 0; n < 512; ++n) {
      float xv = bf2f(xtb[((size_t)bt * NN + n0 + n) * CC + c]);
#pragma unroll
      for (int j = 0; j < 10; ++j) acc[j] += sl[j][n] * xv;
    }
    __syncthreads();
  }
#pragma unroll
  for (int j = 0; j < 10; ++j)
    partial[(((size_t)nc * BT + bt) * KCC + kg * 10 + j) * CC + c] = acc[j];
}

// cosine-sim gating + LN -> cin[b][kc][c]; reduces 4 n-chunk partials
__global__ __launch_bounds__(256) void sim_cin(const float* __restrict__ partial,
                                               const float* __restrict__ alpha_p,
                                               const float* __restrict__ beta_p,
                                               const float* __restrict__ lnw,
                                               const float* __restrict__ lnb,
                                               float* __restrict__ cin) {
  int b = blockIdx.x / KCC, kc = blockIdx.x % KCC;
  int c = threadIdx.x;
  float p0 = 0.f, p1 = 0.f, p2 = 0.f, lst = 0.f;
#pragma unroll
  for (int nc = 0; nc < 4; ++nc) {
    size_t base = ((size_t)nc * BT) * KCC * CC;
    p0 += partial[base + ((size_t)(b * 4 + 0) * KCC + kc) * CC + c];
    p1 += partial[base + ((size_t)(b * 4 + 1) * KCC + kc) * CC + c];
    p2 += partial[base + ((size_t)(b * 4 + 2) * KCC + kc) * CC + c];
    lst += partial[base + ((size_t)(b * 4 + 3) * KCC + kc) * CC + c];
  }
  float ll = block_sum256(lst * lst);
  float q0 = block_sum256(p0 * p0);
  float q1 = block_sum256(p1 * p1);
  float q2 = block_sum256(p2 * p2);
  float d0 = block_sum256(lst * p0);
  float d1 = block_sum256(lst * p1);
  float d2 = block_sum256(lst * p2);
  float alpha = alpha_p[0], beta = beta_p[0];
  float nl = sqrtf(ll);
  float c0 = 1.f / (1.f + expf(-(beta + alpha * (d0 / fmaxf(nl * sqrtf(q0), 1e-8f)))));
  float c1 = 1.f / (1.f + expf(-(beta + alpha * (d1 / fmaxf(nl * sqrtf(q1), 1e-8f)))));
  float c2 = 1.f / (1.f + expf(-(beta + alpha * (d2 / fmaxf(nl * sqrtf(q2), 1e-8f)))));
  float v = lst + c0 * p0 + c1 * p1 + c2 * p2;
  float m = block_sum256(v) * (1.f / CC);
  float dv = v - m;
  float var = block_sum256(dv * dv) * (1.f / CC);
  cin[((size_t)b * KCC + kc) * CC + c] = dv * rsqrtf(var + 1e-5f) * lnw[c] + lnb[c];
}

// attention v2: block = (8 query rows, b). K tiled through LDS, V read once.
__global__ __launch_bounds__(256) void attn2(const float* __restrict__ q,
                                             const float* __restrict__ kb,
                                             const float* __restrict__ vb,
                                             bf16_t* __restrict__ ob) {
  int b = blockIdx.y;
  int n0 = blockIdx.x * 8;
  int tid = threadIdx.x;
  __shared__ float qs[8][256];
  __shared__ float Ks[32][257];
  __shared__ float sc[8][8][104];
#pragma unroll
  for (int r = 0; r < 8; ++r)
    qs[r][tid] = q[((size_t)b * NN + n0 + r) * CC + tid] * 0.17677669529663687f;
  int nn = tid >> 5, kcl = tid & 31;
  for (int kt = 0; kt < 4; ++kt) {
    int kbase = kt * 32;
    int rows = (kbase + 32 <= KCC) ? 32 : (KCC - kbase);
    __syncthreads();  // qs ready (kt=0) / prior readers of Ks done
    for (int idx = tid; idx < rows * 256; idx += 256) {
      int rr = idx >> 8, cc = idx & 255;
      Ks[rr][cc] = kb[((size_t)b * KCC + kbase + rr) * CC + cc];
    }
    __syncthreads();
    if (kcl < rows) {
#pragma unroll
      for (int h = 0; h < NHH; ++h) {
        float s = 0.f;
#pragma unroll
        for (int d = 0; d < HDD; ++d) s += qs[nn][h * HDD + d] * Ks[kcl][h * HDD + d];
        sc[nn][h][kbase + kcl] = s;
      }
    }
  }
  __syncthreads();
  // softmax per (nn,h) row: threads (nn, h, j) each own 25 kc
  {
    int tnn = tid >> 5, th = (tid >> 2) & 7, j = tid & 3;
    float mx = -1e30f;
    for (int kc = j * 25; kc < j * 25 + 25; ++kc) mx = fmaxf(mx, sc[tnn][th][kc]);
    mx = fmaxf(mx, __shfl_xor(mx, 1, 64));
    mx = fmaxf(mx, __shfl_xor(mx, 2, 64));
    float sm = 0.f;
    for (int kc = j * 25; kc < j * 25 + 25; ++kc) {
      float e = expf(sc[tnn][th][kc] - mx);
      sc[tnn][th][kc] = e;
      sm += e;
    }
    sm += __shfl_xor(sm, 1, 64);
    sm += __shfl_xor(sm, 2, 64);
    float inv = 1.f / sm;
    for (int kc = j * 25; kc < j * 25 + 25; ++kc) sc[tnn][th][kc] *= inv;
  }
  __syncthreads();
  // PV: thread = channel c; V row read once, reused for 8 n
  float o[8] = {0, 0, 0, 0, 0, 0, 0, 0};
  int h = tid >> 5;
  for (int kc = 0; kc < KCC; ++kc) {
    float v = vb[((size_t)b * KCC + kc) * CC + tid];
#pragma unroll
    for (int r = 0; r < 8; ++r) o[r] += sc[r][h][kc] * v;
  }
#pragma unroll
  for (int r = 0; r < 8; ++r)
    ob[((size_t)b * NN + n0 + r) * CC + tid] = f2bf(o[r]);
}

// dst[row][c] = res[row][c] + LN(y[row][:])[c]; WB: also write bf16 copy
template <int WB>
__global__ __launch_bounds__(256) void add_ln(const float* __restrict__ res,
                                              const float* __restrict__ y,
                                              const float* __restrict__ lnw,
                                              const float* __restrict__ lnb,
                                              float* __restrict__ dst,
                                              bf16_t* __restrict__ dst_b) {
  size_t row = blockIdx.x;
  int c = threadIdx.x;
  float v = y[row * CC + c];
  float m = block_sum256(v) * (1.f / CC);
  float dv = v - m;
  float var = block_sum256(dv * dv) * (1.f / CC);
  float o = res[row * CC + c] + dv * rsqrtf(var + 1e-5f) * lnw[c] + lnb[c];
  dst[row * CC + c] = o;
  if (WB) dst_b[row * CC + c] = f2bf(o);
}

// depthwise 3x3 + bias + gelu, 2 batches per launch (b = b0 + blockIdx.x>>12)
__global__ __launch_bounds__(256) void dwconv_kernel(const bf16_t* __restrict__ y1,
                                                     const float* __restrict__ dww,
                                                     const float* __restrict__ dwb,
                                                     bf16_t* __restrict__ y2c, int b0) {
  int bb = blockIdx.x >> 12;
  int n = blockIdx.x & 4095;
  int b = b0 + bb;
  int h = n >> 6, w = n & 63;
  int c40 = threadIdx.x * 4;
  float wreg[4][9];
#pragma unroll
  for (int j = 0; j < 4; ++j)
#pragma unroll
    for (int t2 = 0; t2 < 9; ++t2) wreg[j][t2] = dww[(size_t)(c40 + j) * 9 + t2];
  float acc[4] = {0, 0, 0, 0};
#pragma unroll
  for (int dy = 0; dy < 3; ++dy) {
    int r = h + dy - 1;
    if (r < 0 || r >= HH) continue;
#pragma unroll
    for (int dx = 0; dx < 3; ++dx) {
      int cl = w + dx - 1;
      if (cl < 0 || cl >= 64) continue;
      ushort4 u = *(const ushort4*)(y1 + ((size_t)b * NN + r * 64 + cl) * C4 + c40);
      int t2 = dy * 3 + dx;
      acc[0] += bf2f(u.x) * wreg[0][t2];
      acc[1] += bf2f(u.y) * wreg[1][t2];
      acc[2] += bf2f(u.z) * wreg[2][t2];
      acc[3] += bf2f(u.w) * wreg[3][t2];
    }
  }
  ushort4 o;
  o.x = f2bf(gelu_f(acc[0] + dwb[c40 + 0]));
  o.y = f2bf(gelu_f(acc[1] + dwb[c40 + 1]));
  o.z = f2bf(gelu_f(acc[2] + dwb[c40 + 2]));
  o.w = f2bf(gelu_f(acc[3] + dwb[c40 + 3]));
  *(ushort4*)(y2c + ((size_t)bb * NN + n) * C4 + c40) = o;
}

extern "C" void kernel_launch(void* const* d_in, const int* in_sizes, int n_in,
                              void* d_out, int out_size, void* d_ws, size_t ws_size,
                              hipStream_t stream) {
  const float* x = (const float*)d_in[0];
  const float* mem = (const float*)d_in[1];
  const float* conv1_w = (const float*)d_in[2];
  const float* conv1_b = (const float*)d_in[3];
  const float* conv2_w = (const float*)d_in[4];
  const float* conv2_b = (const float*)d_in[5];
  const float* conv3_w = (const float*)d_in[6];
  const float* sim_a = (const float*)d_in[7];
  const float* sim_b = (const float*)d_in[8];
  const float* ln_w = (const float*)d_in[9];
  const float* ln_b = (const float*)d_in[10];
  const float* q_w = (const float*)d_in[11];
  const float* q_b = (const float*)d_in[12];
  const float* k_w = (const float*)d_in[13];
  const float* k_b = (const float*)d_in[14];
  const float* v_w = (const float*)d_in[15];
  const float* v_b = (const float*)d_in[16];
  const float* proj_w = (const float*)d_in[17];
  const float* proj_b = (const float*)d_in[18];
  const float* fc1_w = (const float*)d_in[19];
  const float* fc1_b = (const float*)d_in[20];
  const float* dw_w = (const float*)d_in[21];
  const float* dw_b = (const float*)d_in[22];
  const float* fc2_w = (const float*)d_in[23];
  const float* fc2_b = (const float*)d_in[24];

  // Workspace: 101,353,472 B = 96.7 MB (< 104 MB known-good).
  char* base = (char*)d_ws;
  // R0 [0, 33.5M): xtb [build..q-gemm] -> by1 [fc1..dwconv]
  bf16_t* xtb = (bf16_t*)(base);
  bf16_t* by1 = (bf16_t*)(base);
  // R1 [33.5M, 67.1M): bh1 [conv1..conv2];
  //   partial@+16.8M 6.6MB [center..sim_cin]; qb@+0 [q..attn] -> outb@+0 [addln1..end];
  //   pbuf@+16.8M [proj..addln1] -> yout@+16.8M [fc2..addln2]
  bf16_t* bh1 = (bf16_t*)(base + 33554432);
  float* qb = (float*)(base + 33554432);
  float* outb = (float*)(base + 33554432);
  float* partial = (float*)(base + 50331648);
  float* pbuf = (float*)(base + 50331648);
  float* yout = (float*)(base + 50331648);
  // R2 [67.1M, 80.2M): czt bf16 [conv3..center] -> obz [attn..proj] -> outb_b [addln1..fc1]
  bf16_t* czt = (bf16_t*)(base + 67108864);
  bf16_t* obz = (bf16_t*)(base + 67108864);
  bf16_t* outb_b = (bf16_t*)(base + 67108864);
  // R3 [80.2M, 97.0M): wtb 6.4M [..conv1] -> h2c bf16 16.8M [conv2..conv3 chunks]
  //                    -> y2c bf16 16.8M [dwconv..fc2 chunks]
  bf16_t* wtb = (bf16_t*)(base + 80216064);
  bf16_t* h2c = (bf16_t*)(base + 80216064);
  bf16_t* y2c = (bf16_t*)(base + 80216064);
  // R4 [97.0M, 96.7MB end): packed weights + small tensors
  bf16_t* wbz = (bf16_t*)(base + 96993280);       // 1.5 MB
  float* center_unused = (float*)(base + 98486272);
  float* cin = (float*)(base + 100124672);
  float* kb = (float*)(base + 100534272);
  float* vb = (float*)(base + 100943872);
  float* dout = (float*)d_out;
  (void)center_unused;

  bf16_t* conv2_wb = wbz;            // 65536
  bf16_t* conv3_wb = wbz + 65536;    // 25600
  bf16_t* q_wb = wbz + 91136;        // 65536
  bf16_t* proj_wb = wbz + 156672;    // 65536
  bf16_t* fc1_wb = wbz + 222208;     // 262144
  bf16_t* fc2_wb = wbz + 484352;     // 262144

  cvt_bf16<<<256, 256, 0, stream>>>(conv2_w, conv2_wb, 65536);
  cvt_bf16<<<100, 256, 0, stream>>>(conv3_w, conv3_wb, 25600);
  cvt_bf16<<<256, 256, 0, stream>>>(q_w, q_wb, 65536);
  cvt_bf16<<<256, 256, 0, stream>>>(proj_w, proj_wb, 65536);
  cvt_bf16<<<1024, 256, 0, stream>>>(fc1_w, fc1_wb, 262144);
  cvt_bf16<<<1024, 256, 0, stream>>>(fc2_w, fc2_wb, 262144);
  build_xtb<<<16384, 256, 0, stream>>>(x, mem, xtb);
  transpose_w1b<<<25088, 256, 0, stream>>>(conv1_w, wtb);
  conv1_mfma<<<1024, 256, 0, stream>>>(xtb, wtb, conv1_b, bh1);
  // conv2 (gelu) -> conv3 (transposed), 2 chunks of 32768 px through h2c
  for (int i = 0; i < 2; ++i) {
    gemm_mfma<1, 1, 0, 1><<<dim3(2, 256, 1), 256, 0, stream>>>(
        bh1 + (size_t)i * 32768 * CC, conv2_wb, conv2_b, h2c, 32768, 256, 256, 256, 0, 0);
    gemm_mfma<0, 0, 1, 1><<<dim3(1, 256, 1), 256, 0, stream>>>(
        h2c, conv3_wb, nullptr, czt + (size_t)i * 32768, 32768, 100, 256, 65536, 0, 0);
  }
  softmax_rows<<<1600, 256, 0, stream>>>(czt);
  center_einsum2<<<dim3(16, 10, 4), 256, 0, stream>>>(czt, xtb, partial);
  sim_cin<<<400, 256, 0, stream>>>(partial, sim_a, sim_b, ln_w, ln_b, cin);
  // q = x @ q_w^T + q_b: one 3D launch over 4 batch slabs of xtb (bt = 4b+3)
  gemm_mfma<0, 1, 0, 0><<<dim3(2, 32, 4), 256, 0, stream>>>(
      xtb + (size_t)3 * NN * CC, q_wb, q_b, qb, 4096, 256, 256, 256,
      (size_t)4 * NN * CC, (size_t)NN * CC);
  gemm_nt<0, 1><<<dim3(4, 7), 256, 0, stream>>>(cin, k_w, k_b, kb, 400, 256, 256, 256);
  gemm_nt<0, 1><<<dim3(4, 7), 256, 0, stream>>>(cin, v_w, v_b, vb, 400, 256, 256, 256);
  attn2<<<dim3(512, 4), 256, 0, stream>>>(qb, kb, vb, obz);
  gemm_mfma<0, 1, 0, 0><<<dim3(2, 128, 1), 256, 0, stream>>>(obz, proj_wb, proj_b, pbuf,
                                                             16384, 256, 256, 256, 0, 0);
  add_ln<1><<<16384, 256, 0, stream>>>(x, pbuf, ln_w, ln_b, outb, outb_b);
  gemm_mfma<0, 1, 0, 1><<<dim3(8, 128, 1), 256, 0, stream>>>(outb_b, fc1_wb, fc1_b, by1,
                                                             16384, 1024, 256, 1024, 0, 0);
  // dwconv -> fc2, 2 chunks of 2 batches through y2c
  for (int c = 0; c < 2; ++c) {
    dwconv_kernel<<<8192, 256, 0, stream>>>(by1, dw_w, dw_b, y2c, c * 2);
    gemm_mfma<0, 1, 0, 0><<<dim3(2, 32, 2), 256, 0, stream>>>(
        y2c, fc2_wb, fc2_b, yout + (size_t)c * 2 * NN * CC, 4096, 256, 1024, 256,
        (size_t)NN * C4, (size_t)NN * CC);
  }
  add_ln<0><<<16384, 256, 0, stream>>>(outb, yout, ln_w, ln_b, dout, nullptr);
}

// Round 7
// 1043.655 us; speedup vs baseline: 7.4673x; 1.3151x over previous
//
#include <hip/hip_runtime.h>
#include <math.h>

#define NN 4096
#define CC 256
#define HH 64
#define BT 16
#define KCC 100
#define NHH 8
#define HDD 32
#define C4 1024

typedef unsigned short bf16_t;
typedef short s16x8 __attribute__((ext_vector_type(8)));
typedef float f32x4 __attribute__((ext_vector_type(4)));

__device__ __forceinline__ float bf2f(bf16_t h) {
  return __uint_as_float(((unsigned)h) << 16);
}
__device__ __forceinline__ bf16_t f2bf(float f) {
  unsigned u = __float_as_uint(f);
  return (bf16_t)((u + 0x7FFFu + ((u >> 16) & 1u)) >> 16);
}

__device__ __forceinline__ float gelu_f(float x) {
  return 0.5f * x * (1.0f + erff(x * 0.7071067811865475f));
}

// async global->LDS, 16 B per lane; lds dest = wave-uniform base + lane*16
__device__ __forceinline__ void g2l16(const void* g, void* l) {
  __builtin_amdgcn_global_load_lds((const __attribute__((address_space(1))) void*)g,
                                   (__attribute__((address_space(3))) void*)l, 16, 0, 0);
}

__device__ __forceinline__ float block_sum256(float v) {
  __shared__ float sh[4];
#pragma unroll
  for (int off = 32; off; off >>= 1) v += __shfl_xor(v, off, 64);
  __syncthreads();
  if ((threadIdx.x & 63) == 0) sh[threadIdx.x >> 6] = v;
  __syncthreads();
  return sh[0] + sh[1] + sh[2] + sh[3];
}

__device__ __forceinline__ const float* xt_base(const float* x, const float* mem, int bt) {
  int b = bt >> 2, tt = bt & 3;
  return (tt < 3) ? (mem + (size_t)(b * 3 + tt) * NN * CC)
                  : (x + (size_t)b * NN * CC);
}

__global__ __launch_bounds__(256) void cvt_bf16(const float* __restrict__ src,
                                                bf16_t* __restrict__ dst, int n) {
  int i = blockIdx.x * 256 + threadIdx.x;
  if (i < n) dst[i] = f2bf(src[i]);
}

// xtb[bt][n][c] bf16 from x/mem fp32
__global__ __launch_bounds__(256) void build_xtb(const float* __restrict__ x,
                                                 const float* __restrict__ mem,
                                                 bf16_t* __restrict__ xtb) {
  int i = blockIdx.x * 256 + threadIdx.x;
  int c4 = i & 63;
  int n = (i >> 6) & 4095;
  int bt = i >> 18;
  const float* src = xt_base(x, mem, bt) + (size_t)n * CC + c4 * 4;
  float4 v = *(const float4*)src;
  ushort4 o;
  o.x = f2bf(v.x); o.y = f2bf(v.y); o.z = f2bf(v.z); o.w = f2bf(v.w);
  *(ushort4*)(xtb + (size_t)i * 4) = o;
}

// wtb layout: [ky][cig(8)][cq(4)][kx(7)][oct(4)][co(64)][cj(8)] bf16
__global__ __launch_bounds__(256) void transpose_w1b(const float* __restrict__ w,
                                                     bf16_t* __restrict__ wtb) {
  int i = blockIdx.x * 256 + threadIdx.x;
  if (i >= 7 * 8 * 4 * 7 * 4 * 64 * 8) return;
  int cj = i & 7;
  int t = i >> 3;
  int co = t & 63; t >>= 6;
  int oc = t & 3; t >>= 2;
  int kx = t % 7; t /= 7;
  int cq = t & 3; t >>= 2;
  int cg = t & 7;
  int ky = t >> 3;
  int ci = cg * 32 + oc * 8 + cj;
  int cog = cq * 64 + co;
  wtb[i] = f2bf(w[((size_t)(cog * CC + ci) * 7 + ky) * 7 + kx]);
}

// conv1 v3: bf16 MFMA implicit GEMM with async global->LDS staging.
// Block: (bt, 4 output rows, 64 co). A staged once per cig (10 rows incl. halo);
// W staged per (ky,cig). Halo/OOB rows zeroed once (always outside image).
__global__ __launch_bounds__(256, 2) void conv1_mfma(const bf16_t* __restrict__ xtb,
                                                     const bf16_t* __restrict__ wtb,
                                                     const float* __restrict__ bias,
                                                     bf16_t* __restrict__ h1) {
  int bt = blockIdx.x >> 6;
  int h0 = ((blockIdx.x >> 2) & 15) * 4;
  int cq = blockIdx.x & 3;
  int co0 = cq * 64;
  int tid = threadIdx.x;
  int wv = tid >> 6;
  int lane = tid & 63;
  int lm = lane & 15;
  int g = lane >> 4;
  __shared__ short As[10][4][70][8];  // [row][koct][col+3][cj] 44800 B
  __shared__ short Ws[7][4][64][8];   // [kx][koct][co][cj]     28672 B
  // zero-init As once: halo cols and OOB rows stay zero forever
  {
    s16x8 z = {0, 0, 0, 0, 0, 0, 0, 0};
    for (int i = tid; i < 2800; i += 256) *(s16x8*)((short*)As + i * 8) = z;
  }
  __syncthreads();
  f32x4 acc[4][4] = {};
  const bf16_t* xb = xtb + (size_t)bt * (NN * CC);
  for (int cig = 0; cig < 8; ++cig) {
    int ci0 = cig * 32;
    // stage A: t = rr*4+goct; one async instr covers 64 cols (interior only)
    for (int t = wv; t < 40; t += 4) {
      int rr = t >> 2, go = t & 3;
      int r = h0 - 3 + rr;
      if (r >= 0 && r < HH) {
        const bf16_t* gsrc = xb + ((size_t)(r * 64 + lane)) * CC + ci0 + go * 8;
        g2l16(gsrc, &As[rr][go][3][0]);
      }
    }
    for (int ky = 0; ky < 7; ++ky) {
      const bf16_t* wk = wtb + ((size_t)((ky * 8 + cig) * 4 + cq)) * (1792 * 8);
      for (int t = wv; t < 28; t += 4)
        g2l16(wk + (size_t)t * 512 + lane * 8, (short*)Ws + t * 512);
      __syncthreads();  // drains this wave's async loads (A on ky==0, W always)
#pragma unroll
      for (int kx = 0; kx < 7; ++kx) {
        s16x8 af[4], bf[4];
#pragma unroll
        for (int mt = 0; mt < 4; ++mt)
          af[mt] = *(const s16x8*)&As[wv + ky][g][mt * 16 + lm + kx][0];
#pragma unroll
        for (int nt = 0; nt < 4; ++nt)
          bf[nt] = *(const s16x8*)&Ws[kx][g][nt * 16 + lm][0];
#pragma unroll
        for (int mt = 0; mt < 4; ++mt)
#pragma unroll
          for (int nt = 0; nt < 4; ++nt)
            acc[mt][nt] = __builtin_amdgcn_mfma_f32_16x16x32_bf16(af[mt], bf[nt],
                                                                  acc[mt][nt], 0, 0, 0);
      }
      __syncthreads();  // Ws (and As on last ky of cig) free for restage
    }
  }
  int row = h0 + wv;
  const size_t xbase = (size_t)bt * (NN * CC);
#pragma unroll
  for (int nt = 0; nt < 4; ++nt) {
    int co = co0 + nt * 16 + lm;
    float bs = bias[co];
#pragma unroll
    for (int mt = 0; mt < 4; ++mt) {
#pragma unroll
      for (int rg = 0; rg < 4; ++rg) {
        int col = mt * 16 + g * 4 + rg;
        float vv = acc[mt][nt][rg] + bs;
        h1[xbase + (size_t)(row * 64 + col) * CC + co] = f2bf(gelu_f(vv));
      }
    }
  }
}

// bf16 MFMA GEMM with optional z-slab batching: A += z*aStr (elems), out idx += z*oStr.
template <int GELU, int BIAS, int TOUT, int OBF>
__global__ __launch_bounds__(256) void gemm_mfma(const bf16_t* __restrict__ A,
                                                 const bf16_t* __restrict__ W,
                                                 const float* __restrict__ bias,
                                                 void* __restrict__ outp,
                                                 int M, int N, int K, int ldo,
                                                 size_t aStr, size_t oStr) {
  __shared__ short As[128][40];
  __shared__ short Bs[128][40];
  A += (size_t)blockIdx.z * aStr;
  size_t obase = (size_t)blockIdx.z * oStr;
  int tid = threadIdx.x;
  int n0 = blockIdx.x * 128, m0 = blockIdx.y * 128;
  int lane = tid & 63, wv = tid >> 6;
  int wm = wv & 1, wn = wv >> 1;
  int lm = lane & 15, g = lane >> 4;
  f32x4 acc[4][4] = {};
  int r1 = tid >> 2, kq = tid & 3;
  int r2 = r1 + 64;
  for (int k0 = 0; k0 < K; k0 += 32) {
    *(s16x8*)&As[r1][kq * 8] = *(const s16x8*)(A + (size_t)(m0 + r1) * K + k0 + kq * 8);
    *(s16x8*)&As[r2][kq * 8] = *(const s16x8*)(A + (size_t)(m0 + r2) * K + k0 + kq * 8);
    s16x8 z = {0, 0, 0, 0, 0, 0, 0, 0};
    s16x8 b1 = z, b2 = z;
    if (n0 + r1 < N) b1 = *(const s16x8*)(W + (size_t)(n0 + r1) * K + k0 + kq * 8);
    if (n0 + r2 < N) b2 = *(const s16x8*)(W + (size_t)(n0 + r2) * K + k0 + kq * 8);
    *(s16x8*)&Bs[r1][kq * 8] = b1;
    *(s16x8*)&Bs[r2][kq * 8] = b2;
    __syncthreads();
    s16x8 af[4], bf[4];
#pragma unroll
    for (int mt = 0; mt < 4; ++mt)
      af[mt] = *(const s16x8*)&As[wm * 64 + mt * 16 + lm][g * 8];
#pragma unroll
    for (int nt = 0; nt < 4; ++nt)
      bf[nt] = *(const s16x8*)&Bs[wn * 64 + nt * 16 + lm][g * 8];
#pragma unroll
    for (int mt = 0; mt < 4; ++mt)
#pragma unroll
      for (int nt = 0; nt < 4; ++nt)
        acc[mt][nt] = __builtin_amdgcn_mfma_f32_16x16x32_bf16(af[mt], bf[nt],
                                                              acc[mt][nt], 0, 0, 0);
    __syncthreads();
  }
#pragma unroll
  for (int nt = 0; nt < 4; ++nt) {
    int n = n0 + wn * 64 + nt * 16 + lm;
    if (n >= N) continue;
    float bs = BIAS ? bias[n] : 0.f;
#pragma unroll
    for (int mt = 0; mt < 4; ++mt) {
#pragma unroll
      for (int rg = 0; rg < 4; ++rg) {
        int m = m0 + wm * 64 + mt * 16 + g * 4 + rg;
        float v = acc[mt][nt][rg] + bs;
        if (GELU) v = gelu_f(v);
        size_t idx = obase + (TOUT ? ((size_t)n * ldo + m) : ((size_t)m * ldo + n));
        if (OBF)
          ((bf16_t*)outp)[idx] = f2bf(v);
        else
          ((float*)outp)[idx] = v;
      }
    }
  }
}

// fp32 gemm for tiny k/v projections (M=400)
template <int GELU, int BIAS>
__global__ __launch_bounds__(256) void gemm_nt(const float* __restrict__ Ap,
                                               const float* __restrict__ Wm,
                                               const float* __restrict__ bias,
                                               float* __restrict__ outp,
                                               int M, int N, int K, int ldo) {
  __shared__ float As[16][68];
  __shared__ float Ws[16][68];
  int tid = threadIdx.x;
  int n0 = blockIdx.x * 64, m0 = blockIdx.y * 64;
  int txn = tid & 15, tym = tid >> 4;
  int mi = tid >> 2, kq = (tid & 3) * 4;
  float acc[4][4] = {};
  for (int k0 = 0; k0 < K; k0 += 16) {
    float4 av = {0, 0, 0, 0}, wvv = {0, 0, 0, 0};
    if (m0 + mi < M) av = *(const float4*)&Ap[(size_t)(m0 + mi) * K + k0 + kq];
    if (n0 + mi < N) wvv = *(const float4*)&Wm[(size_t)(n0 + mi) * K + k0 + kq];
    As[kq + 0][mi] = av.x; As[kq + 1][mi] = av.y; As[kq + 2][mi] = av.z; As[kq + 3][mi] = av.w;
    Ws[kq + 0][mi] = wvv.x; Ws[kq + 1][mi] = wvv.y; Ws[kq + 2][mi] = wvv.z; Ws[kq + 3][mi] = wvv.w;
    __syncthreads();
#pragma unroll
    for (int ki = 0; ki < 16; ++ki) {
      float4 a4 = *(const float4*)&As[ki][tym * 4];
      float4 w4 = *(const float4*)&Ws[ki][txn * 4];
      float am[4] = {a4.x, a4.y, a4.z, a4.w};
      float wn[4] = {w4.x, w4.y, w4.z, w4.w};
#pragma unroll
      for (int i = 0; i < 4; ++i)
#pragma unroll
        for (int j = 0; j < 4; ++j) acc[i][j] += am[i] * wn[j];
    }
    __syncthreads();
  }
#pragma unroll
  for (int i = 0; i < 4; ++i) {
    int m = m0 + tym * 4 + i;
    if (m >= M) continue;
#pragma unroll
    for (int j = 0; j < 4; ++j) {
      int n = n0 + txn * 4 + j;
      if (n >= N) continue;
      float v = acc[i][j];
      if (BIAS) v += bias[n];
      if (GELU) v = gelu_f(v);
      outp[(size_t)m * ldo + n] = v;
    }
  }
}

// 1600 rows of 4096 contiguous bf16, softmax in place
__global__ __launch_bounds__(256) void softmax_rows(bf16_t* __restrict__ p) {
  __shared__ float sh[8];
  int tid = threadIdx.x;
  bf16_t* base = p + (size_t)blockIdx.x * NN;
  float vals[16];
  float mx = -1e30f;
#pragma unroll
  for (int i = 0; i < 16; ++i) {
    vals[i] = bf2f(base[tid + i * 256]);
    mx = fmaxf(mx, vals[i]);
  }
#pragma unroll
  for (int off = 32; off; off >>= 1) mx = fmaxf(mx, __shfl_xor(mx, off, 64));
  if ((tid & 63) == 0) sh[tid >> 6] = mx;
  __syncthreads();
  mx = fmaxf(fmaxf(sh[0], sh[1]), fmaxf(sh[2], sh[3]));
  float s = 0.f;
#pragma unroll
  for (int i = 0; i < 16; ++i) {
    vals[i] = expf(vals[i] - mx);
    s += vals[i];
  }
#pragma unroll
  for (int off = 32; off; off >>= 1) s += __shfl_xor(s, off, 64);
  if ((tid & 63) == 0) sh[4 + (tid >> 6)] = s;
  __syncthreads();
  s = sh[4] + sh[5] + sh[6] + sh[7];
  float inv = 1.f / s;
#pragma unroll
  for (int i = 0; i < 16; ++i) base[tid + i * 256] = f2bf(vals[i] * inv);
}

// partial[nc][bt][kc][c] = sum over n-chunk nc of soft * xtb
__global__ __launch_bounds__(256) void center_einsum2(const bf16_t* __restrict__ soft,
                                                      const bf16_t* __restrict__ xtb,
                                                      float* __restrict__ partial) {
  int bt = blockIdx.x, kg = blockIdx.y, nc = blockIdx.z;
  int c = threadIdx.x;
  __shared__ float sl[10][512];
  float acc[10] = {};
  for (int n0 = nc * 1024; n0 < nc * 1024 + 1024; n0 += 512) {
    for (int idx = threadIdx.x; idx < 5120; idx += 256) {
      int n = idx & 511;
      int j = idx >> 9;
      sl[j][n] = bf2f(soft[((size_t)(kg * 10 + j) * BT + bt) * NN + n0 + n]);
    }
    __syncthreads();
    for (int n = 0; n < 512; ++n) {
      float xv = bf2f(xtb[((size_t)bt * NN + n0 + n) * CC + c]);
#pragma unroll
      for (int j = 0; j < 10; ++j) acc[j] += sl[j][n] * xv;
    }
    __syncthreads();
  }
#pragma unroll
  for (int j = 0; j < 10; ++j)
    partial[(((size_t)nc * BT + bt) * KCC + kg * 10 + j) * CC + c] = acc[j];
}

// cosine-sim gating + LN -> cin[b][kc][c]; reduces 4 n-chunk partials
__global__ __launch_bounds__(256) void sim_cin(const float* __restrict__ partial,
                                               const float* __restrict__ alpha_p,
                                               const float* __restrict__ beta_p,
                                               const float* __restrict__ lnw,
                                               const float* __restrict__ lnb,
                                               float* __restrict__ cin) {
  int b = blockIdx.x / KCC, kc = blockIdx.x % KCC;
  int c = threadIdx.x;
  float p0 = 0.f, p1 = 0.f, p2 = 0.f, lst = 0.f;
#pragma unroll
  for (int nc = 0; nc < 4; ++nc) {
    size_t base = ((size_t)nc * BT) * KCC * CC;
    p0 += partial[base + ((size_t)(b * 4 + 0) * KCC + kc) * CC + c];
    p1 += partial[base + ((size_t)(b * 4 + 1) * KCC + kc) * CC + c];
    p2 += partial[base + ((size_t)(b * 4 + 2) * KCC + kc) * CC + c];
    lst += partial[base + ((size_t)(b * 4 + 3) * KCC + kc) * CC + c];
  }
  float ll = block_sum256(lst * lst);
  float q0 = block_sum256(p0 * p0);
  float q1 = block_sum256(p1 * p1);
  float q2 = block_sum256(p2 * p2);
  float d0 = block_sum256(lst * p0);
  float d1 = block_sum256(lst * p1);
  float d2 = block_sum256(lst * p2);
  float alpha = alpha_p[0], beta = beta_p[0];
  float nl = sqrtf(ll);
  float c0 = 1.f / (1.f + expf(-(beta + alpha * (d0 / fmaxf(nl * sqrtf(q0), 1e-8f)))));
  float c1 = 1.f / (1.f + expf(-(beta + alpha * (d1 / fmaxf(nl * sqrtf(q1), 1e-8f)))));
  float c2 = 1.f / (1.f + expf(-(beta + alpha * (d2 / fmaxf(nl * sqrtf(q2), 1e-8f)))));
  float v = lst + c0 * p0 + c1 * p1 + c2 * p2;
  float m = block_sum256(v) * (1.f / CC);
  float dv = v - m;
  float var = block_sum256(dv * dv) * (1.f / CC);
  cin[((size_t)b * KCC + kc) * CC + c] = dv * rsqrtf(var + 1e-5f) * lnw[c] + lnb[c];
}

// attention v2: block = (8 query rows, b). K tiled through LDS, V read once.
__global__ __launch_bounds__(256) void attn2(const float* __restrict__ q,
                                             const float* __restrict__ kb,
                                             const float* __restrict__ vb,
                                             bf16_t* __restrict__ ob) {
  int b = blockIdx.y;
  int n0 = blockIdx.x * 8;
  int tid = threadIdx.x;
  __shared__ float qs[8][256];
  __shared__ float Ks[32][257];
  __shared__ float sc[8][8][104];
#pragma unroll
  for (int r = 0; r < 8; ++r)
    qs[r][tid] = q[((size_t)b * NN + n0 + r) * CC + tid] * 0.17677669529663687f;
  int nn = tid >> 5, kcl = tid & 31;
  for (int kt = 0; kt < 4; ++kt) {
    int kbase = kt * 32;
    int rows = (kbase + 32 <= KCC) ? 32 : (KCC - kbase);
    __syncthreads();
    for (int idx = tid; idx < rows * 256; idx += 256) {
      int rr = idx >> 8, cc = idx & 255;
      Ks[rr][cc] = kb[((size_t)b * KCC + kbase + rr) * CC + cc];
    }
    __syncthreads();
    if (kcl < rows) {
#pragma unroll
      for (int h = 0; h < NHH; ++h) {
        float s = 0.f;
#pragma unroll
        for (int d = 0; d < HDD; ++d) s += qs[nn][h * HDD + d] * Ks[kcl][h * HDD + d];
        sc[nn][h][kbase + kcl] = s;
      }
    }
  }
  __syncthreads();
  {
    int tnn = tid >> 5, th = (tid >> 2) & 7, j = tid & 3;
    float mx = -1e30f;
    for (int kc = j * 25; kc < j * 25 + 25; ++kc) mx = fmaxf(mx, sc[tnn][th][kc]);
    mx = fmaxf(mx, __shfl_xor(mx, 1, 64));
    mx = fmaxf(mx, __shfl_xor(mx, 2, 64));
    float sm = 0.f;
    for (int kc = j * 25; kc < j * 25 + 25; ++kc) {
      float e = expf(sc[tnn][th][kc] - mx);
      sc[tnn][th][kc] = e;
      sm += e;
    }
    sm += __shfl_xor(sm, 1, 64);
    sm += __shfl_xor(sm, 2, 64);
    float inv = 1.f / sm;
    for (int kc = j * 25; kc < j * 25 + 25; ++kc) sc[tnn][th][kc] *= inv;
  }
  __syncthreads();
  float o[8] = {0, 0, 0, 0, 0, 0, 0, 0};
  int h = tid >> 5;
  for (int kc = 0; kc < KCC; ++kc) {
    float v = vb[((size_t)b * KCC + kc) * CC + tid];
#pragma unroll
    for (int r = 0; r < 8; ++r) o[r] += sc[r][h][kc] * v;
  }
#pragma unroll
  for (int r = 0; r < 8; ++r)
    ob[((size_t)b * NN + n0 + r) * CC + tid] = f2bf(o[r]);
}

// dst[row][c] = res[row][c] + LN(y[row][:])[c]; WB: also write bf16 copy
template <int WB>
__global__ __launch_bounds__(256) void add_ln(const float* __restrict__ res,
                                              const float* __restrict__ y,
                                              const float* __restrict__ lnw,
                                              const float* __restrict__ lnb,
                                              float* __restrict__ dst,
                                              bf16_t* __restrict__ dst_b) {
  size_t row = blockIdx.x;
  int c = threadIdx.x;
  float v = y[row * CC + c];
  float m = block_sum256(v) * (1.f / CC);
  float dv = v - m;
  float var = block_sum256(dv * dv) * (1.f / CC);
  float o = res[row * CC + c] + dv * rsqrtf(var + 1e-5f) * lnw[c] + lnb[c];
  dst[row * CC + c] = o;
  if (WB) dst_b[row * CC + c] = f2bf(o);
}

// depthwise 3x3 + bias + gelu, 2 batches per launch (b = b0 + blockIdx.x>>12)
__global__ __launch_bounds__(256) void dwconv_kernel(const bf16_t* __restrict__ y1,
                                                     const float* __restrict__ dww,
                                                     const float* __restrict__ dwb,
                                                     bf16_t* __restrict__ y2c, int b0) {
  int bb = blockIdx.x >> 12;
  int n = blockIdx.x & 4095;
  int b = b0 + bb;
  int h = n >> 6, w = n & 63;
  int c40 = threadIdx.x * 4;
  float wreg[4][9];
#pragma unroll
  for (int j = 0; j < 4; ++j)
#pragma unroll
    for (int t2 = 0; t2 < 9; ++t2) wreg[j][t2] = dww[(size_t)(c40 + j) * 9 + t2];
  float acc[4] = {0, 0, 0, 0};
#pragma unroll
  for (int dy = 0; dy < 3; ++dy) {
    int r = h + dy - 1;
    if (r < 0 || r >= HH) continue;
#pragma unroll
    for (int dx = 0; dx < 3; ++dx) {
      int cl = w + dx - 1;
      if (cl < 0 || cl >= 64) continue;
      ushort4 u = *(const ushort4*)(y1 + ((size_t)b * NN + r * 64 + cl) * C4 + c40);
      int t2 = dy * 3 + dx;
      acc[0] += bf2f(u.x) * wreg[0][t2];
      acc[1] += bf2f(u.y) * wreg[1][t2];
      acc[2] += bf2f(u.z) * wreg[2][t2];
      acc[3] += bf2f(u.w) * wreg[3][t2];
    }
  }
  ushort4 o;
  o.x = f2bf(gelu_f(acc[0] + dwb[c40 + 0]));
  o.y = f2bf(gelu_f(acc[1] + dwb[c40 + 1]));
  o.z = f2bf(gelu_f(acc[2] + dwb[c40 + 2]));
  o.w = f2bf(gelu_f(acc[3] + dwb[c40 + 3]));
  *(ushort4*)(y2c + ((size_t)bb * NN + n) * C4 + c40) = o;
}

extern "C" void kernel_launch(void* const* d_in, const int* in_sizes, int n_in,
                              void* d_out, int out_size, void* d_ws, size_t ws_size,
                              hipStream_t stream) {
  const float* x = (const float*)d_in[0];
  const float* mem = (const float*)d_in[1];
  const float* conv1_w = (const float*)d_in[2];
  const float* conv1_b = (const float*)d_in[3];
  const float* conv2_w = (const float*)d_in[4];
  const float* conv2_b = (const float*)d_in[5];
  const float* conv3_w = (const float*)d_in[6];
  const float* sim_a = (const float*)d_in[7];
  const float* sim_b = (const float*)d_in[8];
  const float* ln_w = (const float*)d_in[9];
  const float* ln_b = (const float*)d_in[10];
  const float* q_w = (const float*)d_in[11];
  const float* q_b = (const float*)d_in[12];
  const float* k_w = (const float*)d_in[13];
  const float* k_b = (const float*)d_in[14];
  const float* v_w = (const float*)d_in[15];
  const float* v_b = (const float*)d_in[16];
  const float* proj_w = (const float*)d_in[17];
  const float* proj_b = (const float*)d_in[18];
  const float* fc1_w = (const float*)d_in[19];
  const float* fc1_b = (const float*)d_in[20];
  const float* dw_w = (const float*)d_in[21];
  const float* dw_b = (const float*)d_in[22];
  const float* fc2_w = (const float*)d_in[23];
  const float* fc2_b = (const float*)d_in[24];

  // Workspace: 101,353,472 B = 96.7 MB (< 104 MB known-good).
  char* base = (char*)d_ws;
  bf16_t* xtb = (bf16_t*)(base);
  bf16_t* by1 = (bf16_t*)(base);
  bf16_t* bh1 = (bf16_t*)(base + 33554432);
  float* qb = (float*)(base + 33554432);
  float* outb = (float*)(base + 33554432);
  float* partial = (float*)(base + 50331648);
  float* pbuf = (float*)(base + 50331648);
  float* yout = (float*)(base + 50331648);
  bf16_t* czt = (bf16_t*)(base + 67108864);
  bf16_t* obz = (bf16_t*)(base + 67108864);
  bf16_t* outb_b = (bf16_t*)(base + 67108864);
  bf16_t* wtb = (bf16_t*)(base + 80216064);
  bf16_t* h2c = (bf16_t*)(base + 80216064);
  bf16_t* y2c = (bf16_t*)(base + 80216064);
  bf16_t* wbz = (bf16_t*)(base + 96993280);
  float* cin = (float*)(base + 100124672);
  float* kb = (float*)(base + 100534272);
  float* vb = (float*)(base + 100943872);
  float* dout = (float*)d_out;

  bf16_t* conv2_wb = wbz;            // 65536
  bf16_t* conv3_wb = wbz + 65536;    // 25600
  bf16_t* q_wb = wbz + 91136;        // 65536
  bf16_t* proj_wb = wbz + 156672;    // 65536
  bf16_t* fc1_wb = wbz + 222208;     // 262144
  bf16_t* fc2_wb = wbz + 484352;     // 262144

  cvt_bf16<<<256, 256, 0, stream>>>(conv2_w, conv2_wb, 65536);
  cvt_bf16<<<100, 256, 0, stream>>>(conv3_w, conv3_wb, 25600);
  cvt_bf16<<<256, 256, 0, stream>>>(q_w, q_wb, 65536);
  cvt_bf16<<<256, 256, 0, stream>>>(proj_w, proj_wb, 65536);
  cvt_bf16<<<1024, 256, 0, stream>>>(fc1_w, fc1_wb, 262144);
  cvt_bf16<<<1024, 256, 0, stream>>>(fc2_w, fc2_wb, 262144);
  build_xtb<<<16384, 256, 0, stream>>>(x, mem, xtb);
  transpose_w1b<<<25088, 256, 0, stream>>>(conv1_w, wtb);
  conv1_mfma<<<1024, 256, 0, stream>>>(xtb, wtb, conv1_b, bh1);
  for (int i = 0; i < 2; ++i) {
    gemm_mfma<1, 1, 0, 1><<<dim3(2, 256, 1), 256, 0, stream>>>(
        bh1 + (size_t)i * 32768 * CC, conv2_wb, conv2_b, h2c, 32768, 256, 256, 256, 0, 0);
    gemm_mfma<0, 0, 1, 1><<<dim3(1, 256, 1), 256, 0, stream>>>(
        h2c, conv3_wb, nullptr, czt + (size_t)i * 32768, 32768, 100, 256, 65536, 0, 0);
  }
  softmax_rows<<<1600, 256, 0, stream>>>(czt);
  center_einsum2<<<dim3(16, 10, 4), 256, 0, stream>>>(czt, xtb, partial);
  sim_cin<<<400, 256, 0, stream>>>(partial, sim_a, sim_b, ln_w, ln_b, cin);
  gemm_mfma<0, 1, 0, 0><<<dim3(2, 32, 4), 256, 0, stream>>>(
      xtb + (size_t)3 * NN * CC, q_wb, q_b, qb, 4096, 256, 256, 256,
      (size_t)4 * NN * CC, (size_t)NN * CC);
  gemm_nt<0, 1><<<dim3(4, 7), 256, 0, stream>>>(cin, k_w, k_b, kb, 400, 256, 256, 256);
  gemm_nt<0, 1><<<dim3(4, 7), 256, 0, stream>>>(cin, v_w, v_b, vb, 400, 256, 256, 256);
  attn2<<<dim3(512, 4), 256, 0, stream>>>(qb, kb, vb, obz);
  gemm_mfma<0, 1, 0, 0><<<dim3(2, 128, 1), 256, 0, stream>>>(obz, proj_wb, proj_b, pbuf,
                                                             16384, 256, 256, 256, 0, 0);
  add_ln<1><<<16384, 256, 0, stream>>>(x, pbuf, ln_w, ln_b, outb, outb_b);
  gemm_mfma<0, 1, 0, 1><<<dim3(8, 128, 1), 256, 0, stream>>>(outb_b, fc1_wb, fc1_b, by1,
                                                             16384, 1024, 256, 1024, 0, 0);
  for (int c = 0; c < 2; ++c) {
    dwconv_kernel<<<8192, 256, 0, stream>>>(by1, dw_w, dw_b, y2c, c * 2);
    gemm_mfma<0, 1, 0, 0><<<dim3(2, 32, 2), 256, 0, stream>>>(
        y2c, fc2_wb, fc2_b, yout + (size_t)c * 2 * NN * CC, 4096, 256, 1024, 256,
        (size_t)NN * C4, (size_t)NN * CC);
  }
  add_ln<0><<<16384, 256, 0, stream>>>(outb, yout, ln_w, ln_b, dout, nullptr);
}

// Round 8
// 945.791 us; speedup vs baseline: 8.2400x; 1.1035x over previous
//
#include <hip/hip_runtime.h>
#include <math.h>

#define NN 4096
#define CC 256
#define HH 64
#define BT 16
#define KCC 100
#define NHH 8
#define HDD 32
#define C4 1024

typedef unsigned short bf16_t;
typedef short s16x8 __attribute__((ext_vector_type(8)));
typedef float f32x4 __attribute__((ext_vector_type(4)));

__device__ __forceinline__ float bf2f(bf16_t h) {
  return __uint_as_float(((unsigned)h) << 16);
}
__device__ __forceinline__ bf16_t f2bf(float f) {
  unsigned u = __float_as_uint(f);
  return (bf16_t)((u + 0x7FFFu + ((u >> 16) & 1u)) >> 16);
}

__device__ __forceinline__ float gelu_f(float x) {
  return 0.5f * x * (1.0f + erff(x * 0.7071067811865475f));
}

// async global->LDS, 16 B per lane; lds dest = wave-uniform base + lane*16
__device__ __forceinline__ void g2l16(const void* g, void* l) {
  __builtin_amdgcn_global_load_lds((const __attribute__((address_space(1))) void*)g,
                                   (__attribute__((address_space(3))) void*)l, 16, 0, 0);
}

__device__ __forceinline__ float block_sum256(float v) {
  __shared__ float sh[4];
#pragma unroll
  for (int off = 32; off; off >>= 1) v += __shfl_xor(v, off, 64);
  __syncthreads();
  if ((threadIdx.x & 63) == 0) sh[threadIdx.x >> 6] = v;
  __syncthreads();
  return sh[0] + sh[1] + sh[2] + sh[3];
}

__device__ __forceinline__ const float* xt_base(const float* x, const float* mem, int bt) {
  int b = bt >> 2, tt = bt & 3;
  return (tt < 3) ? (mem + (size_t)(b * 3 + tt) * NN * CC)
                  : (x + (size_t)b * NN * CC);
}

// fused prologue: [0,16384) build xtb; [16384,19520) transpose conv1_w -> wtb;
// [19520,22436) convert 6 weight mats to bf16 pack wbz.
__global__ __launch_bounds__(256) void prologue(const float* __restrict__ x,
                                                const float* __restrict__ mem,
                                                bf16_t* __restrict__ xtb,
                                                const float* __restrict__ w1,
                                                bf16_t* __restrict__ wtb,
                                                const float* __restrict__ c2w,
                                                const float* __restrict__ c3w,
                                                const float* __restrict__ qw,
                                                const float* __restrict__ pw,
                                                const float* __restrict__ f1w,
                                                const float* __restrict__ f2w,
                                                bf16_t* __restrict__ wbz) {
  int bid = blockIdx.x;
  int tid = threadIdx.x;
  if (bid < 16384) {
    int i = bid * 256 + tid;
    int c4 = i & 63;
    int n = (i >> 6) & 4095;
    int bt = i >> 18;
    const float* src = xt_base(x, mem, bt) + (size_t)n * CC + c4 * 4;
    float4 v = *(const float4*)src;
    ushort4 o;
    o.x = f2bf(v.x); o.y = f2bf(v.y); o.z = f2bf(v.z); o.w = f2bf(v.w);
    *(ushort4*)(xtb + (size_t)i * 4) = o;
  } else if (bid < 19520) {
    int i = (bid - 16384) * 256 + tid;  // < 802816 exactly
    int cj = i & 7;
    int t = i >> 3;
    int co = t & 63; t >>= 6;
    int oc = t & 3; t >>= 2;
    int kx = t % 7; t /= 7;
    int cq = t & 3; t >>= 2;
    int cg = t & 7;
    int ky = t >> 3;
    int ci = cg * 32 + oc * 8 + cj;
    int cog = cq * 64 + co;
    wtb[i] = f2bf(w1[((size_t)(cog * CC + ci) * 7 + ky) * 7 + kx]);
  } else {
    int j = (bid - 19520) * 256 + tid;  // < 746496 exactly
    float v;
    if (j < 65536) v = c2w[j];
    else if (j < 91136) v = c3w[j - 65536];
    else if (j < 156672) v = qw[j - 91136];
    else if (j < 222208) v = pw[j - 156672];
    else if (j < 484352) v = f1w[j - 222208];
    else v = f2w[j - 484352];
    wbz[j] = f2bf(v);
  }
}

// conv1 v3: bf16 MFMA implicit GEMM with async global->LDS staging. (unchanged, 370us)
__global__ __launch_bounds__(256, 2) void conv1_mfma(const bf16_t* __restrict__ xtb,
                                                     const bf16_t* __restrict__ wtb,
                                                     const float* __restrict__ bias,
                                                     bf16_t* __restrict__ h1) {
  int bt = blockIdx.x >> 6;
  int h0 = ((blockIdx.x >> 2) & 15) * 4;
  int cq = blockIdx.x & 3;
  int co0 = cq * 64;
  int tid = threadIdx.x;
  int wv = tid >> 6;
  int lane = tid & 63;
  int lm = lane & 15;
  int g = lane >> 4;
  __shared__ short As[10][4][70][8];
  __shared__ short Ws[7][4][64][8];
  {
    s16x8 z = {0, 0, 0, 0, 0, 0, 0, 0};
    for (int i = tid; i < 2800; i += 256) *(s16x8*)((short*)As + i * 8) = z;
  }
  __syncthreads();
  f32x4 acc[4][4] = {};
  const bf16_t* xb = xtb + (size_t)bt * (NN * CC);
  for (int cig = 0; cig < 8; ++cig) {
    int ci0 = cig * 32;
    for (int t = wv; t < 40; t += 4) {
      int rr = t >> 2, go = t & 3;
      int r = h0 - 3 + rr;
      if (r >= 0 && r < HH) {
        const bf16_t* gsrc = xb + ((size_t)(r * 64 + lane)) * CC + ci0 + go * 8;
        g2l16(gsrc, &As[rr][go][3][0]);
      }
    }
    for (int ky = 0; ky < 7; ++ky) {
      const bf16_t* wk = wtb + ((size_t)((ky * 8 + cig) * 4 + cq)) * (1792 * 8);
      for (int t = wv; t < 28; t += 4)
        g2l16(wk + (size_t)t * 512 + lane * 8, (short*)Ws + t * 512);
      __syncthreads();
#pragma unroll
      for (int kx = 0; kx < 7; ++kx) {
        s16x8 af[4], bf[4];
#pragma unroll
        for (int mt = 0; mt < 4; ++mt)
          af[mt] = *(const s16x8*)&As[wv + ky][g][mt * 16 + lm + kx][0];
#pragma unroll
        for (int nt = 0; nt < 4; ++nt)
          bf[nt] = *(const s16x8*)&Ws[kx][g][nt * 16 + lm][0];
#pragma unroll
        for (int mt = 0; mt < 4; ++mt)
#pragma unroll
          for (int nt = 0; nt < 4; ++nt)
            acc[mt][nt] = __builtin_amdgcn_mfma_f32_16x16x32_bf16(af[mt], bf[nt],
                                                                  acc[mt][nt], 0, 0, 0);
      }
      __syncthreads();
    }
  }
  int row = h0 + wv;
  const size_t xbase = (size_t)bt * (NN * CC);
#pragma unroll
  for (int nt = 0; nt < 4; ++nt) {
    int co = co0 + nt * 16 + lm;
    float bs = bias[co];
#pragma unroll
    for (int mt = 0; mt < 4; ++mt) {
#pragma unroll
      for (int rg = 0; rg < 4; ++rg) {
        int col = mt * 16 + g * 4 + rg;
        float vv = acc[mt][nt][rg] + bs;
        h1[xbase + (size_t)(row * 64 + col) * CC + co] = f2bf(gelu_f(vv));
      }
    }
  }
}

// bf16 MFMA GEMM with optional z-slab batching (unchanged)
template <int GELU, int BIAS, int TOUT, int OBF>
__global__ __launch_bounds__(256) void gemm_mfma(const bf16_t* __restrict__ A,
                                                 const bf16_t* __restrict__ W,
                                                 const float* __restrict__ bias,
                                                 void* __restrict__ outp,
                                                 int M, int N, int K, int ldo,
                                                 size_t aStr, size_t oStr) {
  __shared__ short As[128][40];
  __shared__ short Bs[128][40];
  A += (size_t)blockIdx.z * aStr;
  size_t obase = (size_t)blockIdx.z * oStr;
  int tid = threadIdx.x;
  int n0 = blockIdx.x * 128, m0 = blockIdx.y * 128;
  int lane = tid & 63, wv = tid >> 6;
  int wm = wv & 1, wn = wv >> 1;
  int lm = lane & 15, g = lane >> 4;
  f32x4 acc[4][4] = {};
  int r1 = tid >> 2, kq = tid & 3;
  int r2 = r1 + 64;
  for (int k0 = 0; k0 < K; k0 += 32) {
    *(s16x8*)&As[r1][kq * 8] = *(const s16x8*)(A + (size_t)(m0 + r1) * K + k0 + kq * 8);
    *(s16x8*)&As[r2][kq * 8] = *(const s16x8*)(A + (size_t)(m0 + r2) * K + k0 + kq * 8);
    s16x8 z = {0, 0, 0, 0, 0, 0, 0, 0};
    s16x8 b1 = z, b2 = z;
    if (n0 + r1 < N) b1 = *(const s16x8*)(W + (size_t)(n0 + r1) * K + k0 + kq * 8);
    if (n0 + r2 < N) b2 = *(const s16x8*)(W + (size_t)(n0 + r2) * K + k0 + kq * 8);
    *(s16x8*)&Bs[r1][kq * 8] = b1;
    *(s16x8*)&Bs[r2][kq * 8] = b2;
    __syncthreads();
    s16x8 af[4], bf[4];
#pragma unroll
    for (int mt = 0; mt < 4; ++mt)
      af[mt] = *(const s16x8*)&As[wm * 64 + mt * 16 + lm][g * 8];
#pragma unroll
    for (int nt = 0; nt < 4; ++nt)
      bf[nt] = *(const s16x8*)&Bs[wn * 64 + nt * 16 + lm][g * 8];
#pragma unroll
    for (int mt = 0; mt < 4; ++mt)
#pragma unroll
      for (int nt = 0; nt < 4; ++nt)
        acc[mt][nt] = __builtin_amdgcn_mfma_f32_16x16x32_bf16(af[mt], bf[nt],
                                                              acc[mt][nt], 0, 0, 0);
    __syncthreads();
  }
#pragma unroll
  for (int nt = 0; nt < 4; ++nt) {
    int n = n0 + wn * 64 + nt * 16 + lm;
    if (n >= N) continue;
    float bs = BIAS ? bias[n] : 0.f;
#pragma unroll
    for (int mt = 0; mt < 4; ++mt) {
#pragma unroll
      for (int rg = 0; rg < 4; ++rg) {
        int m = m0 + wm * 64 + mt * 16 + g * 4 + rg;
        float v = acc[mt][nt][rg] + bs;
        if (GELU) v = gelu_f(v);
        size_t idx = obase + (TOUT ? ((size_t)n * ldo + m) : ((size_t)m * ldo + n));
        if (OBF)
          ((bf16_t*)outp)[idx] = f2bf(v);
        else
          ((float*)outp)[idx] = v;
      }
    }
  }
}

// fused k/v projections: z=0 -> k, z=1 -> v. M=400, N=256, K=256.
__global__ __launch_bounds__(256) void gemm_kv(const float* __restrict__ cin,
                                               const float* __restrict__ kw,
                                               const float* __restrict__ kbias,
                                               const float* __restrict__ vw,
                                               const float* __restrict__ vbias,
                                               float* __restrict__ kout,
                                               float* __restrict__ vout) {
  const float* Wm = blockIdx.z ? vw : kw;
  const float* bias = blockIdx.z ? vbias : kbias;
  float* outp = blockIdx.z ? vout : kout;
  const int M = 400, N = 256, K = 256;
  __shared__ float As[16][68];
  __shared__ float Ws[16][68];
  int tid = threadIdx.x;
  int n0 = blockIdx.x * 64, m0 = blockIdx.y * 64;
  int txn = tid & 15, tym = tid >> 4;
  int mi = tid >> 2, kq = (tid & 3) * 4;
  float acc[4][4] = {};
  for (int k0 = 0; k0 < K; k0 += 16) {
    float4 av = {0, 0, 0, 0}, wvv = {0, 0, 0, 0};
    if (m0 + mi < M) av = *(const float4*)&cin[(size_t)(m0 + mi) * K + k0 + kq];
    if (n0 + mi < N) wvv = *(const float4*)&Wm[(size_t)(n0 + mi) * K + k0 + kq];
    As[kq + 0][mi] = av.x; As[kq + 1][mi] = av.y; As[kq + 2][mi] = av.z; As[kq + 3][mi] = av.w;
    Ws[kq + 0][mi] = wvv.x; Ws[kq + 1][mi] = wvv.y; Ws[kq + 2][mi] = wvv.z; Ws[kq + 3][mi] = wvv.w;
    __syncthreads();
#pragma unroll
    for (int ki = 0; ki < 16; ++ki) {
      float4 a4 = *(const float4*)&As[ki][tym * 4];
      float4 w4 = *(const float4*)&Ws[ki][txn * 4];
      float am[4] = {a4.x, a4.y, a4.z, a4.w};
      float wn[4] = {w4.x, w4.y, w4.z, w4.w};
#pragma unroll
      for (int i = 0; i < 4; ++i)
#pragma unroll
        for (int j = 0; j < 4; ++j) acc[i][j] += am[i] * wn[j];
    }
    __syncthreads();
  }
#pragma unroll
  for (int i = 0; i < 4; ++i) {
    int m = m0 + tym * 4 + i;
    if (m >= M) continue;
#pragma unroll
    for (int j = 0; j < 4; ++j) {
      int n = n0 + txn * 4 + j;
      outp[(size_t)m * 256 + n] = acc[i][j] + bias[n];
    }
  }
}

// 1600 rows of 4096 bf16, softmax in place; thread owns 16 contiguous elems
__global__ __launch_bounds__(256) void softmax_rows(bf16_t* __restrict__ p) {
  __shared__ float sh[8];
  int tid = threadIdx.x;
  bf16_t* base = p + (size_t)blockIdx.x * NN + tid * 16;
  s16x8 a = *(const s16x8*)base;
  s16x8 b = *(const s16x8*)(base + 8);
  float vals[16];
#pragma unroll
  for (int j = 0; j < 8; ++j) {
    vals[j] = bf2f((bf16_t)a[j]);
    vals[8 + j] = bf2f((bf16_t)b[j]);
  }
  float mx = -1e30f;
#pragma unroll
  for (int j = 0; j < 16; ++j) mx = fmaxf(mx, vals[j]);
#pragma unroll
  for (int off = 32; off; off >>= 1) mx = fmaxf(mx, __shfl_xor(mx, off, 64));
  if ((tid & 63) == 0) sh[tid >> 6] = mx;
  __syncthreads();
  mx = fmaxf(fmaxf(sh[0], sh[1]), fmaxf(sh[2], sh[3]));
  float s = 0.f;
#pragma unroll
  for (int j = 0; j < 16; ++j) {
    vals[j] = expf(vals[j] - mx);
    s += vals[j];
  }
#pragma unroll
  for (int off = 32; off; off >>= 1) s += __shfl_xor(s, off, 64);
  if ((tid & 63) == 0) sh[4 + (tid >> 6)] = s;
  __syncthreads();
  s = sh[4] + sh[5] + sh[6] + sh[7];
  float inv = 1.f / s;
  s16x8 oa, ob;
#pragma unroll
  for (int j = 0; j < 8; ++j) {
    oa[j] = (short)f2bf(vals[j] * inv);
    ob[j] = (short)f2bf(vals[8 + j] * inv);
  }
  *(s16x8*)base = oa;
  *(s16x8*)(base + 8) = ob;
}

// center via MFMA split-K: partial[nc][bt][kc][c] = sum_{n in chunk nc} soft*xt.
// A = soft rows (kc, stride 16*NN), B = xtb transposed in LDS staging.
// grid (2 c-halves, 16 bt, 4 nc).
__global__ __launch_bounds__(256) void center_mfma(const bf16_t* __restrict__ soft,
                                                   const bf16_t* __restrict__ xtb,
                                                   float* __restrict__ partial) {
  int c0 = blockIdx.x * 128;
  int bt = blockIdx.y;
  int nc = blockIdx.z;
  int tid = threadIdx.x;
  int lane = tid & 63, wv = tid >> 6;
  int wm = wv & 1, wn = wv >> 1;
  int lm = lane & 15, g = lane >> 4;
  __shared__ short As[128][40];
  __shared__ short Bs[128][40];
  f32x4 acc[4][4] = {};
  int r1 = tid >> 2, kq = tid & 3;
  int r2 = r1 + 64;
  int bk = tid & 31, bc = (tid >> 5) * 16;
  const bf16_t* sb = soft + (size_t)bt * NN + (size_t)nc * 1024;
  const bf16_t* xb = xtb + ((size_t)bt * NN + (size_t)nc * 1024) * CC + c0;
  for (int k0 = 0; k0 < 1024; k0 += 32) {
    // A: row kc at global stride 16*NN; rows >= 100 left stale (outputs guarded)
    *(s16x8*)&As[r1][kq * 8] =
        *(const s16x8*)(sb + (size_t)r1 * (BT * NN) + k0 + kq * 8);
    if (r2 < KCC)
      *(s16x8*)&As[r2][kq * 8] =
          *(const s16x8*)(sb + (size_t)r2 * (BT * NN) + k0 + kq * 8);
    // B: transpose xtb[k][c] -> Bs[c][k] (thread: k=bk, 16 c at bc)
    s16x8 v0 = *(const s16x8*)(xb + (size_t)(k0 + bk) * CC + bc);
    s16x8 v1 = *(const s16x8*)(xb + (size_t)(k0 + bk) * CC + bc + 8);
#pragma unroll
    for (int j = 0; j < 8; ++j) Bs[bc + j][bk] = v0[j];
#pragma unroll
    for (int j = 0; j < 8; ++j) Bs[bc + 8 + j][bk] = v1[j];
    __syncthreads();
    s16x8 af[4], bf[4];
#pragma unroll
    for (int mt = 0; mt < 4; ++mt)
      af[mt] = *(const s16x8*)&As[wm * 64 + mt * 16 + lm][g * 8];
#pragma unroll
    for (int nt = 0; nt < 4; ++nt)
      bf[nt] = *(const s16x8*)&Bs[wn * 64 + nt * 16 + lm][g * 8];
#pragma unroll
    for (int mt = 0; mt < 4; ++mt)
#pragma unroll
      for (int nt = 0; nt < 4; ++nt)
        acc[mt][nt] = __builtin_amdgcn_mfma_f32_16x16x32_bf16(af[mt], bf[nt],
                                                              acc[mt][nt], 0, 0, 0);
    __syncthreads();
  }
  size_t obase = ((size_t)nc * BT + bt) * (KCC * CC);
#pragma unroll
  for (int nt = 0; nt < 4; ++nt) {
    int c = c0 + wn * 64 + nt * 16 + lm;
#pragma unroll
    for (int mt = 0; mt < 4; ++mt) {
#pragma unroll
      for (int rg = 0; rg < 4; ++rg) {
        int m = wm * 64 + mt * 16 + g * 4 + rg;
        if (m < KCC) partial[obase + (size_t)m * CC + c] = acc[mt][nt][rg];
      }
    }
  }
}

// cosine-sim gating + LN -> cin[b][kc][c]; reduces 4 n-chunk partials
__global__ __launch_bounds__(256) void sim_cin(const float* __restrict__ partial,
                                               const float* __restrict__ alpha_p,
                                               const float* __restrict__ beta_p,
                                               const float* __restrict__ lnw,
                                               const float* __restrict__ lnb,
                                               float* __restrict__ cin) {
  int b = blockIdx.x / KCC, kc = blockIdx.x % KCC;
  int c = threadIdx.x;
  float p0 = 0.f, p1 = 0.f, p2 = 0.f, lst = 0.f;
#pragma unroll
  for (int nc = 0; nc < 4; ++nc) {
    size_t base = ((size_t)nc * BT) * KCC * CC;
    p0 += partial[base + ((size_t)(b * 4 + 0) * KCC + kc) * CC + c];
    p1 += partial[base + ((size_t)(b * 4 + 1) * KCC + kc) * CC + c];
    p2 += partial[base + ((size_t)(b * 4 + 2) * KCC + kc) * CC + c];
    lst += partial[base + ((size_t)(b * 4 + 3) * KCC + kc) * CC + c];
  }
  float ll = block_sum256(lst * lst);
  float q0 = block_sum256(p0 * p0);
  float q1 = block_sum256(p1 * p1);
  float q2 = block_sum256(p2 * p2);
  float d0 = block_sum256(lst * p0);
  float d1 = block_sum256(lst * p1);
  float d2 = block_sum256(lst * p2);
  float alpha = alpha_p[0], beta = beta_p[0];
  float nl = sqrtf(ll);
  float c0 = 1.f / (1.f + expf(-(beta + alpha * (d0 / fmaxf(nl * sqrtf(q0), 1e-8f)))));
  float c1 = 1.f / (1.f + expf(-(beta + alpha * (d1 / fmaxf(nl * sqrtf(q1), 1e-8f)))));
  float c2 = 1.f / (1.f + expf(-(beta + alpha * (d2 / fmaxf(nl * sqrtf(q2), 1e-8f)))));
  float v = lst + c0 * p0 + c1 * p1 + c2 * p2;
  float m = block_sum256(v) * (1.f / CC);
  float dv = v - m;
  float var = block_sum256(dv * dv) * (1.f / CC);
  cin[((size_t)b * KCC + kc) * CC + c] = dv * rsqrtf(var + 1e-5f) * lnw[c] + lnb[c];
}

// attention v2: block = (8 query rows, b). K tiled through LDS, V read once.
__global__ __launch_bounds__(256) void attn2(const float* __restrict__ q,
                                             const float* __restrict__ kb,
                                             const float* __restrict__ vb,
                                             bf16_t* __restrict__ ob) {
  int b = blockIdx.y;
  int n0 = blockIdx.x * 8;
  int tid = threadIdx.x;
  __shared__ float qs[8][256];
  __shared__ float Ks[32][257];
  __shared__ float sc[8][8][104];
#pragma unroll
  for (int r = 0; r < 8; ++r)
    qs[r][tid] = q[((size_t)b * NN + n0 + r) * CC + tid] * 0.17677669529663687f;
  int nn = tid >> 5, kcl = tid & 31;
  for (int kt = 0; kt < 4; ++kt) {
    int kbase = kt * 32;
    int rows = (kbase + 32 <= KCC) ? 32 : (KCC - kbase);
    __syncthreads();
    for (int idx = tid; idx < rows * 256; idx += 256) {
      int rr = idx >> 8, cc = idx & 255;
      Ks[rr][cc] = kb[((size_t)b * KCC + kbase + rr) * CC + cc];
    }
    __syncthreads();
    if (kcl < rows) {
#pragma unroll
      for (int h = 0; h < NHH; ++h) {
        float s = 0.f;
#pragma unroll
        for (int d = 0; d < HDD; ++d) s += qs[nn][h * HDD + d] * Ks[kcl][h * HDD + d];
        sc[nn][h][kbase + kcl] = s;
      }
    }
  }
  __syncthreads();
  {
    int tnn = tid >> 5, th = (tid >> 2) & 7, j = tid & 3;
    float mx = -1e30f;
    for (int kc = j * 25; kc < j * 25 + 25; ++kc) mx = fmaxf(mx, sc[tnn][th][kc]);
    mx = fmaxf(mx, __shfl_xor(mx, 1, 64));
    mx = fmaxf(mx, __shfl_xor(mx, 2, 64));
    float sm = 0.f;
    for (int kc = j * 25; kc < j * 25 + 25; ++kc) {
      float e = expf(sc[tnn][th][kc] - mx);
      sc[tnn][th][kc] = e;
      sm += e;
    }
    sm += __shfl_xor(sm, 1, 64);
    sm += __shfl_xor(sm, 2, 64);
    float inv = 1.f / sm;
    for (int kc = j * 25; kc < j * 25 + 25; ++kc) sc[tnn][th][kc] *= inv;
  }
  __syncthreads();
  float o[8] = {0, 0, 0, 0, 0, 0, 0, 0};
  int h = tid >> 5;
  for (int kc = 0; kc < KCC; ++kc) {
    float v = vb[((size_t)b * KCC + kc) * CC + tid];
#pragma unroll
    for (int r = 0; r < 8; ++r) o[r] += sc[r][h][kc] * v;
  }
#pragma unroll
  for (int r = 0; r < 8; ++r)
    ob[((size_t)b * NN + n0 + r) * CC + tid] = f2bf(o[r]);
}

// dst[row][c] = res[row][c] + LN(y[row][:])[c]; WB: also write bf16 copy
template <int WB>
__global__ __launch_bounds__(256) void add_ln(const float* __restrict__ res,
                                              const float* __restrict__ y,
                                              const float* __restrict__ lnw,
                                              const float* __restrict__ lnb,
                                              float* __restrict__ dst,
                                              bf16_t* __restrict__ dst_b) {
  size_t row = blockIdx.x;
  int c = threadIdx.x;
  float v = y[row * CC + c];
  float m = block_sum256(v) * (1.f / CC);
  float dv = v - m;
  float var = block_sum256(dv * dv) * (1.f / CC);
  float o = res[row * CC + c] + dv * rsqrtf(var + 1e-5f) * lnw[c] + lnb[c];
  dst[row * CC + c] = o;
  if (WB) dst_b[row * CC + c] = f2bf(o);
}

// depthwise 3x3 + bias + gelu, 2 batches per launch
__global__ __launch_bounds__(256) void dwconv_kernel(const bf16_t* __restrict__ y1,
                                                     const float* __restrict__ dww,
                                                     const float* __restrict__ dwb,
                                                     bf16_t* __restrict__ y2c, int b0) {
  int bb = blockIdx.x >> 12;
  int n = blockIdx.x & 4095;
  int b = b0 + bb;
  int h = n >> 6, w = n & 63;
  int c40 = threadIdx.x * 4;
  float wreg[4][9];
#pragma unroll
  for (int j = 0; j < 4; ++j)
#pragma unroll
    for (int t2 = 0; t2 < 9; ++t2) wreg[j][t2] = dww[(size_t)(c40 + j) * 9 + t2];
  float acc[4] = {0, 0, 0, 0};
#pragma unroll
  for (int dy = 0; dy < 3; ++dy) {
    int r = h + dy - 1;
    if (r < 0 || r >= HH) continue;
#pragma unroll
    for (int dx = 0; dx < 3; ++dx) {
      int cl = w + dx - 1;
      if (cl < 0 || cl >= 64) continue;
      ushort4 u = *(const ushort4*)(y1 + ((size_t)b * NN + r * 64 + cl) * C4 + c40);
      int t2 = dy * 3 + dx;
      acc[0] += bf2f(u.x) * wreg[0][t2];
      acc[1] += bf2f(u.y) * wreg[1][t2];
      acc[2] += bf2f(u.z) * wreg[2][t2];
      acc[3] += bf2f(u.w) * wreg[3][t2];
    }
  }
  ushort4 o;
  o.x = f2bf(gelu_f(acc[0] + dwb[c40 + 0]));
  o.y = f2bf(gelu_f(acc[1] + dwb[c40 + 1]));
  o.z = f2bf(gelu_f(acc[2] + dwb[c40 + 2]));
  o.w = f2bf(gelu_f(acc[3] + dwb[c40 + 3]));
  *(ushort4*)(y2c + ((size_t)bb * NN + n) * C4 + c40) = o;
}

extern "C" void kernel_launch(void* const* d_in, const int* in_sizes, int n_in,
                              void* d_out, int out_size, void* d_ws, size_t ws_size,
                              hipStream_t stream) {
  const float* x = (const float*)d_in[0];
  const float* mem = (const float*)d_in[1];
  const float* conv1_w = (const float*)d_in[2];
  const float* conv1_b = (const float*)d_in[3];
  const float* conv2_w = (const float*)d_in[4];
  const float* conv2_b = (const float*)d_in[5];
  const float* conv3_w = (const float*)d_in[6];
  const float* sim_a = (const float*)d_in[7];
  const float* sim_b = (const float*)d_in[8];
  const float* ln_w = (const float*)d_in[9];
  const float* ln_b = (const float*)d_in[10];
  const float* q_w = (const float*)d_in[11];
  const float* q_b = (const float*)d_in[12];
  const float* k_w = (const float*)d_in[13];
  const float* k_b = (const float*)d_in[14];
  const float* v_w = (const float*)d_in[15];
  const float* v_b = (const float*)d_in[16];
  const float* proj_w = (const float*)d_in[17];
  const float* proj_b = (const float*)d_in[18];
  const float* fc1_w = (const float*)d_in[19];
  const float* fc1_b = (const float*)d_in[20];
  const float* dw_w = (const float*)d_in[21];
  const float* dw_b = (const float*)d_in[22];
  const float* fc2_w = (const float*)d_in[23];
  const float* fc2_b = (const float*)d_in[24];

  // Workspace: 101,353,472 B = 96.7 MB (< 104 MB known-good).
  char* base = (char*)d_ws;
  bf16_t* xtb = (bf16_t*)(base);
  bf16_t* by1 = (bf16_t*)(base);
  bf16_t* bh1 = (bf16_t*)(base + 33554432);
  float* qb = (float*)(base + 33554432);
  float* outb = (float*)(base + 33554432);
  float* partial = (float*)(base + 50331648);
  float* pbuf = (float*)(base + 50331648);
  float* yout = (float*)(base + 50331648);
  bf16_t* czt = (bf16_t*)(base + 67108864);
  bf16_t* obz = (bf16_t*)(base + 67108864);
  bf16_t* outb_b = (bf16_t*)(base + 67108864);
  bf16_t* wtb = (bf16_t*)(base + 80216064);
  bf16_t* h2c = (bf16_t*)(base + 80216064);
  bf16_t* y2c = (bf16_t*)(base + 80216064);
  bf16_t* wbz = (bf16_t*)(base + 96993280);
  float* cin = (float*)(base + 100124672);
  float* kb = (float*)(base + 100534272);
  float* vb = (float*)(base + 100943872);
  float* dout = (float*)d_out;

  bf16_t* conv2_wb = wbz;            // 65536
  bf16_t* conv3_wb = wbz + 65536;    // 25600
  bf16_t* q_wb = wbz + 91136;        // 65536
  bf16_t* proj_wb = wbz + 156672;    // 65536
  bf16_t* fc1_wb = wbz + 222208;     // 262144
  bf16_t* fc2_wb = wbz + 484352;     // 262144

  prologue<<<22436, 256, 0, stream>>>(x, mem, xtb, conv1_w, wtb, conv2_w, conv3_w,
                                      q_w, proj_w, fc1_w, fc2_w, wbz);
  conv1_mfma<<<1024, 256, 0, stream>>>(xtb, wtb, conv1_b, bh1);
  for (int i = 0; i < 2; ++i) {
    gemm_mfma<1, 1, 0, 1><<<dim3(2, 256, 1), 256, 0, stream>>>(
        bh1 + (size_t)i * 32768 * CC, conv2_wb, conv2_b, h2c, 32768, 256, 256, 256, 0, 0);
    gemm_mfma<0, 0, 1, 1><<<dim3(1, 256, 1), 256, 0, stream>>>(
        h2c, conv3_wb, nullptr, czt + (size_t)i * 32768, 32768, 100, 256, 65536, 0, 0);
  }
  softmax_rows<<<1600, 256, 0, stream>>>(czt);
  center_mfma<<<dim3(2, 16, 4), 256, 0, stream>>>(czt, xtb, partial);
  sim_cin<<<400, 256, 0, stream>>>(partial, sim_a, sim_b, ln_w, ln_b, cin);
  gemm_mfma<0, 1, 0, 0><<<dim3(2, 32, 4), 256, 0, stream>>>(
      xtb + (size_t)3 * NN * CC, q_wb, q_b, qb, 4096, 256, 256, 256,
      (size_t)4 * NN * CC, (size_t)NN * CC);
  gemm_kv<<<dim3(4, 7, 2), 256, 0, stream>>>(cin, k_w, k_b, v_w, v_b, kb, vb);
  attn2<<<dim3(512, 4), 256, 0, stream>>>(qb, kb, vb, obz);
  gemm_mfma<0, 1, 0, 0><<<dim3(2, 128, 1), 256, 0, stream>>>(obz, proj_wb, proj_b, pbuf,
                                                             16384, 256, 256, 256, 0, 0);
  add_ln<1><<<16384, 256, 0, stream>>>(x, pbuf, ln_w, ln_b, outb, outb_b);
  gemm_mfma<0, 1, 0, 1><<<dim3(8, 128, 1), 256, 0, stream>>>(outb_b, fc1_wb, fc1_b, by1,
                                                             16384, 1024, 256, 1024, 0, 0);
  for (int c = 0; c < 2; ++c) {
    dwconv_kernel<<<8192, 256, 0, stream>>>(by1, dw_w, dw_b, y2c, c * 2);
    gemm_mfma<0, 1, 0, 0><<<dim3(2, 32, 2), 256, 0, stream>>>(
        y2c, fc2_wb, fc2_b, yout + (size_t)c * 2 * NN * CC, 4096, 256, 1024, 256,
        (size_t)NN * C4, (size_t)NN * CC);
  }
  add_ln<0><<<16384, 256, 0, stream>>>(outb, yout, ln_w, ln_b, dout, nullptr);
}

// Round 9
// 888.285 us; speedup vs baseline: 8.7734x; 1.0647x over previous
//
#include <hip/hip_runtime.h>
#include <math.h>

#define NN 4096
#define CC 256
#define HH 64
#define BT 16
#define KCC 100
#define NHH 8
#define HDD 32
#define C4 1024

typedef unsigned short bf16_t;
typedef short s16x8 __attribute__((ext_vector_type(8)));
typedef float f32x4 __attribute__((ext_vector_type(4)));

__device__ __forceinline__ float bf2f(bf16_t h) {
  return __uint_as_float(((unsigned)h) << 16);
}
__device__ __forceinline__ bf16_t f2bf(float f) {
  unsigned u = __float_as_uint(f);
  return (bf16_t)((u + 0x7FFFu + ((u >> 16) & 1u)) >> 16);
}

__device__ __forceinline__ float gelu_f(float x) {
  return 0.5f * x * (1.0f + erff(x * 0.7071067811865475f));
}

// async global->LDS, 16 B per lane; lds dest = wave-uniform base + lane*16
__device__ __forceinline__ void g2l16(const void* g, void* l) {
  __builtin_amdgcn_global_load_lds((const __attribute__((address_space(1))) void*)g,
                                   (__attribute__((address_space(3))) void*)l, 16, 0, 0);
}

__device__ __forceinline__ float block_sum256(float v) {
  __shared__ float sh[4];
#pragma unroll
  for (int off = 32; off; off >>= 1) v += __shfl_xor(v, off, 64);
  __syncthreads();
  if ((threadIdx.x & 63) == 0) sh[threadIdx.x >> 6] = v;
  __syncthreads();
  return sh[0] + sh[1] + sh[2] + sh[3];
}

__device__ __forceinline__ const float* xt_base(const float* x, const float* mem, int bt) {
  int b = bt >> 2, tt = bt & 3;
  return (tt < 3) ? (mem + (size_t)(b * 3 + tt) * NN * CC)
                  : (x + (size_t)b * NN * CC);
}

// fused prologue: [0,16384) build xtb; [16384,19520) transpose conv1_w -> wtb;
// [19520,22436) convert 6 weight mats to bf16 pack wbz.
__global__ __launch_bounds__(256) void prologue(const float* __restrict__ x,
                                                const float* __restrict__ mem,
                                                bf16_t* __restrict__ xtb,
                                                const float* __restrict__ w1,
                                                bf16_t* __restrict__ wtb,
                                                const float* __restrict__ c2w,
                                                const float* __restrict__ c3w,
                                                const float* __restrict__ qw,
                                                const float* __restrict__ pw,
                                                const float* __restrict__ f1w,
                                                const float* __restrict__ f2w,
                                                bf16_t* __restrict__ wbz) {
  int bid = blockIdx.x;
  int tid = threadIdx.x;
  if (bid < 16384) {
    int i = bid * 256 + tid;
    int c4 = i & 63;
    int n = (i >> 6) & 4095;
    int bt = i >> 18;
    const float* src = xt_base(x, mem, bt) + (size_t)n * CC + c4 * 4;
    float4 v = *(const float4*)src;
    ushort4 o;
    o.x = f2bf(v.x); o.y = f2bf(v.y); o.z = f2bf(v.z); o.w = f2bf(v.w);
    *(ushort4*)(xtb + (size_t)i * 4) = o;
  } else if (bid < 19520) {
    int i = (bid - 16384) * 256 + tid;  // < 802816 exactly
    int cj = i & 7;
    int t = i >> 3;
    int co = t & 63; t >>= 6;
    int oc = t & 3; t >>= 2;
    int kx = t % 7; t /= 7;
    int cq = t & 3; t >>= 2;
    int cg = t & 7;
    int ky = t >> 3;
    int ci = cg * 32 + oc * 8 + cj;
    int cog = cq * 64 + co;
    wtb[i] = f2bf(w1[((size_t)(cog * CC + ci) * 7 + ky) * 7 + kx]);
  } else {
    int j = (bid - 19520) * 256 + tid;  // < 746496 exactly
    float v;
    if (j < 65536) v = c2w[j];
    else if (j < 91136) v = c3w[j - 65536];
    else if (j < 156672) v = qw[j - 91136];
    else if (j < 222208) v = pw[j - 156672];
    else if (j < 484352) v = f1w[j - 222208];
    else v = f2w[j - 484352];
    wbz[j] = f2bf(v);
  }
}

// conv1 v4: async-LDS MFMA implicit GEMM, cq-MAJOR grid so 256 consecutive
// blocks share one 1.6 MB W slice (per-XCD L2-resident; was thrashing 6.4 MB).
__global__ __launch_bounds__(256, 2) void conv1_mfma(const bf16_t* __restrict__ xtb,
                                                     const bf16_t* __restrict__ wtb,
                                                     const float* __restrict__ bias,
                                                     bf16_t* __restrict__ h1) {
  int cq = blockIdx.x >> 8;            // slowest: W slice phase
  int bt = (blockIdx.x >> 4) & 15;
  int h0 = (blockIdx.x & 15) * 4;
  int co0 = cq * 64;
  int tid = threadIdx.x;
  int wv = tid >> 6;
  int lane = tid & 63;
  int lm = lane & 15;
  int g = lane >> 4;
  __shared__ short As[10][4][70][8];
  __shared__ short Ws[7][4][64][8];
  {
    s16x8 z = {0, 0, 0, 0, 0, 0, 0, 0};
    for (int i = tid; i < 2800; i += 256) *(s16x8*)((short*)As + i * 8) = z;
  }
  __syncthreads();
  f32x4 acc[4][4] = {};
  const bf16_t* xb = xtb + (size_t)bt * (NN * CC);
  for (int cig = 0; cig < 8; ++cig) {
    int ci0 = cig * 32;
    for (int t = wv; t < 40; t += 4) {
      int rr = t >> 2, go = t & 3;
      int r = h0 - 3 + rr;
      if (r >= 0 && r < HH) {
        const bf16_t* gsrc = xb + ((size_t)(r * 64 + lane)) * CC + ci0 + go * 8;
        g2l16(gsrc, &As[rr][go][3][0]);
      }
    }
    for (int ky = 0; ky < 7; ++ky) {
      const bf16_t* wk = wtb + ((size_t)((ky * 8 + cig) * 4 + cq)) * (1792 * 8);
      for (int t = wv; t < 28; t += 4)
        g2l16(wk + (size_t)t * 512 + lane * 8, (short*)Ws + t * 512);
      __syncthreads();
#pragma unroll
      for (int kx = 0; kx < 7; ++kx) {
        s16x8 af[4], bf[4];
#pragma unroll
        for (int mt = 0; mt < 4; ++mt)
          af[mt] = *(const s16x8*)&As[wv + ky][g][mt * 16 + lm + kx][0];
#pragma unroll
        for (int nt = 0; nt < 4; ++nt)
          bf[nt] = *(const s16x8*)&Ws[kx][g][nt * 16 + lm][0];
#pragma unroll
        for (int mt = 0; mt < 4; ++mt)
#pragma unroll
          for (int nt = 0; nt < 4; ++nt)
            acc[mt][nt] = __builtin_amdgcn_mfma_f32_16x16x32_bf16(af[mt], bf[nt],
                                                                  acc[mt][nt], 0, 0, 0);
      }
      __syncthreads();
    }
  }
  int row = h0 + wv;
  const size_t xbase = (size_t)bt * (NN * CC);
#pragma unroll
  for (int nt = 0; nt < 4; ++nt) {
    int co = co0 + nt * 16 + lm;
    float bs = bias[co];
#pragma unroll
    for (int mt = 0; mt < 4; ++mt) {
#pragma unroll
      for (int rg = 0; rg < 4; ++rg) {
        int col = mt * 16 + g * 4 + rg;
        float vv = acc[mt][nt][rg] + bs;
        h1[xbase + (size_t)(row * 64 + col) * CC + co] = f2bf(gelu_f(vv));
      }
    }
  }
}

// bf16 MFMA GEMM with optional z-slab batching (unchanged)
template <int GELU, int BIAS, int TOUT, int OBF>
__global__ __launch_bounds__(256) void gemm_mfma(const bf16_t* __restrict__ A,
                                                 const bf16_t* __restrict__ W,
                                                 const float* __restrict__ bias,
                                                 void* __restrict__ outp,
                                                 int M, int N, int K, int ldo,
                                                 size_t aStr, size_t oStr) {
  __shared__ short As[128][40];
  __shared__ short Bs[128][40];
  A += (size_t)blockIdx.z * aStr;
  size_t obase = (size_t)blockIdx.z * oStr;
  int tid = threadIdx.x;
  int n0 = blockIdx.x * 128, m0 = blockIdx.y * 128;
  int lane = tid & 63, wv = tid >> 6;
  int wm = wv & 1, wn = wv >> 1;
  int lm = lane & 15, g = lane >> 4;
  f32x4 acc[4][4] = {};
  int r1 = tid >> 2, kq = tid & 3;
  int r2 = r1 + 64;
  for (int k0 = 0; k0 < K; k0 += 32) {
    *(s16x8*)&As[r1][kq * 8] = *(const s16x8*)(A + (size_t)(m0 + r1) * K + k0 + kq * 8);
    *(s16x8*)&As[r2][kq * 8] = *(const s16x8*)(A + (size_t)(m0 + r2) * K + k0 + kq * 8);
    s16x8 z = {0, 0, 0, 0, 0, 0, 0, 0};
    s16x8 b1 = z, b2 = z;
    if (n0 + r1 < N) b1 = *(const s16x8*)(W + (size_t)(n0 + r1) * K + k0 + kq * 8);
    if (n0 + r2 < N) b2 = *(const s16x8*)(W + (size_t)(n0 + r2) * K + k0 + kq * 8);
    *(s16x8*)&Bs[r1][kq * 8] = b1;
    *(s16x8*)&Bs[r2][kq * 8] = b2;
    __syncthreads();
    s16x8 af[4], bf[4];
#pragma unroll
    for (int mt = 0; mt < 4; ++mt)
      af[mt] = *(const s16x8*)&As[wm * 64 + mt * 16 + lm][g * 8];
#pragma unroll
    for (int nt = 0; nt < 4; ++nt)
      bf[nt] = *(const s16x8*)&Bs[wn * 64 + nt * 16 + lm][g * 8];
#pragma unroll
    for (int mt = 0; mt < 4; ++mt)
#pragma unroll
      for (int nt = 0; nt < 4; ++nt)
        acc[mt][nt] = __builtin_amdgcn_mfma_f32_16x16x32_bf16(af[mt], bf[nt],
                                                              acc[mt][nt], 0, 0, 0);
    __syncthreads();
  }
#pragma unroll
  for (int nt = 0; nt < 4; ++nt) {
    int n = n0 + wn * 64 + nt * 16 + lm;
    if (n >= N) continue;
    float bs = BIAS ? bias[n] : 0.f;
#pragma unroll
    for (int mt = 0; mt < 4; ++mt) {
#pragma unroll
      for (int rg = 0; rg < 4; ++rg) {
        int m = m0 + wm * 64 + mt * 16 + g * 4 + rg;
        float v = acc[mt][nt][rg] + bs;
        if (GELU) v = gelu_f(v);
        size_t idx = obase + (TOUT ? ((size_t)n * ldo + m) : ((size_t)m * ldo + n));
        if (OBF)
          ((bf16_t*)outp)[idx] = f2bf(v);
        else
          ((float*)outp)[idx] = v;
      }
    }
  }
}

// fused k/v projections: z=0 -> k, z=1 -> v. M=400, N=256, K=256.
__global__ __launch_bounds__(256) void gemm_kv(const float* __restrict__ cin,
                                               const float* __restrict__ kw,
                                               const float* __restrict__ kbias,
                                               const float* __restrict__ vw,
                                               const float* __restrict__ vbias,
                                               float* __restrict__ kout,
                                               float* __restrict__ vout) {
  const float* Wm = blockIdx.z ? vw : kw;
  const float* bias = blockIdx.z ? vbias : kbias;
  float* outp = blockIdx.z ? vout : kout;
  const int M = 400, N = 256, K = 256;
  __shared__ float As[16][68];
  __shared__ float Ws[16][68];
  int tid = threadIdx.x;
  int n0 = blockIdx.x * 64, m0 = blockIdx.y * 64;
  int txn = tid & 15, tym = tid >> 4;
  int mi = tid >> 2, kq = (tid & 3) * 4;
  float acc[4][4] = {};
  for (int k0 = 0; k0 < K; k0 += 16) {
    float4 av = {0, 0, 0, 0}, wvv = {0, 0, 0, 0};
    if (m0 + mi < M) av = *(const float4*)&cin[(size_t)(m0 + mi) * K + k0 + kq];
    if (n0 + mi < N) wvv = *(const float4*)&Wm[(size_t)(n0 + mi) * K + k0 + kq];
    As[kq + 0][mi] = av.x; As[kq + 1][mi] = av.y; As[kq + 2][mi] = av.z; As[kq + 3][mi] = av.w;
    Ws[kq + 0][mi] = wvv.x; Ws[kq + 1][mi] = wvv.y; Ws[kq + 2][mi] = wvv.z; Ws[kq + 3][mi] = wvv.w;
    __syncthreads();
#pragma unroll
    for (int ki = 0; ki < 16; ++ki) {
      float4 a4 = *(const float4*)&As[ki][tym * 4];
      float4 w4 = *(const float4*)&Ws[ki][txn * 4];
      float am[4] = {a4.x, a4.y, a4.z, a4.w};
      float wn[4] = {w4.x, w4.y, w4.z, w4.w};
#pragma unroll
      for (int i = 0; i < 4; ++i)
#pragma unroll
        for (int j = 0; j < 4; ++j) acc[i][j] += am[i] * wn[j];
    }
    __syncthreads();
  }
#pragma unroll
  for (int i = 0; i < 4; ++i) {
    int m = m0 + tym * 4 + i;
    if (m >= M) continue;
#pragma unroll
    for (int j = 0; j < 4; ++j) {
      int n = n0 + txn * 4 + j;
      outp[(size_t)m * 256 + n] = acc[i][j] + bias[n];
    }
  }
}

// 1600 rows of 4096 bf16, softmax in place; thread owns 16 contiguous elems
__global__ __launch_bounds__(256) void softmax_rows(bf16_t* __restrict__ p) {
  __shared__ float sh[8];
  int tid = threadIdx.x;
  bf16_t* base = p + (size_t)blockIdx.x * NN + tid * 16;
  s16x8 a = *(const s16x8*)base;
  s16x8 b = *(const s16x8*)(base + 8);
  float vals[16];
#pragma unroll
  for (int j = 0; j < 8; ++j) {
    vals[j] = bf2f((bf16_t)a[j]);
    vals[8 + j] = bf2f((bf16_t)b[j]);
  }
  float mx = -1e30f;
#pragma unroll
  for (int j = 0; j < 16; ++j) mx = fmaxf(mx, vals[j]);
#pragma unroll
  for (int off = 32; off; off >>= 1) mx = fmaxf(mx, __shfl_xor(mx, off, 64));
  if ((tid & 63) == 0) sh[tid >> 6] = mx;
  __syncthreads();
  mx = fmaxf(fmaxf(sh[0], sh[1]), fmaxf(sh[2], sh[3]));
  float s = 0.f;
#pragma unroll
  for (int j = 0; j < 16; ++j) {
    vals[j] = expf(vals[j] - mx);
    s += vals[j];
  }
#pragma unroll
  for (int off = 32; off; off >>= 1) s += __shfl_xor(s, off, 64);
  if ((tid & 63) == 0) sh[4 + (tid >> 6)] = s;
  __syncthreads();
  s = sh[4] + sh[5] + sh[6] + sh[7];
  float inv = 1.f / s;
  s16x8 oa, ob;
#pragma unroll
  for (int j = 0; j < 8; ++j) {
    oa[j] = (short)f2bf(vals[j] * inv);
    ob[j] = (short)f2bf(vals[8 + j] * inv);
  }
  *(s16x8*)base = oa;
  *(s16x8*)(base + 8) = ob;
}

// center via MFMA split-K (8 chunks of 512): partial[nc][bt][kc][c].
__global__ __launch_bounds__(256) void center_mfma(const bf16_t* __restrict__ soft,
                                                   const bf16_t* __restrict__ xtb,
                                                   float* __restrict__ partial) {
  int c0 = blockIdx.x * 128;
  int bt = blockIdx.y;
  int nc = blockIdx.z;
  int tid = threadIdx.x;
  int lane = tid & 63, wv = tid >> 6;
  int wm = wv & 1, wn = wv >> 1;
  int lm = lane & 15, g = lane >> 4;
  __shared__ short As[128][40];
  __shared__ short Bs[128][40];
  f32x4 acc[4][4] = {};
  int r1 = tid >> 2, kq = tid & 3;
  int r2 = r1 + 64;
  int bk = tid & 31, bc = (tid >> 5) * 16;
  const bf16_t* sb = soft + (size_t)bt * NN + (size_t)nc * 512;
  const bf16_t* xb = xtb + ((size_t)bt * NN + (size_t)nc * 512) * CC + c0;
  for (int k0 = 0; k0 < 512; k0 += 32) {
    *(s16x8*)&As[r1][kq * 8] =
        *(const s16x8*)(sb + (size_t)r1 * (BT * NN) + k0 + kq * 8);
    if (r2 < KCC)
      *(s16x8*)&As[r2][kq * 8] =
          *(const s16x8*)(sb + (size_t)r2 * (BT * NN) + k0 + kq * 8);
    s16x8 v0 = *(const s16x8*)(xb + (size_t)(k0 + bk) * CC + bc);
    s16x8 v1 = *(const s16x8*)(xb + (size_t)(k0 + bk) * CC + bc + 8);
#pragma unroll
    for (int j = 0; j < 8; ++j) Bs[bc + j][bk] = v0[j];
#pragma unroll
    for (int j = 0; j < 8; ++j) Bs[bc + 8 + j][bk] = v1[j];
    __syncthreads();
    s16x8 af[4], bf[4];
#pragma unroll
    for (int mt = 0; mt < 4; ++mt)
      af[mt] = *(const s16x8*)&As[wm * 64 + mt * 16 + lm][g * 8];
#pragma unroll
    for (int nt = 0; nt < 4; ++nt)
      bf[nt] = *(const s16x8*)&Bs[wn * 64 + nt * 16 + lm][g * 8];
#pragma unroll
    for (int mt = 0; mt < 4; ++mt)
#pragma unroll
      for (int nt = 0; nt < 4; ++nt)
        acc[mt][nt] = __builtin_amdgcn_mfma_f32_16x16x32_bf16(af[mt], bf[nt],
                                                              acc[mt][nt], 0, 0, 0);
    __syncthreads();
  }
  size_t obase = ((size_t)nc * BT + bt) * (KCC * CC);
#pragma unroll
  for (int nt = 0; nt < 4; ++nt) {
    int c = c0 + wn * 64 + nt * 16 + lm;
#pragma unroll
    for (int mt = 0; mt < 4; ++mt) {
#pragma unroll
      for (int rg = 0; rg < 4; ++rg) {
        int m = wm * 64 + mt * 16 + g * 4 + rg;
        if (m < KCC) partial[obase + (size_t)m * CC + c] = acc[mt][nt][rg];
      }
    }
  }
}

// cosine-sim gating + LN -> cin[b][kc][c]; reduces 8 n-chunk partials
__global__ __launch_bounds__(256) void sim_cin(const float* __restrict__ partial,
                                               const float* __restrict__ alpha_p,
                                               const float* __restrict__ beta_p,
                                               const float* __restrict__ lnw,
                                               const float* __restrict__ lnb,
                                               float* __restrict__ cin) {
  int b = blockIdx.x / KCC, kc = blockIdx.x % KCC;
  int c = threadIdx.x;
  float p0 = 0.f, p1 = 0.f, p2 = 0.f, lst = 0.f;
#pragma unroll
  for (int nc = 0; nc < 8; ++nc) {
    size_t base = ((size_t)nc * BT) * KCC * CC;
    p0 += partial[base + ((size_t)(b * 4 + 0) * KCC + kc) * CC + c];
    p1 += partial[base + ((size_t)(b * 4 + 1) * KCC + kc) * CC + c];
    p2 += partial[base + ((size_t)(b * 4 + 2) * KCC + kc) * CC + c];
    lst += partial[base + ((size_t)(b * 4 + 3) * KCC + kc) * CC + c];
  }
  float ll = block_sum256(lst * lst);
  float q0 = block_sum256(p0 * p0);
  float q1 = block_sum256(p1 * p1);
  float q2 = block_sum256(p2 * p2);
  float d0 = block_sum256(lst * p0);
  float d1 = block_sum256(lst * p1);
  float d2 = block_sum256(lst * p2);
  float alpha = alpha_p[0], beta = beta_p[0];
  float nl = sqrtf(ll);
  float c0 = 1.f / (1.f + expf(-(beta + alpha * (d0 / fmaxf(nl * sqrtf(q0), 1e-8f)))));
  float c1 = 1.f / (1.f + expf(-(beta + alpha * (d1 / fmaxf(nl * sqrtf(q1), 1e-8f)))));
  float c2 = 1.f / (1.f + expf(-(beta + alpha * (d2 / fmaxf(nl * sqrtf(q2), 1e-8f)))));
  float v = lst + c0 * p0 + c1 * p1 + c2 * p2;
  float m = block_sum256(v) * (1.f / CC);
  float dv = v - m;
  float var = block_sum256(dv * dv) * (1.f / CC);
  cin[((size_t)b * KCC + kc) * CC + c] = dv * rsqrtf(var + 1e-5f) * lnw[c] + lnb[c];
}

// attention v2: block = (8 query rows, b). K tiled through LDS, V read once.
__global__ __launch_bounds__(256) void attn2(const float* __restrict__ q,
                                             const float* __restrict__ kb,
                                             const float* __restrict__ vb,
                                             bf16_t* __restrict__ ob) {
  int b = blockIdx.y;
  int n0 = blockIdx.x * 8;
  int tid = threadIdx.x;
  __shared__ float qs[8][256];
  __shared__ float Ks[32][257];
  __shared__ float sc[8][8][104];
#pragma unroll
  for (int r = 0; r < 8; ++r)
    qs[r][tid] = q[((size_t)b * NN + n0 + r) * CC + tid] * 0.17677669529663687f;
  int nn = tid >> 5, kcl = tid & 31;
  for (int kt = 0; kt < 4; ++kt) {
    int kbase = kt * 32;
    int rows = (kbase + 32 <= KCC) ? 32 : (KCC - kbase);
    __syncthreads();
    for (int idx = tid; idx < rows * 256; idx += 256) {
      int rr = idx >> 8, cc = idx & 255;
      Ks[rr][cc] = kb[((size_t)b * KCC + kbase + rr) * CC + cc];
    }
    __syncthreads();
    if (kcl < rows) {
#pragma unroll
      for (int h = 0; h < NHH; ++h) {
        float s = 0.f;
#pragma unroll
        for (int d = 0; d < HDD; ++d) s += qs[nn][h * HDD + d] * Ks[kcl][h * HDD + d];
        sc[nn][h][kbase + kcl] = s;
      }
    }
  }
  __syncthreads();
  {
    int tnn = tid >> 5, th = (tid >> 2) & 7, j = tid & 3;
    float mx = -1e30f;
    for (int kc = j * 25; kc < j * 25 + 25; ++kc) mx = fmaxf(mx, sc[tnn][th][kc]);
    mx = fmaxf(mx, __shfl_xor(mx, 1, 64));
    mx = fmaxf(mx, __shfl_xor(mx, 2, 64));
    float sm = 0.f;
    for (int kc = j * 25; kc < j * 25 + 25; ++kc) {
      float e = expf(sc[tnn][th][kc] - mx);
      sc[tnn][th][kc] = e;
      sm += e;
    }
    sm += __shfl_xor(sm, 1, 64);
    sm += __shfl_xor(sm, 2, 64);
    float inv = 1.f / sm;
    for (int kc = j * 25; kc < j * 25 + 25; ++kc) sc[tnn][th][kc] *= inv;
  }
  __syncthreads();
  float o[8] = {0, 0, 0, 0, 0, 0, 0, 0};
  int h = tid >> 5;
  for (int kc = 0; kc < KCC; ++kc) {
    float v = vb[((size_t)b * KCC + kc) * CC + tid];
#pragma unroll
    for (int r = 0; r < 8; ++r) o[r] += sc[r][h][kc] * v;
  }
#pragma unroll
  for (int r = 0; r < 8; ++r)
    ob[((size_t)b * NN + n0 + r) * CC + tid] = f2bf(o[r]);
}

// dst[row][c] = res[row][c] + LN(y[row][:])[c]; WB: also write bf16 copy
template <int WB>
__global__ __launch_bounds__(256) void add_ln(const float* __restrict__ res,
                                              const float* __restrict__ y,
                                              const float* __restrict__ lnw,
                                              const float* __restrict__ lnb,
                                              float* __restrict__ dst,
                                              bf16_t* __restrict__ dst_b) {
  size_t row = blockIdx.x;
  int c = threadIdx.x;
  float v = y[row * CC + c];
  float m = block_sum256(v) * (1.f / CC);
  float dv = v - m;
  float var = block_sum256(dv * dv) * (1.f / CC);
  float o = res[row * CC + c] + dv * rsqrtf(var + 1e-5f) * lnw[c] + lnb[c];
  dst[row * CC + c] = o;
  if (WB) dst_b[row * CC + c] = f2bf(o);
}

// depthwise 3x3 + bias + gelu, all 4 batches (grid 16384)
__global__ __launch_bounds__(256) void dwconv_kernel(const bf16_t* __restrict__ y1,
                                                     const float* __restrict__ dww,
                                                     const float* __restrict__ dwb,
                                                     bf16_t* __restrict__ y2) {
  int b = blockIdx.x >> 12;
  int n = blockIdx.x & 4095;
  int h = n >> 6, w = n & 63;
  int c40 = threadIdx.x * 4;
  float wreg[4][9];
#pragma unroll
  for (int j = 0; j < 4; ++j)
#pragma unroll
    for (int t2 = 0; t2 < 9; ++t2) wreg[j][t2] = dww[(size_t)(c40 + j) * 9 + t2];
  float acc[4] = {0, 0, 0, 0};
#pragma unroll
  for (int dy = 0; dy < 3; ++dy) {
    int r = h + dy - 1;
    if (r < 0 || r >= HH) continue;
#pragma unroll
    for (int dx = 0; dx < 3; ++dx) {
      int cl = w + dx - 1;
      if (cl < 0 || cl >= 64) continue;
      ushort4 u = *(const ushort4*)(y1 + ((size_t)b * NN + r * 64 + cl) * C4 + c40);
      int t2 = dy * 3 + dx;
      acc[0] += bf2f(u.x) * wreg[0][t2];
      acc[1] += bf2f(u.y) * wreg[1][t2];
      acc[2] += bf2f(u.z) * wreg[2][t2];
      acc[3] += bf2f(u.w) * wreg[3][t2];
    }
  }
  ushort4 o;
  o.x = f2bf(gelu_f(acc[0] + dwb[c40 + 0]));
  o.y = f2bf(gelu_f(acc[1] + dwb[c40 + 1]));
  o.z = f2bf(gelu_f(acc[2] + dwb[c40 + 2]));
  o.w = f2bf(gelu_f(acc[3] + dwb[c40 + 3]));
  *(ushort4*)(y2 + ((size_t)b * NN + n) * C4 + c40) = o;
}

extern "C" void kernel_launch(void* const* d_in, const int* in_sizes, int n_in,
                              void* d_out, int out_size, void* d_ws, size_t ws_size,
                              hipStream_t stream) {
  const float* x = (const float*)d_in[0];
  const float* mem = (const float*)d_in[1];
  const float* conv1_w = (const float*)d_in[2];
  const float* conv1_b = (const float*)d_in[3];
  const float* conv2_w = (const float*)d_in[4];
  const float* conv2_b = (const float*)d_in[5];
  const float* conv3_w = (const float*)d_in[6];
  const float* sim_a = (const float*)d_in[7];
  const float* sim_b = (const float*)d_in[8];
  const float* ln_w = (const float*)d_in[9];
  const float* ln_b = (const float*)d_in[10];
  const float* q_w = (const float*)d_in[11];
  const float* q_b = (const float*)d_in[12];
  const float* k_w = (const float*)d_in[13];
  const float* k_b = (const float*)d_in[14];
  const float* v_w = (const float*)d_in[15];
  const float* v_b = (const float*)d_in[16];
  const float* proj_w = (const float*)d_in[17];
  const float* proj_b = (const float*)d_in[18];
  const float* fc1_w = (const float*)d_in[19];
  const float* fc1_b = (const float*)d_in[20];
  const float* dw_w = (const float*)d_in[21];
  const float* dw_b = (const float*)d_in[22];
  const float* fc2_w = (const float*)d_in[23];
  const float* fc2_b = (const float*)d_in[24];

  // Workspace: 101,353,472 B = 96.7 MB (< 104 MB known-good).
  char* base = (char*)d_ws;
  bf16_t* xtb = (bf16_t*)(base);
  bf16_t* by1 = (bf16_t*)(base);
  bf16_t* bh1 = (bf16_t*)(base + 33554432);
  float* qb = (float*)(base + 33554432);
  float* outb = (float*)(base + 33554432);
  float* partial = (float*)(base + 50331648);   // 13.1 MB [center..sim_cin]
  float* pbuf = (float*)(base + 50331648);
  bf16_t* y2 = (bf16_t*)(base + 50331648);      // 33.5 MB [dwconv..fc2]; pbuf/czt dead
  bf16_t* czt = (bf16_t*)(base + 67108864);
  bf16_t* obz = (bf16_t*)(base + 67108864);
  bf16_t* outb_b = (bf16_t*)(base + 67108864);
  bf16_t* wtb = (bf16_t*)(base + 80216064);
  bf16_t* h2c = (bf16_t*)(base + 80216064);
  bf16_t* wbz = (bf16_t*)(base + 96993280);
  float* cin = (float*)(base + 100124672);
  float* kb = (float*)(base + 100534272);
  float* vb = (float*)(base + 100943872);
  float* dout = (float*)d_out;                  // fc2 writes here (yout), add_ln in-place

  bf16_t* conv2_wb = wbz;            // 65536
  bf16_t* conv3_wb = wbz + 65536;    // 25600
  bf16_t* q_wb = wbz + 91136;        // 65536
  bf16_t* proj_wb = wbz + 156672;    // 65536
  bf16_t* fc1_wb = wbz + 222208;     // 262144
  bf16_t* fc2_wb = wbz + 484352;     // 262144

  prologue<<<22436, 256, 0, stream>>>(x, mem, xtb, conv1_w, wtb, conv2_w, conv3_w,
                                      q_w, proj_w, fc1_w, fc2_w, wbz);
  conv1_mfma<<<1024, 256, 0, stream>>>(xtb, wtb, conv1_b, bh1);
  for (int i = 0; i < 2; ++i) {
    gemm_mfma<1, 1, 0, 1><<<dim3(2, 256, 1), 256, 0, stream>>>(
        bh1 + (size_t)i * 32768 * CC, conv2_wb, conv2_b, h2c, 32768, 256, 256, 256, 0, 0);
    gemm_mfma<0, 0, 1, 1><<<dim3(1, 256, 1), 256, 0, stream>>>(
        h2c, conv3_wb, nullptr, czt + (size_t)i * 32768, 32768, 100, 256, 65536, 0, 0);
  }
  softmax_rows<<<1600, 256, 0, stream>>>(czt);
  center_mfma<<<dim3(2, 16, 8), 256, 0, stream>>>(czt, xtb, partial);
  sim_cin<<<400, 256, 0, stream>>>(partial, sim_a, sim_b, ln_w, ln_b, cin);
  gemm_mfma<0, 1, 0, 0><<<dim3(2, 32, 4), 256, 0, stream>>>(
      xtb + (size_t)3 * NN * CC, q_wb, q_b, qb, 4096, 256, 256, 256,
      (size_t)4 * NN * CC, (size_t)NN * CC);
  gemm_kv<<<dim3(4, 7, 2), 256, 0, stream>>>(cin, k_w, k_b, v_w, v_b, kb, vb);
  attn2<<<dim3(512, 4), 256, 0, stream>>>(qb, kb, vb, obz);
  gemm_mfma<0, 1, 0, 0><<<dim3(2, 128, 1), 256, 0, stream>>>(obz, proj_wb, proj_b, pbuf,
                                                             16384, 256, 256, 256, 0, 0);
  add_ln<1><<<16384, 256, 0, stream>>>(x, pbuf, ln_w, ln_b, outb, outb_b);
  gemm_mfma<0, 1, 0, 1><<<dim3(8, 128, 1), 256, 0, stream>>>(outb_b, fc1_wb, fc1_b, by1,
                                                             16384, 1024, 256, 1024, 0, 0);
  dwconv_kernel<<<16384, 256, 0, stream>>>(by1, dw_w, dw_b, y2);
  gemm_mfma<0, 1, 0, 0><<<dim3(2, 32, 4), 256, 0, stream>>>(
      y2, fc2_wb, fc2_b, dout, 4096, 256, 1024, 256,
      (size_t)NN * C4, (size_t)NN * CC);
  add_ln<0><<<16384, 256, 0, stream>>>(outb, dout, ln_w, ln_b, dout, nullptr);
}